// Round 1
// baseline (2169.070 us; speedup 1.0000x reference)
//
#include <hip/hip_runtime.h>
#include <math.h>

// ---------------------------------------------------------------------------
// TemporalGraphEncoder: N=50000 nodes, E=1.6M edges, D=128, H=4, C=32, HOPS=3
// Pipeline: sn(W_in) GEMM+gelu -> GAT x2 (fused gelu+LN) -> RK4 ODE (16 GEMMs)
//           -> 3-hop mean broadcast -> hop-attention combine.
// All fp32. CSR built on device (hist/scan/scatter) to avoid fp32 atomics.
// ---------------------------------------------------------------------------

__device__ __forceinline__ float gelu_f(float x) {
    return 0.5f * x * (1.0f + erff(x * 0.70710678118654752f));
}

// ---------------------- spectral norm (power iteration) --------------------
// one block per matrix; 128 threads; W and W^T staged in LDS.
__launch_bounds__(128, 1)
__global__ void sn_k(const float* __restrict__ Win, const float* __restrict__ Wode,
                     float* __restrict__ WnIn, float* __restrict__ WnOde)
{
    __shared__ float Ws[128 * 128];
    __shared__ float Wt[128 * 128];
    __shared__ float red[128];
    const float* W  = (blockIdx.x == 0) ? Win  : Wode;
    float*       Wn = (blockIdx.x == 0) ? WnIn : WnOde;
    const int t = threadIdx.x;

    for (int i = t * 4; i < 16384; i += 512) {
        float4 v = *(const float4*)&W[i];
        *(float4*)&Ws[i] = v;
        int r = i >> 7, c = i & 127;
        Wt[(c + 0) * 128 + r] = v.x;
        Wt[(c + 1) * 128 + r] = v.y;
        Wt[(c + 2) * 128 + r] = v.z;
        Wt[(c + 3) * 128 + r] = v.w;
    }
    __syncthreads();

    float u = 0.088388347648318447f;  // 1/sqrt(128)
    float v = 0.0f;
    for (int it = 0; it < 5; it++) {
        // v = normalize(W^T u)
        red[t] = u; __syncthreads();
        float vv = 0.f;
        for (int i = 0; i < 128; i++) vv = fmaf(Ws[i * 128 + t], red[i], vv);
        __syncthreads();
        red[t] = vv * vv; __syncthreads();
        for (int s = 64; s > 0; s >>= 1) { if (t < s) red[t] += red[t + s]; __syncthreads(); }
        float nv = sqrtf(red[0]) + 1e-12f;
        v = vv / nv;
        __syncthreads();
        // u = normalize(W v)
        red[t] = v; __syncthreads();
        float uu = 0.f;
        for (int i = 0; i < 128; i++) uu = fmaf(Wt[i * 128 + t], red[i], uu);
        __syncthreads();
        red[t] = uu * uu; __syncthreads();
        for (int s = 64; s > 0; s >>= 1) { if (t < s) red[t] += red[t + s]; __syncthreads(); }
        float nu = sqrtf(red[0]) + 1e-12f;
        u = uu / nu;
        __syncthreads();
    }
    // sigma = u . (W v)
    red[t] = v; __syncthreads();
    float wv = 0.f;
    for (int i = 0; i < 128; i++) wv = fmaf(Wt[i * 128 + t], red[i], wv);
    __syncthreads();
    red[t] = u * wv; __syncthreads();
    for (int s = 64; s > 0; s >>= 1) { if (t < s) red[t] += red[t + s]; __syncthreads(); }
    float inv = 1.0f / (red[0] + 1e-12f);
    __syncthreads();
    for (int i = t * 4; i < 16384; i += 512) {
        float4 w = *(const float4*)&Ws[i];
        w.x *= inv; w.y *= inv; w.z *= inv; w.w *= inv;
        *(float4*)&Wn[i] = w;
    }
}

// ------------------------------ CSR build ----------------------------------
__global__ void hist_k(const int* __restrict__ dst, int* __restrict__ deg, int E, int N)
{
    int e = blockIdx.x * blockDim.x + threadIdx.x;
    if (e < E) {
        int d = dst[e];
        d = (d < 0) ? 0 : (d >= N ? N - 1 : d);
        atomicAdd(&deg[d], 1);
    }
}

__launch_bounds__(1024, 1)
__global__ void scan_k(const int* __restrict__ deg, int* __restrict__ offs, int n)
{
    __shared__ int part[1024];
    const int t = threadIdx.x;
    const int chunk = (n + 1023) >> 10;
    int lo = t * chunk; if (lo > n) lo = n;
    int hi = lo + chunk; if (hi > n) hi = n;
    int s = 0;
    for (int i = lo; i < hi; i++) s += deg[i];
    part[t] = s; __syncthreads();
    for (int d = 1; d < 1024; d <<= 1) {
        int v = (t >= d) ? part[t - d] : 0;
        __syncthreads();
        part[t] += v;
        __syncthreads();
    }
    int run = (t == 0) ? 0 : part[t - 1];
    for (int i = lo; i < hi; i++) { offs[i] = run; run += deg[i]; }
    if (t == 1023) offs[n] = run;
}

__global__ void scatter_k(const int* __restrict__ src, const int* __restrict__ dst,
                          const int* __restrict__ offs, int* __restrict__ cursor,
                          int* __restrict__ col, int E, int N)
{
    int e = blockIdx.x * blockDim.x + threadIdx.x;
    if (e < E) {
        int d = dst[e];
        d = (d < 0) ? 0 : (d >= N ? N - 1 : d);
        int s = src[e];
        s = (s < 0) ? 0 : (s >= N ? N - 1 : s);
        int pos = offs[d] + atomicAdd(&cursor[d], 1);
        col[pos] = s;
    }
}

// ------------------------------ GEMM 128 -----------------------------------
// [nrows,128] @ [128,128]; W in LDS; 8x8 register tile; x streamed from global.
// mode 0: out = in@W (raw), + fused al_s/al_d head reductions
// mode 1: out = gelu(in@W + bias)
// mode 2: K = gelu(in@W + bias); accout = (accin? accin : yv) + ca*K;
//         if (tout) tout = yv + ct*K          (rows are block-disjoint)
__launch_bounds__(256, 2)
__global__ void gemm128_k(const float* __restrict__ in, const float* __restrict__ W,
                          const float* __restrict__ bias, float* __restrict__ out,
                          int nrows, int mode,
                          const float* __restrict__ a_s, const float* __restrict__ a_d,
                          float* __restrict__ als, float* __restrict__ ald,
                          const float* __restrict__ yv, const float* __restrict__ accin,
                          float* __restrict__ accout, float* __restrict__ tout,
                          float ca, float ct)
{
    __shared__ float Ws[128 * 128];
    const int t = threadIdx.x;
    const int n0 = blockIdx.x * 128;

    for (int i = t * 4; i < 16384; i += 1024)
        *(float4*)&Ws[i] = *(const float4*)&W[i];
    __syncthreads();

    const int cg = t & 15, rg = t >> 4;
    const int c0 = cg * 8, r0 = rg * 8;

    const float* xrow[8];
    bool rowok[8];
#pragma unroll
    for (int i = 0; i < 8; i++) {
        int r = n0 + r0 + i;
        rowok[i] = (r < nrows);
        int rc = rowok[i] ? r : (nrows - 1);
        xrow[i] = in + (size_t)rc * 128;
    }

    float acc[8][8];
#pragma unroll
    for (int i = 0; i < 8; i++)
#pragma unroll
        for (int j = 0; j < 8; j++) acc[i][j] = 0.f;

    for (int k = 0; k < 128; k += 4) {
        float4 xv[8];
#pragma unroll
        for (int i = 0; i < 8; i++) xv[i] = *(const float4*)(xrow[i] + k);
#pragma unroll
        for (int kk = 0; kk < 4; kk++) {
            float4 w0 = *(const float4*)&Ws[(k + kk) * 128 + c0];
            float4 w1 = *(const float4*)&Ws[(k + kk) * 128 + c0 + 4];
#pragma unroll
            for (int i = 0; i < 8; i++) {
                float xk = (kk == 0) ? xv[i].x : (kk == 1) ? xv[i].y : (kk == 2) ? xv[i].z : xv[i].w;
                acc[i][0] = fmaf(xk, w0.x, acc[i][0]);
                acc[i][1] = fmaf(xk, w0.y, acc[i][1]);
                acc[i][2] = fmaf(xk, w0.z, acc[i][2]);
                acc[i][3] = fmaf(xk, w0.w, acc[i][3]);
                acc[i][4] = fmaf(xk, w1.x, acc[i][4]);
                acc[i][5] = fmaf(xk, w1.y, acc[i][5]);
                acc[i][6] = fmaf(xk, w1.z, acc[i][6]);
                acc[i][7] = fmaf(xk, w1.w, acc[i][7]);
            }
        }
    }

    if (mode == 0) {
        // fused attention-logit reductions: head h = c0/32
        const int h = cg >> 2, coff = (cg & 3) * 8;
        float ps[8], pd[8];
#pragma unroll
        for (int i = 0; i < 8; i++) {
            float s_ = 0.f, d_ = 0.f;
#pragma unroll
            for (int j = 0; j < 8; j++) {
                s_ = fmaf(acc[i][j], a_s[h * 32 + coff + j], s_);
                d_ = fmaf(acc[i][j], a_d[h * 32 + coff + j], d_);
            }
            ps[i] = s_; pd[i] = d_;
        }
#pragma unroll
        for (int mk = 1; mk < 4; mk <<= 1) {
#pragma unroll
            for (int i = 0; i < 8; i++) {
                ps[i] += __shfl_xor(ps[i], mk);
                pd[i] += __shfl_xor(pd[i], mk);
            }
        }
        if ((cg & 3) == 0) {
#pragma unroll
            for (int i = 0; i < 8; i++) if (rowok[i]) {
                als[(size_t)(n0 + r0 + i) * 4 + h] = ps[i];
                ald[(size_t)(n0 + r0 + i) * 4 + h] = pd[i];
            }
        }
#pragma unroll
        for (int i = 0; i < 8; i++) if (rowok[i]) {
            size_t b = (size_t)(n0 + r0 + i) * 128 + c0;
            *(float4*)&out[b]     = make_float4(acc[i][0], acc[i][1], acc[i][2], acc[i][3]);
            *(float4*)&out[b + 4] = make_float4(acc[i][4], acc[i][5], acc[i][6], acc[i][7]);
        }
    } else if (mode == 1) {
#pragma unroll
        for (int i = 0; i < 8; i++) if (rowok[i]) {
            size_t b = (size_t)(n0 + r0 + i) * 128 + c0;
            float o[8];
#pragma unroll
            for (int j = 0; j < 8; j++) o[j] = gelu_f(acc[i][j] + bias[c0 + j]);
            *(float4*)&out[b]     = make_float4(o[0], o[1], o[2], o[3]);
            *(float4*)&out[b + 4] = make_float4(o[4], o[5], o[6], o[7]);
        }
    } else {  // mode 2: RK4 sub-step epilogue
#pragma unroll
        for (int i = 0; i < 8; i++) {
            if (!rowok[i]) continue;
            size_t b = (size_t)(n0 + r0 + i) * 128 + c0;
            float K[8];
#pragma unroll
            for (int j = 0; j < 8; j++) K[j] = gelu_f(acc[i][j] + bias[c0 + j]);
            float4 y0 = *(const float4*)&yv[b];
            float4 y1 = *(const float4*)&yv[b + 4];
            float yb[8] = { y0.x, y0.y, y0.z, y0.w, y1.x, y1.y, y1.z, y1.w };
            float ab[8];
            if (accin) {
                float4 a0 = *(const float4*)&accin[b];
                float4 a1 = *(const float4*)&accin[b + 4];
                ab[0] = a0.x; ab[1] = a0.y; ab[2] = a0.z; ab[3] = a0.w;
                ab[4] = a1.x; ab[5] = a1.y; ab[6] = a1.z; ab[7] = a1.w;
            } else {
#pragma unroll
                for (int j = 0; j < 8; j++) ab[j] = yb[j];
            }
            float ov[8];
#pragma unroll
            for (int j = 0; j < 8; j++) ov[j] = fmaf(ca, K[j], ab[j]);
            *(float4*)&accout[b]     = make_float4(ov[0], ov[1], ov[2], ov[3]);
            *(float4*)&accout[b + 4] = make_float4(ov[4], ov[5], ov[6], ov[7]);
            if (tout) {
                float tv[8];
#pragma unroll
                for (int j = 0; j < 8; j++) tv[j] = fmaf(ct, K[j], yb[j]);
                *(float4*)&tout[b]     = make_float4(tv[0], tv[1], tv[2], tv[3]);
                *(float4*)&tout[b + 4] = make_float4(tv[4], tv[5], tv[6], tv[7]);
            }
        }
    }
}

// ----------------------- GAT aggregation (wave per node) -------------------
// edge-softmax (max, sumexp, weighted sum) + bias + gelu + LayerNorm fused.
__launch_bounds__(256)
__global__ void gat_agg_k(const float* __restrict__ xh, const float* __restrict__ als,
                          const float* __restrict__ ald, const int* __restrict__ col,
                          const int* __restrict__ offs,
                          const float* __restrict__ bias, const float* __restrict__ g,
                          const float* __restrict__ be, float* __restrict__ hout, int nnodes)
{
    const int n = blockIdx.x * 4 + (threadIdx.x >> 6);
    if (n >= nnodes) return;
    const int lane = threadIdx.x & 63;
    const int e0 = offs[n], e1 = offs[n + 1];
    const float4 aldv = *(const float4*)&ald[(size_t)n * 4];

    float m0 = -1e30f, m1 = -1e30f, m2 = -1e30f, m3 = -1e30f;
    for (int i = e0 + lane; i < e1; i += 64) {
        int s = col[i];
        float4 av = *(const float4*)&als[(size_t)s * 4];
        float l0 = av.x + aldv.x; l0 = l0 > 0.f ? l0 : 0.2f * l0;
        float l1 = av.y + aldv.y; l1 = l1 > 0.f ? l1 : 0.2f * l1;
        float l2 = av.z + aldv.z; l2 = l2 > 0.f ? l2 : 0.2f * l2;
        float l3 = av.w + aldv.w; l3 = l3 > 0.f ? l3 : 0.2f * l3;
        m0 = fmaxf(m0, l0); m1 = fmaxf(m1, l1); m2 = fmaxf(m2, l2); m3 = fmaxf(m3, l3);
    }
#pragma unroll
    for (int mk = 32; mk >= 1; mk >>= 1) {
        m0 = fmaxf(m0, __shfl_xor(m0, mk));
        m1 = fmaxf(m1, __shfl_xor(m1, mk));
        m2 = fmaxf(m2, __shfl_xor(m2, mk));
        m3 = fmaxf(m3, __shfl_xor(m3, mk));
    }
    float s0 = 0.f, s1 = 0.f, s2 = 0.f, s3 = 0.f;
    for (int i = e0 + lane; i < e1; i += 64) {
        int s = col[i];
        float4 av = *(const float4*)&als[(size_t)s * 4];
        float l0 = av.x + aldv.x; l0 = l0 > 0.f ? l0 : 0.2f * l0;
        float l1 = av.y + aldv.y; l1 = l1 > 0.f ? l1 : 0.2f * l1;
        float l2 = av.z + aldv.z; l2 = l2 > 0.f ? l2 : 0.2f * l2;
        float l3 = av.w + aldv.w; l3 = l3 > 0.f ? l3 : 0.2f * l3;
        s0 += expf(l0 - m0); s1 += expf(l1 - m1); s2 += expf(l2 - m2); s3 += expf(l3 - m3);
    }
#pragma unroll
    for (int mk = 32; mk >= 1; mk >>= 1) {
        s0 += __shfl_xor(s0, mk); s1 += __shfl_xor(s1, mk);
        s2 += __shfl_xor(s2, mk); s3 += __shfl_xor(s3, mk);
    }

    const int c0 = lane * 2;
    const int hh = c0 >> 5;
    const float mh = (hh == 0) ? m0 : (hh == 1) ? m1 : (hh == 2) ? m2 : m3;
    const float sh = (hh == 0) ? s0 : (hh == 1) ? s1 : (hh == 2) ? s2 : s3;
    const float aldh = (hh == 0) ? aldv.x : (hh == 1) ? aldv.y : (hh == 2) ? aldv.z : aldv.w;

    float ax = 0.f, ay = 0.f;
    for (int i = e0; i < e1; i++) {
        int s = col[i];
        float asv = als[(size_t)s * 4 + hh];
        float l = asv + aldh; l = l > 0.f ? l : 0.2f * l;
        float alpha = expf(l - mh) / (sh + 1e-16f);
        float2 xv = *(const float2*)&xh[(size_t)s * 128 + c0];
        ax = fmaf(alpha, xv.x, ax);
        ay = fmaf(alpha, xv.y, ay);
    }

    float v0 = gelu_f(ax + bias[c0]);
    float v1 = gelu_f(ay + bias[c0 + 1]);
    float sum = v0 + v1;
#pragma unroll
    for (int mk = 32; mk >= 1; mk >>= 1) sum += __shfl_xor(sum, mk);
    float mean = sum * (1.0f / 128.0f);
    float d0 = v0 - mean, d1 = v1 - mean;
    float vs = d0 * d0 + d1 * d1;
#pragma unroll
    for (int mk = 32; mk >= 1; mk >>= 1) vs += __shfl_xor(vs, mk);
    float rstd = rsqrtf(vs * (1.0f / 128.0f) + 1e-5f);
    size_t b = (size_t)n * 128 + c0;
    hout[b]     = d0 * rstd * g[c0] + be[c0];
    hout[b + 1] = d1 * rstd * g[c0 + 1] + be[c0 + 1];
}

// ----------------------- hop mean-aggregation ------------------------------
__launch_bounds__(256)
__global__ void hop_agg_k(const float* __restrict__ cur, const int* __restrict__ col,
                          const int* __restrict__ offs, const int* __restrict__ deg,
                          float* __restrict__ outv, int nnodes)
{
    const int n = blockIdx.x * 4 + (threadIdx.x >> 6);
    if (n >= nnodes) return;
    const int lane = threadIdx.x & 63;
    const int c0 = lane * 2;
    const int e0 = offs[n], e1 = offs[n + 1];
    float ax = 0.f, ay = 0.f;
    for (int i = e0; i < e1; i++) {
        int s = col[i];
        float2 v = *(const float2*)&cur[(size_t)s * 128 + c0];
        ax += v.x; ay += v.y;
    }
    float dg = fmaxf((float)deg[n], 1.0f);
    size_t b = (size_t)n * 128 + c0;
    outv[b]     = ax / dg;
    outv[b + 1] = ay / dg;
}

// ----------------------- hop-attention combine -----------------------------
__launch_bounds__(256)
__global__ void final_k(const float* __restrict__ st0, const float* __restrict__ st1,
                        const float* __restrict__ st2, float* __restrict__ st3out,
                        const float* __restrict__ att, int nnodes)
{
    const int n = blockIdx.x * 4 + (threadIdx.x >> 6);
    if (n >= nnodes) return;
    const int lane = threadIdx.x & 63;
    const int c0 = lane * 2;
    size_t b = (size_t)n * 128 + c0;
    float2 a  = *(const float2*)&att[c0];
    float2 v0 = *(const float2*)&st0[b];
    float2 v1 = *(const float2*)&st1[b];
    float2 v2 = *(const float2*)&st2[b];
    float2 v3 = *(const float2*)&st3out[b];
    float p0 = v0.x * a.x + v0.y * a.y;
    float p1 = v1.x * a.x + v1.y * a.y;
    float p2 = v2.x * a.x + v2.y * a.y;
    float p3 = v3.x * a.x + v3.y * a.y;
#pragma unroll
    for (int mk = 32; mk >= 1; mk >>= 1) {
        p0 += __shfl_xor(p0, mk); p1 += __shfl_xor(p1, mk);
        p2 += __shfl_xor(p2, mk); p3 += __shfl_xor(p3, mk);
    }
    float mm = fmaxf(fmaxf(p0, p1), fmaxf(p2, p3));
    float e0 = expf(p0 - mm), e1 = expf(p1 - mm), e2 = expf(p2 - mm), e3 = expf(p3 - mm);
    float inv = 1.0f / (e0 + e1 + e2 + e3);
    float w0 = e0 * inv, w1 = e1 * inv, w2 = e2 * inv, w3 = e3 * inv;
    float ox = w0 * v0.x + w1 * v1.x + w2 * v2.x + w3 * v3.x;
    float oy = w0 * v0.y + w1 * v1.y + w2 * v2.y + w3 * v3.y;
    st3out[b]     = ox;
    st3out[b + 1] = oy;
}

// ---------------------------------------------------------------------------
extern "C" void kernel_launch(void* const* d_in, const int* in_sizes, int n_in,
                              void* d_out, int out_size, void* d_ws, size_t ws_size,
                              hipStream_t stream)
{
    const float* x     = (const float*)d_in[0];
    const int*   ei    = (const int*)d_in[1];
    const float* W_in  = (const float*)d_in[2];
    const float* b_in  = (const float*)d_in[3];
    const float* W1    = (const float*)d_in[4];
    const float* a_s1  = (const float*)d_in[5];
    const float* a_d1  = (const float*)d_in[6];
    const float* b1    = (const float*)d_in[7];
    const float* W2    = (const float*)d_in[8];
    const float* a_s2  = (const float*)d_in[9];
    const float* a_d2  = (const float*)d_in[10];
    const float* b2    = (const float*)d_in[11];
    const float* g1    = (const float*)d_in[12];
    const float* be1   = (const float*)d_in[13];
    const float* g2    = (const float*)d_in[14];
    const float* be2   = (const float*)d_in[15];
    const float* W_ode = (const float*)d_in[16];
    const float* b_ode = (const float*)d_in[17];
    const float* att   = (const float*)d_in[18];

    const int N = in_sizes[0] / 128;
    const int E = in_sizes[1] / 2;
    const int* srcv = ei;
    const int* dstv = ei + E;

    char* wsb = (char*)d_ws;
    size_t off = 0;
    auto alloc = [&](size_t bytes) -> void* {
        void* p = wsb + off;
        off = (off + bytes + 511) & ~(size_t)511;
        return p;
    };
    float* WnIn   = (float*)alloc(65536);
    float* WnOde  = (float*)alloc(65536);
    float* als    = (float*)alloc((size_t)N * 4 * 4);
    float* ald    = (float*)alloc((size_t)N * 4 * 4);
    int*   deg    = (int*)alloc((size_t)N * 4);
    int*   cursor = (int*)alloc((size_t)N * 4);
    int*   offs   = (int*)alloc((size_t)(N + 1) * 4);
    int*   col    = (int*)alloc((size_t)E * 4);
    float* B0     = (float*)alloc((size_t)N * 128 * 4);
    float* B1     = (float*)alloc((size_t)N * 128 * 4);
    float* B2     = (float*)alloc((size_t)N * 128 * 4);

    (void)hipMemsetAsync(deg, 0, (size_t)N * 4, stream);
    (void)hipMemsetAsync(cursor, 0, (size_t)N * 4, stream);

    sn_k<<<2, 128, 0, stream>>>(W_in, W_ode, WnIn, WnOde);
    hist_k<<<(E + 255) / 256, 256, 0, stream>>>(dstv, deg, E, N);
    scan_k<<<1, 1024, 0, stream>>>(deg, offs, N);
    scatter_k<<<(E + 255) / 256, 256, 0, stream>>>(srcv, dstv, offs, cursor, col, E, N);

    const int gblocks = (N + 127) / 128;
    const int ablocks = (N + 3) / 4;

    // input layer: B0 = gelu(x @ sn(W_in) + b_in)
    gemm128_k<<<gblocks, 256, 0, stream>>>(x, WnIn, b_in, B0, N, 1,
        nullptr, nullptr, nullptr, nullptr, nullptr, nullptr, nullptr, nullptr, 0.f, 0.f);

    // GAT layer 1
    gemm128_k<<<gblocks, 256, 0, stream>>>(B0, W1, nullptr, B1, N, 0,
        a_s1, a_d1, als, ald, nullptr, nullptr, nullptr, nullptr, 0.f, 0.f);
    gat_agg_k<<<ablocks, 256, 0, stream>>>(B1, als, ald, col, offs, b1, g1, be1, B0, N);

    // GAT layer 2
    gemm128_k<<<gblocks, 256, 0, stream>>>(B0, W2, nullptr, B1, N, 0,
        a_s2, a_d2, als, ald, nullptr, nullptr, nullptr, nullptr, 0.f, 0.f);
    gat_agg_k<<<ablocks, 256, 0, stream>>>(B1, als, ald, col, offs, b2, g2, be2, B0, N);

    // ODE block: 4 RK4 steps, f(y) = gelu(y @ sn(W_ode) + b_ode)
    const float dt = 0.25f;
    float* ybuf = B0;
    float* abuf = B1;
    for (int step = 0; step < 4; step++) {
        gemm128_k<<<gblocks, 256, 0, stream>>>(ybuf, WnOde, b_ode, nullptr, N, 2,
            nullptr, nullptr, nullptr, nullptr, ybuf, nullptr, abuf, B2, dt / 6.f, dt * 0.5f);
        gemm128_k<<<gblocks, 256, 0, stream>>>(B2, WnOde, b_ode, nullptr, N, 2,
            nullptr, nullptr, nullptr, nullptr, ybuf, abuf, abuf, B2, dt / 3.f, dt * 0.5f);
        gemm128_k<<<gblocks, 256, 0, stream>>>(B2, WnOde, b_ode, nullptr, N, 2,
            nullptr, nullptr, nullptr, nullptr, ybuf, abuf, abuf, B2, dt / 3.f, dt);
        gemm128_k<<<gblocks, 256, 0, stream>>>(B2, WnOde, b_ode, nullptr, N, 2,
            nullptr, nullptr, nullptr, nullptr, ybuf, abuf, abuf, nullptr, dt / 6.f, 0.f);
        float* tmp = ybuf; ybuf = abuf; abuf = tmp;
    }
    // after 4 swaps: ybuf == B0 holds the ODE output

    float* out = (float*)d_out;
    hop_agg_k<<<ablocks, 256, 0, stream>>>(ybuf, col, offs, deg, abuf, N);  // hop1 -> B1
    hop_agg_k<<<ablocks, 256, 0, stream>>>(abuf, col, offs, deg, B2, N);    // hop2 -> B2
    hop_agg_k<<<ablocks, 256, 0, stream>>>(B2, col, offs, deg, out, N);     // hop3 -> out
    final_k<<<ablocks, 256, 0, stream>>>(ybuf, abuf, B2, out, att, N);
}

// Round 2
// 1483.091 us; speedup vs baseline: 1.4625x; 1.4625x over previous
//
#include <hip/hip_runtime.h>
#include <math.h>

// ---------------------------------------------------------------------------
// TemporalGraphEncoder: N=50000, E=1.6M, D=128, H=4, C=32, HOPS=3
// r2: fused single-kernel RK4 ODE (W + stage vectors in LDS),
//     bf16 gather payloads (xh, hop stack), online-softmax GAT agg with
//     LDS-cached per-edge alpha.
// ---------------------------------------------------------------------------

__device__ __forceinline__ float gelu_f(float x) {
    return 0.5f * x * (1.0f + erff(x * 0.70710678118654752f));
}
__device__ __forceinline__ unsigned pack_bf16(float a, float b) {
    unsigned ua = __float_as_uint(a), ub = __float_as_uint(b);
    ua += 0x7fffu + ((ua >> 16) & 1u);
    ub += 0x7fffu + ((ub >> 16) & 1u);
    return (ua >> 16) | (ub & 0xffff0000u);
}
__device__ __forceinline__ float bf_lo(unsigned u) { return __uint_as_float(u << 16); }
__device__ __forceinline__ float bf_hi(unsigned u) { return __uint_as_float(u & 0xffff0000u); }

// ---------------------- spectral norm (power iteration) --------------------
__launch_bounds__(128, 1)
__global__ void sn_k(const float* __restrict__ Win, const float* __restrict__ Wode,
                     float* __restrict__ WnIn, float* __restrict__ WnOde)
{
    __shared__ float Ws[128 * 128];
    __shared__ float Wt[128 * 128];
    __shared__ float red[128];
    const float* W  = (blockIdx.x == 0) ? Win  : Wode;
    float*       Wn = (blockIdx.x == 0) ? WnIn : WnOde;
    const int t = threadIdx.x;

    for (int i = t * 4; i < 16384; i += 512) {
        float4 v = *(const float4*)&W[i];
        *(float4*)&Ws[i] = v;
        int r = i >> 7, c = i & 127;
        Wt[(c + 0) * 128 + r] = v.x;
        Wt[(c + 1) * 128 + r] = v.y;
        Wt[(c + 2) * 128 + r] = v.z;
        Wt[(c + 3) * 128 + r] = v.w;
    }
    __syncthreads();

    float u = 0.088388347648318447f;  // 1/sqrt(128)
    float v = 0.0f;
    for (int it = 0; it < 5; it++) {
        red[t] = u; __syncthreads();
        float vv = 0.f;
        for (int i = 0; i < 128; i++) vv = fmaf(Ws[i * 128 + t], red[i], vv);
        __syncthreads();
        red[t] = vv * vv; __syncthreads();
        for (int s = 64; s > 0; s >>= 1) { if (t < s) red[t] += red[t + s]; __syncthreads(); }
        float nv = sqrtf(red[0]) + 1e-12f;
        v = vv / nv;
        __syncthreads();
        red[t] = v; __syncthreads();
        float uu = 0.f;
        for (int i = 0; i < 128; i++) uu = fmaf(Wt[i * 128 + t], red[i], uu);
        __syncthreads();
        red[t] = uu * uu; __syncthreads();
        for (int s = 64; s > 0; s >>= 1) { if (t < s) red[t] += red[t + s]; __syncthreads(); }
        float nu = sqrtf(red[0]) + 1e-12f;
        u = uu / nu;
        __syncthreads();
    }
    red[t] = v; __syncthreads();
    float wv = 0.f;
    for (int i = 0; i < 128; i++) wv = fmaf(Wt[i * 128 + t], red[i], wv);
    __syncthreads();
    red[t] = u * wv; __syncthreads();
    for (int s = 64; s > 0; s >>= 1) { if (t < s) red[t] += red[t + s]; __syncthreads(); }
    float inv = 1.0f / (red[0] + 1e-12f);
    __syncthreads();
    for (int i = t * 4; i < 16384; i += 512) {
        float4 w = *(const float4*)&Ws[i];
        w.x *= inv; w.y *= inv; w.z *= inv; w.w *= inv;
        *(float4*)&Wn[i] = w;
    }
}

// ------------------------------ CSR build ----------------------------------
__global__ void hist_k(const int* __restrict__ dst, int* __restrict__ deg, int E, int N)
{
    int e = blockIdx.x * blockDim.x + threadIdx.x;
    if (e < E) {
        int d = dst[e];
        d = (d < 0) ? 0 : (d >= N ? N - 1 : d);
        atomicAdd(&deg[d], 1);
    }
}

__launch_bounds__(1024, 1)
__global__ void scan_k(const int* __restrict__ deg, int* __restrict__ offs, int n)
{
    __shared__ int part[1024];
    const int t = threadIdx.x;
    const int chunk = (n + 1023) >> 10;
    int lo = t * chunk; if (lo > n) lo = n;
    int hi = lo + chunk; if (hi > n) hi = n;
    int s = 0;
    for (int i = lo; i < hi; i++) s += deg[i];
    part[t] = s; __syncthreads();
    for (int d = 1; d < 1024; d <<= 1) {
        int v = (t >= d) ? part[t - d] : 0;
        __syncthreads();
        part[t] += v;
        __syncthreads();
    }
    int run = (t == 0) ? 0 : part[t - 1];
    for (int i = lo; i < hi; i++) { offs[i] = run; run += deg[i]; }
    if (t == 1023) offs[n] = run;
}

__global__ void scatter_k(const int* __restrict__ src, const int* __restrict__ dst,
                          const int* __restrict__ offs, int* __restrict__ cursor,
                          int* __restrict__ col, int E, int N)
{
    int e = blockIdx.x * blockDim.x + threadIdx.x;
    if (e < E) {
        int d = dst[e];
        d = (d < 0) ? 0 : (d >= N ? N - 1 : d);
        int s = src[e];
        s = (s < 0) ? 0 : (s >= N ? N - 1 : s);
        int pos = offs[d] + atomicAdd(&cursor[d], 1);
        col[pos] = s;
    }
}

// ------------------------------ GEMM 128 -----------------------------------
// mode 0: xh = in@W -> bf16 out_bf + fused al_s/al_d head reductions (fp32)
// mode 1: out_f32 = gelu(in@W + bias)
__launch_bounds__(256, 2)
__global__ void gemm128_k(const float* __restrict__ in, const float* __restrict__ W,
                          const float* __restrict__ bias, float* __restrict__ out_f32,
                          unsigned* __restrict__ out_bf, int nrows, int mode,
                          const float* __restrict__ a_s, const float* __restrict__ a_d,
                          float* __restrict__ als, float* __restrict__ ald)
{
    __shared__ float Ws[128 * 128];
    const int t = threadIdx.x;
    const int n0 = blockIdx.x * 128;

    for (int i = t * 4; i < 16384; i += 1024)
        *(float4*)&Ws[i] = *(const float4*)&W[i];
    __syncthreads();

    const int cg = t & 15, rg = t >> 4;
    const int c0 = cg * 8, r0 = rg * 8;

    const float* xrow[8];
    bool rowok[8];
#pragma unroll
    for (int i = 0; i < 8; i++) {
        int r = n0 + r0 + i;
        rowok[i] = (r < nrows);
        int rc = rowok[i] ? r : (nrows - 1);
        xrow[i] = in + (size_t)rc * 128;
    }

    float acc[8][8];
#pragma unroll
    for (int i = 0; i < 8; i++)
#pragma unroll
        for (int j = 0; j < 8; j++) acc[i][j] = 0.f;

    for (int k = 0; k < 128; k += 4) {
        float4 xv[8];
#pragma unroll
        for (int i = 0; i < 8; i++) xv[i] = *(const float4*)(xrow[i] + k);
#pragma unroll
        for (int kk = 0; kk < 4; kk++) {
            float4 w0 = *(const float4*)&Ws[(k + kk) * 128 + c0];
            float4 w1 = *(const float4*)&Ws[(k + kk) * 128 + c0 + 4];
#pragma unroll
            for (int i = 0; i < 8; i++) {
                float xk = (kk == 0) ? xv[i].x : (kk == 1) ? xv[i].y : (kk == 2) ? xv[i].z : xv[i].w;
                acc[i][0] = fmaf(xk, w0.x, acc[i][0]);
                acc[i][1] = fmaf(xk, w0.y, acc[i][1]);
                acc[i][2] = fmaf(xk, w0.z, acc[i][2]);
                acc[i][3] = fmaf(xk, w0.w, acc[i][3]);
                acc[i][4] = fmaf(xk, w1.x, acc[i][4]);
                acc[i][5] = fmaf(xk, w1.y, acc[i][5]);
                acc[i][6] = fmaf(xk, w1.z, acc[i][6]);
                acc[i][7] = fmaf(xk, w1.w, acc[i][7]);
            }
        }
    }

    if (mode == 0) {
        const int h = cg >> 2, coff = (cg & 3) * 8;
        float ps[8], pd[8];
#pragma unroll
        for (int i = 0; i < 8; i++) {
            float s_ = 0.f, d_ = 0.f;
#pragma unroll
            for (int j = 0; j < 8; j++) {
                s_ = fmaf(acc[i][j], a_s[h * 32 + coff + j], s_);
                d_ = fmaf(acc[i][j], a_d[h * 32 + coff + j], d_);
            }
            ps[i] = s_; pd[i] = d_;
        }
#pragma unroll
        for (int mk = 1; mk < 4; mk <<= 1) {
#pragma unroll
            for (int i = 0; i < 8; i++) {
                ps[i] += __shfl_xor(ps[i], mk);
                pd[i] += __shfl_xor(pd[i], mk);
            }
        }
        if ((cg & 3) == 0) {
#pragma unroll
            for (int i = 0; i < 8; i++) if (rowok[i]) {
                als[(size_t)(n0 + r0 + i) * 4 + h] = ps[i];
                ald[(size_t)(n0 + r0 + i) * 4 + h] = pd[i];
            }
        }
#pragma unroll
        for (int i = 0; i < 8; i++) if (rowok[i]) {
            size_t b = (size_t)(n0 + r0 + i) * 64 + cg * 4;
            uint4 o;
            o.x = pack_bf16(acc[i][0], acc[i][1]);
            o.y = pack_bf16(acc[i][2], acc[i][3]);
            o.z = pack_bf16(acc[i][4], acc[i][5]);
            o.w = pack_bf16(acc[i][6], acc[i][7]);
            *(uint4*)&out_bf[b] = o;
        }
    } else {
#pragma unroll
        for (int i = 0; i < 8; i++) if (rowok[i]) {
            size_t b = (size_t)(n0 + r0 + i) * 128 + c0;
            float o[8];
#pragma unroll
            for (int j = 0; j < 8; j++) o[j] = gelu_f(acc[i][j] + bias[c0 + j]);
            *(float4*)&out_f32[b]     = make_float4(o[0], o[1], o[2], o[3]);
            *(float4*)&out_f32[b + 4] = make_float4(o[4], o[5], o[6], o[7]);
        }
    }
}

// ----------------------- GAT aggregation v2 --------------------------------
// online edge-softmax + LDS-cached alpha + bf16 xh gather + gelu + LN fused.
__launch_bounds__(256)
__global__ void gat_agg2_k(const unsigned* __restrict__ xhbf, const float* __restrict__ als,
                           const float* __restrict__ ald, const int* __restrict__ col,
                           const int* __restrict__ offs, const float* __restrict__ bias,
                           const float* __restrict__ g, const float* __restrict__ be,
                           float* __restrict__ hout, int nnodes)
{
    __shared__ float alph[4][64][4];
    __shared__ int   scol[4][64];
    const int w = threadIdx.x >> 6;
    const int n = blockIdx.x * 4 + w;
    if (n >= nnodes) return;
    const int lane = threadIdx.x & 63;
    const int e0 = offs[n], e1 = offs[n + 1];
    const float4 aldv = *(const float4*)&ald[(size_t)n * 4];

    // online softmax stats, lane-strided over edges
    float m0 = -1e30f, m1 = -1e30f, m2 = -1e30f, m3 = -1e30f;
    float s0 = 0.f, s1 = 0.f, s2 = 0.f, s3 = 0.f;
    for (int i = e0 + lane; i < e1; i += 64) {
        int sv = col[i];
        float4 av = *(const float4*)&als[(size_t)sv * 4];
        float l0 = av.x + aldv.x; l0 = l0 > 0.f ? l0 : 0.2f * l0;
        float l1 = av.y + aldv.y; l1 = l1 > 0.f ? l1 : 0.2f * l1;
        float l2 = av.z + aldv.z; l2 = l2 > 0.f ? l2 : 0.2f * l2;
        float l3 = av.w + aldv.w; l3 = l3 > 0.f ? l3 : 0.2f * l3;
        float M;
        M = fmaxf(m0, l0); s0 = s0 * __expf(m0 - M) + __expf(l0 - M); m0 = M;
        M = fmaxf(m1, l1); s1 = s1 * __expf(m1 - M) + __expf(l1 - M); m1 = M;
        M = fmaxf(m2, l2); s2 = s2 * __expf(m2 - M) + __expf(l2 - M); m2 = M;
        M = fmaxf(m3, l3); s3 = s3 * __expf(m3 - M) + __expf(l3 - M); m3 = M;
    }
#pragma unroll
    for (int mk = 1; mk < 64; mk <<= 1) {
        float mo, so, M;
        mo = __shfl_xor(m0, mk); so = __shfl_xor(s0, mk);
        M = fmaxf(m0, mo); s0 = s0 * __expf(m0 - M) + so * __expf(mo - M); m0 = M;
        mo = __shfl_xor(m1, mk); so = __shfl_xor(s1, mk);
        M = fmaxf(m1, mo); s1 = s1 * __expf(m1 - M) + so * __expf(mo - M); m1 = M;
        mo = __shfl_xor(m2, mk); so = __shfl_xor(s2, mk);
        M = fmaxf(m2, mo); s2 = s2 * __expf(m2 - M) + so * __expf(mo - M); m2 = M;
        mo = __shfl_xor(m3, mk); so = __shfl_xor(s3, mk);
        M = fmaxf(m3, mo); s3 = s3 * __expf(m3 - M) + so * __expf(mo - M); m3 = M;
    }
    const float i0 = 1.f / (s0 + 1e-16f), i1 = 1.f / (s1 + 1e-16f);
    const float i2 = 1.f / (s2 + 1e-16f), i3 = 1.f / (s3 + 1e-16f);

    const int hh = lane >> 4;
    float ax = 0.f, ay = 0.f;
    for (int base = e0; base < e1; base += 64) {
        int idx = base + lane;
        if (idx < e1) {
            int sv = col[idx];
            float4 av = *(const float4*)&als[(size_t)sv * 4];
            float l0 = av.x + aldv.x; l0 = l0 > 0.f ? l0 : 0.2f * l0;
            float l1 = av.y + aldv.y; l1 = l1 > 0.f ? l1 : 0.2f * l1;
            float l2 = av.z + aldv.z; l2 = l2 > 0.f ? l2 : 0.2f * l2;
            float l3 = av.w + aldv.w; l3 = l3 > 0.f ? l3 : 0.2f * l3;
            float4 a4;
            a4.x = __expf(l0 - m0) * i0;
            a4.y = __expf(l1 - m1) * i1;
            a4.z = __expf(l2 - m2) * i2;
            a4.w = __expf(l3 - m3) * i3;
            *(float4*)&alph[w][lane][0] = a4;
            scol[w][lane] = sv;
        }
        int cnt = e1 - base; if (cnt > 64) cnt = 64;
#pragma unroll 4
        for (int j = 0; j < cnt; j++) {
            int sj = scol[w][j];
            float aj = alph[w][j][hh];
            unsigned u = xhbf[(size_t)sj * 64 + lane];
            ax = fmaf(aj, bf_lo(u), ax);
            ay = fmaf(aj, bf_hi(u), ay);
        }
    }

    const int c0 = lane * 2;
    float v0 = gelu_f(ax + bias[c0]);
    float v1 = gelu_f(ay + bias[c0 + 1]);
    float sum = v0 + v1;
#pragma unroll
    for (int mk = 32; mk >= 1; mk >>= 1) sum += __shfl_xor(sum, mk);
    float mean = sum * (1.0f / 128.0f);
    float d0 = v0 - mean, d1 = v1 - mean;
    float vs = d0 * d0 + d1 * d1;
#pragma unroll
    for (int mk = 32; mk >= 1; mk >>= 1) vs += __shfl_xor(vs, mk);
    float rstd = rsqrtf(vs * (1.0f / 128.0f) + 1e-5f);
    size_t b = (size_t)n * 128 + c0;
    hout[b]     = d0 * rstd * g[c0] + be[c0];
    hout[b + 1] = d1 * rstd * g[c0 + 1] + be[c0 + 1];
}

// ----------------------- fused RK4 ODE block -------------------------------
// one kernel for all 4 RK4 steps x 4 stages. W + bias + per-wave stage vector
// in LDS; each wave owns 8 rows, each lane 2 columns. No cross-wave sync.
__launch_bounds__(512, 1)
__global__ void ode_k(const float* __restrict__ yin, const float* __restrict__ Wn,
                      const float* __restrict__ bias, unsigned* __restrict__ ybf,
                      int nrows, int nchunks)
{
    __shared__ float Ws[128 * 128];
    __shared__ float bs[128];
    __shared__ float tl[8][8][128];
    const int t = threadIdx.x;
    for (int i = t * 8; i < 16384; i += 4096) {
        *(float4*)&Ws[i]     = *(const float4*)&Wn[i];
        *(float4*)&Ws[i + 4] = *(const float4*)&Wn[i + 4];
    }
    if (t < 128) bs[t] = bias[t];
    __syncthreads();

    const int w = t >> 6, lane = t & 63, c0 = lane * 2;
    const float b0 = bs[c0], b1 = bs[c0 + 1];
    const float dt = 0.25f;
    const float CA0 = dt / 6.f, CA1 = dt / 3.f, CA2 = dt / 3.f, CA3 = dt / 6.f;
    const float CT0 = dt * 0.5f, CT1 = dt * 0.5f, CT2 = dt;

    for (int chunk = blockIdx.x; chunk < nchunks; chunk += gridDim.x) {
        const int r0 = chunk * 64 + w * 8;
        float yv[8][2], av[8][2];
#pragma unroll
        for (int i = 0; i < 8; i++) {
            int rc = r0 + i; if (rc > nrows - 1) rc = nrows - 1;
            float2 v = *(const float2*)&yin[(size_t)rc * 128 + c0];
            yv[i][0] = v.x; yv[i][1] = v.y;
            av[i][0] = v.x; av[i][1] = v.y;
            tl[w][i][c0] = v.x; tl[w][i][c0 + 1] = v.y;
        }
        for (int step = 0; step < 4; step++) {
            for (int st = 0; st < 4; st++) {
                float z[8][2];
#pragma unroll
                for (int i = 0; i < 8; i++) { z[i][0] = b0; z[i][1] = b1; }
#pragma unroll 4
                for (int k = 0; k < 128; k += 4) {
                    float2 w0 = *(const float2*)&Ws[(k + 0) * 128 + c0];
                    float2 w1 = *(const float2*)&Ws[(k + 1) * 128 + c0];
                    float2 w2 = *(const float2*)&Ws[(k + 2) * 128 + c0];
                    float2 w3 = *(const float2*)&Ws[(k + 3) * 128 + c0];
#pragma unroll
                    for (int i = 0; i < 8; i++) {
                        float4 tv = *(const float4*)&tl[w][i][k];
                        z[i][0] = fmaf(tv.x, w0.x, z[i][0]); z[i][1] = fmaf(tv.x, w0.y, z[i][1]);
                        z[i][0] = fmaf(tv.y, w1.x, z[i][0]); z[i][1] = fmaf(tv.y, w1.y, z[i][1]);
                        z[i][0] = fmaf(tv.z, w2.x, z[i][0]); z[i][1] = fmaf(tv.z, w2.y, z[i][1]);
                        z[i][0] = fmaf(tv.w, w3.x, z[i][0]); z[i][1] = fmaf(tv.w, w3.y, z[i][1]);
                    }
                }
                if (st < 3) {
                    float ca = (st == 0) ? CA0 : (st == 1) ? CA1 : CA2;
                    float ct = (st == 0) ? CT0 : (st == 1) ? CT1 : CT2;
#pragma unroll
                    for (int i = 0; i < 8; i++) {
                        float k0 = gelu_f(z[i][0]), k1 = gelu_f(z[i][1]);
                        av[i][0] = fmaf(ca, k0, av[i][0]);
                        av[i][1] = fmaf(ca, k1, av[i][1]);
                        tl[w][i][c0]     = fmaf(ct, k0, yv[i][0]);
                        tl[w][i][c0 + 1] = fmaf(ct, k1, yv[i][1]);
                    }
                } else {
#pragma unroll
                    for (int i = 0; i < 8; i++) {
                        float k0 = gelu_f(z[i][0]), k1 = gelu_f(z[i][1]);
                        av[i][0] = fmaf(CA3, k0, av[i][0]);
                        av[i][1] = fmaf(CA3, k1, av[i][1]);
                        yv[i][0] = av[i][0]; yv[i][1] = av[i][1];
                        tl[w][i][c0]     = yv[i][0];
                        tl[w][i][c0 + 1] = yv[i][1];
                    }
                }
            }
        }
#pragma unroll
        for (int i = 0; i < 8; i++) {
            int r = r0 + i;
            if (r < nrows) ybf[(size_t)r * 64 + lane] = pack_bf16(av[i][0], av[i][1]);
        }
    }
}

// ----------------------- hop mean-aggregation (bf16) -----------------------
__launch_bounds__(256)
__global__ void hop_k(const unsigned* __restrict__ cur, const int* __restrict__ col,
                      const int* __restrict__ offs, const int* __restrict__ deg,
                      unsigned* __restrict__ outbf, int nnodes)
{
    __shared__ int scol[4][64];
    const int w = threadIdx.x >> 6;
    const int n = blockIdx.x * 4 + w;
    if (n >= nnodes) return;
    const int lane = threadIdx.x & 63;
    const int e0 = offs[n], e1 = offs[n + 1];
    float ax = 0.f, ay = 0.f;
    for (int base = e0; base < e1; base += 64) {
        int idx = base + lane;
        if (idx < e1) scol[w][lane] = col[idx];
        int cnt = e1 - base; if (cnt > 64) cnt = 64;
#pragma unroll 4
        for (int j = 0; j < cnt; j++) {
            int sj = scol[w][j];
            unsigned u = cur[(size_t)sj * 64 + lane];
            ax += bf_lo(u); ay += bf_hi(u);
        }
    }
    float dg = fmaxf((float)deg[n], 1.0f);
    outbf[(size_t)n * 64 + lane] = pack_bf16(ax / dg, ay / dg);
}

// ----------------------- hop-attention combine -----------------------------
__launch_bounds__(256)
__global__ void final2_k(const unsigned* __restrict__ s0b, const unsigned* __restrict__ s1b,
                         const unsigned* __restrict__ s2b, const unsigned* __restrict__ s3b,
                         const float* __restrict__ att, float* __restrict__ outp, int nnodes)
{
    const int n = blockIdx.x * 4 + (threadIdx.x >> 6);
    if (n >= nnodes) return;
    const int lane = threadIdx.x & 63;
    size_t b = (size_t)n * 64 + lane;
    float2 a = *(const float2*)&att[lane * 2];
    unsigned u0 = s0b[b], u1 = s1b[b], u2 = s2b[b], u3 = s3b[b];
    float p0 = bf_lo(u0) * a.x + bf_hi(u0) * a.y;
    float p1 = bf_lo(u1) * a.x + bf_hi(u1) * a.y;
    float p2 = bf_lo(u2) * a.x + bf_hi(u2) * a.y;
    float p3 = bf_lo(u3) * a.x + bf_hi(u3) * a.y;
#pragma unroll
    for (int mk = 32; mk >= 1; mk >>= 1) {
        p0 += __shfl_xor(p0, mk); p1 += __shfl_xor(p1, mk);
        p2 += __shfl_xor(p2, mk); p3 += __shfl_xor(p3, mk);
    }
    float mm = fmaxf(fmaxf(p0, p1), fmaxf(p2, p3));
    float e0 = __expf(p0 - mm), e1 = __expf(p1 - mm), e2 = __expf(p2 - mm), e3 = __expf(p3 - mm);
    float inv = 1.0f / (e0 + e1 + e2 + e3);
    float w0 = e0 * inv, w1 = e1 * inv, w2 = e2 * inv, w3 = e3 * inv;
    float ox = w0 * bf_lo(u0) + w1 * bf_lo(u1) + w2 * bf_lo(u2) + w3 * bf_lo(u3);
    float oy = w0 * bf_hi(u0) + w1 * bf_hi(u1) + w2 * bf_hi(u2) + w3 * bf_hi(u3);
    *(float2*)&outp[(size_t)n * 128 + lane * 2] = make_float2(ox, oy);
}

// ---------------------------------------------------------------------------
extern "C" void kernel_launch(void* const* d_in, const int* in_sizes, int n_in,
                              void* d_out, int out_size, void* d_ws, size_t ws_size,
                              hipStream_t stream)
{
    const float* x     = (const float*)d_in[0];
    const int*   ei    = (const int*)d_in[1];
    const float* W_in  = (const float*)d_in[2];
    const float* b_in  = (const float*)d_in[3];
    const float* W1    = (const float*)d_in[4];
    const float* a_s1  = (const float*)d_in[5];
    const float* a_d1  = (const float*)d_in[6];
    const float* b1    = (const float*)d_in[7];
    const float* W2    = (const float*)d_in[8];
    const float* a_s2  = (const float*)d_in[9];
    const float* a_d2  = (const float*)d_in[10];
    const float* b2    = (const float*)d_in[11];
    const float* g1    = (const float*)d_in[12];
    const float* be1   = (const float*)d_in[13];
    const float* g2    = (const float*)d_in[14];
    const float* be2   = (const float*)d_in[15];
    const float* W_ode = (const float*)d_in[16];
    const float* b_ode = (const float*)d_in[17];
    const float* att   = (const float*)d_in[18];

    const int N = in_sizes[0] / 128;
    const int E = in_sizes[1] / 2;
    const int* srcv = ei;
    const int* dstv = ei + E;

    char* wsb = (char*)d_ws;
    size_t off = 0;
    auto alloc = [&](size_t bytes) -> void* {
        void* p = wsb + off;
        off = (off + bytes + 511) & ~(size_t)511;
        return p;
    };
    float*    WnIn   = (float*)alloc(65536);
    float*    WnOde  = (float*)alloc(65536);
    float*    als    = (float*)alloc((size_t)N * 4 * 4);
    float*    ald    = (float*)alloc((size_t)N * 4 * 4);
    int*      deg    = (int*)alloc((size_t)N * 4);
    int*      cursor = (int*)alloc((size_t)N * 4);
    int*      offs   = (int*)alloc((size_t)(N + 1) * 4);
    int*      col    = (int*)alloc((size_t)E * 4);
    float*    B0     = (float*)alloc((size_t)N * 128 * 4);   // fp32 activations
    unsigned* xhbf   = (unsigned*)alloc((size_t)N * 64 * 4); // bf16 xh / hop1
    unsigned* ybf    = (unsigned*)alloc((size_t)N * 64 * 4); // bf16 ODE out
    unsigned* h2bf   = (unsigned*)alloc((size_t)N * 64 * 4);
    unsigned* h3bf   = (unsigned*)alloc((size_t)N * 64 * 4);

    (void)hipMemsetAsync(deg, 0, (size_t)N * 4, stream);
    (void)hipMemsetAsync(cursor, 0, (size_t)N * 4, stream);

    sn_k<<<2, 128, 0, stream>>>(W_in, W_ode, WnIn, WnOde);
    hist_k<<<(E + 255) / 256, 256, 0, stream>>>(dstv, deg, E, N);
    scan_k<<<1, 1024, 0, stream>>>(deg, offs, N);
    scatter_k<<<(E + 255) / 256, 256, 0, stream>>>(srcv, dstv, offs, cursor, col, E, N);

    const int gblocks = (N + 127) / 128;
    const int ablocks = (N + 3) / 4;

    // input layer: B0 = gelu(x @ sn(W_in) + b_in)
    gemm128_k<<<gblocks, 256, 0, stream>>>(x, WnIn, b_in, B0, nullptr, N, 1,
        nullptr, nullptr, nullptr, nullptr);

    // GAT layer 1
    gemm128_k<<<gblocks, 256, 0, stream>>>(B0, W1, nullptr, nullptr, xhbf, N, 0,
        a_s1, a_d1, als, ald);
    gat_agg2_k<<<ablocks, 256, 0, stream>>>(xhbf, als, ald, col, offs, b1, g1, be1, B0, N);

    // GAT layer 2
    gemm128_k<<<gblocks, 256, 0, stream>>>(B0, W2, nullptr, nullptr, xhbf, N, 0,
        a_s2, a_d2, als, ald);
    gat_agg2_k<<<ablocks, 256, 0, stream>>>(xhbf, als, ald, col, offs, b2, g2, be2, B0, N);

    // fused RK4 ODE: B0 -> ybf (bf16)
    const int nchunks = (N + 63) / 64;
    ode_k<<<256, 512, 0, stream>>>(B0, WnOde, b_ode, ybf, N, nchunks);

    // 3-hop mean broadcast (bf16 stack) + attention combine
    hop_k<<<ablocks, 256, 0, stream>>>(ybf,  col, offs, deg, xhbf, N);  // hop1
    hop_k<<<ablocks, 256, 0, stream>>>(xhbf, col, offs, deg, h2bf, N);  // hop2
    hop_k<<<ablocks, 256, 0, stream>>>(h2bf, col, offs, deg, h3bf, N);  // hop3
    final2_k<<<ablocks, 256, 0, stream>>>(ybf, xhbf, h2bf, h3bf, att, (float*)d_out, N);
}

// Round 3
// 1151.140 us; speedup vs baseline: 1.8843x; 1.2884x over previous
//
#include <hip/hip_runtime.h>
#include <math.h>

// ---------------------------------------------------------------------------
// TemporalGraphEncoder: N=50000, E=1.6M, D=128, H=4, C=32, HOPS=3
// r3: ODE block rewritten on bf16 MFMA (mfma_f32_32x32x16_bf16), W^T + per-wave
//     t-buffer in XOR-swizzled LDS, RK4 state (y, acc) fp32 in registers.
// ---------------------------------------------------------------------------

typedef __attribute__((ext_vector_type(8)))  short bf16x8;
typedef __attribute__((ext_vector_type(16))) float f32x16;

__device__ __forceinline__ float gelu_f(float x) {
    return 0.5f * x * (1.0f + erff(x * 0.70710678118654752f));
}
__device__ __forceinline__ unsigned pack_bf16(float a, float b) {
    unsigned ua = __float_as_uint(a), ub = __float_as_uint(b);
    ua += 0x7fffu + ((ua >> 16) & 1u);
    ub += 0x7fffu + ((ub >> 16) & 1u);
    return (ua >> 16) | (ub & 0xffff0000u);
}
__device__ __forceinline__ unsigned short bfbits(float x) {
    unsigned u = __float_as_uint(x);
    u += 0x7fffu + ((u >> 16) & 1u);
    return (unsigned short)(u >> 16);
}
__device__ __forceinline__ float bf_lo(unsigned u) { return __uint_as_float(u << 16); }
__device__ __forceinline__ float bf_hi(unsigned u) { return __uint_as_float(u & 0xffff0000u); }
// swizzle for 256B-row-stride LDS tiles (breaks same-bank column reads; 16B granule)
__device__ __forceinline__ int swz(int byte) { return byte ^ (((byte >> 8) & 15) << 4); }

// ---------------------- spectral norm (power iteration) --------------------
__launch_bounds__(128, 1)
__global__ void sn_k(const float* __restrict__ Win, const float* __restrict__ Wode,
                     float* __restrict__ WnIn, float* __restrict__ WnOde)
{
    __shared__ float Ws[128 * 128];
    __shared__ float Wt[128 * 128];
    __shared__ float red[128];
    const float* W  = (blockIdx.x == 0) ? Win  : Wode;
    float*       Wn = (blockIdx.x == 0) ? WnIn : WnOde;
    const int t = threadIdx.x;

    for (int i = t * 4; i < 16384; i += 512) {
        float4 v = *(const float4*)&W[i];
        *(float4*)&Ws[i] = v;
        int r = i >> 7, c = i & 127;
        Wt[(c + 0) * 128 + r] = v.x;
        Wt[(c + 1) * 128 + r] = v.y;
        Wt[(c + 2) * 128 + r] = v.z;
        Wt[(c + 3) * 128 + r] = v.w;
    }
    __syncthreads();

    float u = 0.088388347648318447f;  // 1/sqrt(128)
    float v = 0.0f;
    for (int it = 0; it < 5; it++) {
        red[t] = u; __syncthreads();
        float vv = 0.f;
        for (int i = 0; i < 128; i++) vv = fmaf(Ws[i * 128 + t], red[i], vv);
        __syncthreads();
        red[t] = vv * vv; __syncthreads();
        for (int s = 64; s > 0; s >>= 1) { if (t < s) red[t] += red[t + s]; __syncthreads(); }
        float nv = sqrtf(red[0]) + 1e-12f;
        v = vv / nv;
        __syncthreads();
        red[t] = v; __syncthreads();
        float uu = 0.f;
        for (int i = 0; i < 128; i++) uu = fmaf(Wt[i * 128 + t], red[i], uu);
        __syncthreads();
        red[t] = uu * uu; __syncthreads();
        for (int s = 64; s > 0; s >>= 1) { if (t < s) red[t] += red[t + s]; __syncthreads(); }
        float nu = sqrtf(red[0]) + 1e-12f;
        u = uu / nu;
        __syncthreads();
    }
    red[t] = v; __syncthreads();
    float wv = 0.f;
    for (int i = 0; i < 128; i++) wv = fmaf(Wt[i * 128 + t], red[i], wv);
    __syncthreads();
    red[t] = u * wv; __syncthreads();
    for (int s = 64; s > 0; s >>= 1) { if (t < s) red[t] += red[t + s]; __syncthreads(); }
    float inv = 1.0f / (red[0] + 1e-12f);
    __syncthreads();
    for (int i = t * 4; i < 16384; i += 512) {
        float4 w = *(const float4*)&Ws[i];
        w.x *= inv; w.y *= inv; w.z *= inv; w.w *= inv;
        *(float4*)&Wn[i] = w;
    }
}

// ------------------------------ CSR build ----------------------------------
__global__ void hist_k(const int* __restrict__ dst, int* __restrict__ deg, int E, int N)
{
    int e = blockIdx.x * blockDim.x + threadIdx.x;
    if (e < E) {
        int d = dst[e];
        d = (d < 0) ? 0 : (d >= N ? N - 1 : d);
        atomicAdd(&deg[d], 1);
    }
}

__launch_bounds__(1024, 1)
__global__ void scan_k(const int* __restrict__ deg, int* __restrict__ offs, int n)
{
    __shared__ int part[1024];
    const int t = threadIdx.x;
    const int chunk = (n + 1023) >> 10;
    int lo = t * chunk; if (lo > n) lo = n;
    int hi = lo + chunk; if (hi > n) hi = n;
    int s = 0;
    for (int i = lo; i < hi; i++) s += deg[i];
    part[t] = s; __syncthreads();
    for (int d = 1; d < 1024; d <<= 1) {
        int v = (t >= d) ? part[t - d] : 0;
        __syncthreads();
        part[t] += v;
        __syncthreads();
    }
    int run = (t == 0) ? 0 : part[t - 1];
    for (int i = lo; i < hi; i++) { offs[i] = run; run += deg[i]; }
    if (t == 1023) offs[n] = run;
}

__global__ void scatter_k(const int* __restrict__ src, const int* __restrict__ dst,
                          const int* __restrict__ offs, int* __restrict__ cursor,
                          int* __restrict__ col, int E, int N)
{
    int e = blockIdx.x * blockDim.x + threadIdx.x;
    if (e < E) {
        int d = dst[e];
        d = (d < 0) ? 0 : (d >= N ? N - 1 : d);
        int s = src[e];
        s = (s < 0) ? 0 : (s >= N ? N - 1 : s);
        int pos = offs[d] + atomicAdd(&cursor[d], 1);
        col[pos] = s;
    }
}

// ------------------------------ GEMM 128 (fp32 VALU) -----------------------
// mode 0: xh = in@W -> bf16 out_bf + fused al_s/al_d head reductions (fp32)
// mode 1: out_f32 = gelu(in@W + bias)
__launch_bounds__(256, 2)
__global__ void gemm128_k(const float* __restrict__ in, const float* __restrict__ W,
                          const float* __restrict__ bias, float* __restrict__ out_f32,
                          unsigned* __restrict__ out_bf, int nrows, int mode,
                          const float* __restrict__ a_s, const float* __restrict__ a_d,
                          float* __restrict__ als, float* __restrict__ ald)
{
    __shared__ float Ws[128 * 128];
    const int t = threadIdx.x;
    const int n0 = blockIdx.x * 128;

    for (int i = t * 4; i < 16384; i += 1024)
        *(float4*)&Ws[i] = *(const float4*)&W[i];
    __syncthreads();

    const int cg = t & 15, rg = t >> 4;
    const int c0 = cg * 8, r0 = rg * 8;

    const float* xrow[8];
    bool rowok[8];
#pragma unroll
    for (int i = 0; i < 8; i++) {
        int r = n0 + r0 + i;
        rowok[i] = (r < nrows);
        int rc = rowok[i] ? r : (nrows - 1);
        xrow[i] = in + (size_t)rc * 128;
    }

    float acc[8][8];
#pragma unroll
    for (int i = 0; i < 8; i++)
#pragma unroll
        for (int j = 0; j < 8; j++) acc[i][j] = 0.f;

    for (int k = 0; k < 128; k += 4) {
        float4 xv[8];
#pragma unroll
        for (int i = 0; i < 8; i++) xv[i] = *(const float4*)(xrow[i] + k);
#pragma unroll
        for (int kk = 0; kk < 4; kk++) {
            float4 w0 = *(const float4*)&Ws[(k + kk) * 128 + c0];
            float4 w1 = *(const float4*)&Ws[(k + kk) * 128 + c0 + 4];
#pragma unroll
            for (int i = 0; i < 8; i++) {
                float xk = (kk == 0) ? xv[i].x : (kk == 1) ? xv[i].y : (kk == 2) ? xv[i].z : xv[i].w;
                acc[i][0] = fmaf(xk, w0.x, acc[i][0]);
                acc[i][1] = fmaf(xk, w0.y, acc[i][1]);
                acc[i][2] = fmaf(xk, w0.z, acc[i][2]);
                acc[i][3] = fmaf(xk, w0.w, acc[i][3]);
                acc[i][4] = fmaf(xk, w1.x, acc[i][4]);
                acc[i][5] = fmaf(xk, w1.y, acc[i][5]);
                acc[i][6] = fmaf(xk, w1.z, acc[i][6]);
                acc[i][7] = fmaf(xk, w1.w, acc[i][7]);
            }
        }
    }

    if (mode == 0) {
        const int h = cg >> 2, coff = (cg & 3) * 8;
        float ps[8], pd[8];
#pragma unroll
        for (int i = 0; i < 8; i++) {
            float s_ = 0.f, d_ = 0.f;
#pragma unroll
            for (int j = 0; j < 8; j++) {
                s_ = fmaf(acc[i][j], a_s[h * 32 + coff + j], s_);
                d_ = fmaf(acc[i][j], a_d[h * 32 + coff + j], d_);
            }
            ps[i] = s_; pd[i] = d_;
        }
#pragma unroll
        for (int mk = 1; mk < 4; mk <<= 1) {
#pragma unroll
            for (int i = 0; i < 8; i++) {
                ps[i] += __shfl_xor(ps[i], mk);
                pd[i] += __shfl_xor(pd[i], mk);
            }
        }
        if ((cg & 3) == 0) {
#pragma unroll
            for (int i = 0; i < 8; i++) if (rowok[i]) {
                als[(size_t)(n0 + r0 + i) * 4 + h] = ps[i];
                ald[(size_t)(n0 + r0 + i) * 4 + h] = pd[i];
            }
        }
#pragma unroll
        for (int i = 0; i < 8; i++) if (rowok[i]) {
            size_t b = (size_t)(n0 + r0 + i) * 64 + cg * 4;
            uint4 o;
            o.x = pack_bf16(acc[i][0], acc[i][1]);
            o.y = pack_bf16(acc[i][2], acc[i][3]);
            o.z = pack_bf16(acc[i][4], acc[i][5]);
            o.w = pack_bf16(acc[i][6], acc[i][7]);
            *(uint4*)&out_bf[b] = o;
        }
    } else {
#pragma unroll
        for (int i = 0; i < 8; i++) if (rowok[i]) {
            size_t b = (size_t)(n0 + r0 + i) * 128 + c0;
            float o[8];
#pragma unroll
            for (int j = 0; j < 8; j++) o[j] = gelu_f(acc[i][j] + bias[c0 + j]);
            *(float4*)&out_f32[b]     = make_float4(o[0], o[1], o[2], o[3]);
            *(float4*)&out_f32[b + 4] = make_float4(o[4], o[5], o[6], o[7]);
        }
    }
}

// ----------------------- GAT aggregation v2 --------------------------------
__launch_bounds__(256)
__global__ void gat_agg2_k(const unsigned* __restrict__ xhbf, const float* __restrict__ als,
                           const float* __restrict__ ald, const int* __restrict__ col,
                           const int* __restrict__ offs, const float* __restrict__ bias,
                           const float* __restrict__ g, const float* __restrict__ be,
                           float* __restrict__ hout, int nnodes)
{
    __shared__ float alph[4][64][4];
    __shared__ int   scol[4][64];
    const int w = threadIdx.x >> 6;
    const int n = blockIdx.x * 4 + w;
    if (n >= nnodes) return;
    const int lane = threadIdx.x & 63;
    const int e0 = offs[n], e1 = offs[n + 1];
    const float4 aldv = *(const float4*)&ald[(size_t)n * 4];

    float m0 = -1e30f, m1 = -1e30f, m2 = -1e30f, m3 = -1e30f;
    float s0 = 0.f, s1 = 0.f, s2 = 0.f, s3 = 0.f;
    for (int i = e0 + lane; i < e1; i += 64) {
        int sv = col[i];
        float4 av = *(const float4*)&als[(size_t)sv * 4];
        float l0 = av.x + aldv.x; l0 = l0 > 0.f ? l0 : 0.2f * l0;
        float l1 = av.y + aldv.y; l1 = l1 > 0.f ? l1 : 0.2f * l1;
        float l2 = av.z + aldv.z; l2 = l2 > 0.f ? l2 : 0.2f * l2;
        float l3 = av.w + aldv.w; l3 = l3 > 0.f ? l3 : 0.2f * l3;
        float M;
        M = fmaxf(m0, l0); s0 = s0 * __expf(m0 - M) + __expf(l0 - M); m0 = M;
        M = fmaxf(m1, l1); s1 = s1 * __expf(m1 - M) + __expf(l1 - M); m1 = M;
        M = fmaxf(m2, l2); s2 = s2 * __expf(m2 - M) + __expf(l2 - M); m2 = M;
        M = fmaxf(m3, l3); s3 = s3 * __expf(m3 - M) + __expf(l3 - M); m3 = M;
    }
#pragma unroll
    for (int mk = 1; mk < 64; mk <<= 1) {
        float mo, so, M;
        mo = __shfl_xor(m0, mk); so = __shfl_xor(s0, mk);
        M = fmaxf(m0, mo); s0 = s0 * __expf(m0 - M) + so * __expf(mo - M); m0 = M;
        mo = __shfl_xor(m1, mk); so = __shfl_xor(s1, mk);
        M = fmaxf(m1, mo); s1 = s1 * __expf(m1 - M) + so * __expf(mo - M); m1 = M;
        mo = __shfl_xor(m2, mk); so = __shfl_xor(s2, mk);
        M = fmaxf(m2, mo); s2 = s2 * __expf(m2 - M) + so * __expf(mo - M); m2 = M;
        mo = __shfl_xor(m3, mk); so = __shfl_xor(s3, mk);
        M = fmaxf(m3, mo); s3 = s3 * __expf(m3 - M) + so * __expf(mo - M); m3 = M;
    }
    const float i0 = 1.f / (s0 + 1e-16f), i1 = 1.f / (s1 + 1e-16f);
    const float i2 = 1.f / (s2 + 1e-16f), i3 = 1.f / (s3 + 1e-16f);

    const int hh = lane >> 4;
    float ax = 0.f, ay = 0.f;
    for (int base = e0; base < e1; base += 64) {
        int idx = base + lane;
        if (idx < e1) {
            int sv = col[idx];
            float4 av = *(const float4*)&als[(size_t)sv * 4];
            float l0 = av.x + aldv.x; l0 = l0 > 0.f ? l0 : 0.2f * l0;
            float l1 = av.y + aldv.y; l1 = l1 > 0.f ? l1 : 0.2f * l1;
            float l2 = av.z + aldv.z; l2 = l2 > 0.f ? l2 : 0.2f * l2;
            float l3 = av.w + aldv.w; l3 = l3 > 0.f ? l3 : 0.2f * l3;
            float4 a4;
            a4.x = __expf(l0 - m0) * i0;
            a4.y = __expf(l1 - m1) * i1;
            a4.z = __expf(l2 - m2) * i2;
            a4.w = __expf(l3 - m3) * i3;
            *(float4*)&alph[w][lane][0] = a4;
            scol[w][lane] = sv;
        }
        int cnt = e1 - base; if (cnt > 64) cnt = 64;
#pragma unroll 4
        for (int j = 0; j < cnt; j++) {
            int sj = scol[w][j];
            float aj = alph[w][j][hh];
            unsigned u = xhbf[(size_t)sj * 64 + lane];
            ax = fmaf(aj, bf_lo(u), ax);
            ay = fmaf(aj, bf_hi(u), ay);
        }
    }

    const int c0 = lane * 2;
    float v0 = gelu_f(ax + bias[c0]);
    float v1 = gelu_f(ay + bias[c0 + 1]);
    float sum = v0 + v1;
#pragma unroll
    for (int mk = 32; mk >= 1; mk >>= 1) sum += __shfl_xor(sum, mk);
    float mean = sum * (1.0f / 128.0f);
    float d0 = v0 - mean, d1 = v1 - mean;
    float vs = d0 * d0 + d1 * d1;
#pragma unroll
    for (int mk = 32; mk >= 1; mk >>= 1) vs += __shfl_xor(vs, mk);
    float rstd = rsqrtf(vs * (1.0f / 128.0f) + 1e-5f);
    size_t b = (size_t)n * 128 + c0;
    hout[b]     = d0 * rstd * g[c0] + be[c0];
    hout[b + 1] = d1 * rstd * g[c0 + 1] + be[c0 + 1];
}

// ----------------------- fused RK4 ODE block (bf16 MFMA) -------------------
// Block: 256 threads = 4 waves. LDS: W^T bf16 swizzled (32KB) + bias +
// per-wave 32x128 bf16 t-buffer (8KB each). Each wave: one 32-row chunk,
// all 16 RK4 stages; z = t@W via mfma_f32_32x32x16_bf16; y/acc fp32 in regs.
// C/D layout: col = lane&31, row = (reg&3)+8*(reg>>2)+4*(lane>>5).
// A frag: row = lane&31, k = (lane>>5)*8 + 0..7 (contiguous, b128 from LDS).
// B frag: col = lane&31 -> W^T row, same k pattern.
__launch_bounds__(256, 2)
__global__ void ode_mfma_k(const float* __restrict__ yin, const float* __restrict__ Wn,
                           const float* __restrict__ bias, unsigned short* __restrict__ ybf,
                           int nrows, int nchunks)
{
    __shared__ unsigned short Wt[128 * 128];     // [c][k] bf16, swizzled
    __shared__ float bs[128];
    __shared__ unsigned short tl[4][32 * 128];   // per-wave [r][k] bf16, swizzled
    const int t = threadIdx.x;
    const int w = t >> 6, lane = t & 63;
    const int cl = lane & 31, lh = lane >> 5;

    // stage W^T (bf16, swizzled): read W[k][c] coalesced, scatter b16
    for (int i = t; i < 16384; i += 256) {
        int k = i >> 7, c = i & 127;
        float v = Wn[i];
        *(unsigned short*)((char*)Wt + swz((c << 8) + (k << 1))) = bfbits(v);
    }
    if (t < 128) bs[t] = bias[t];
    __syncthreads();

    float bcol[4];
#pragma unroll
    for (int n = 0; n < 4; n++) bcol[n] = bs[n * 32 + cl];

    const float dt = 0.25f;
    char* tbase = (char*)&tl[w][0];

    for (int chunk = blockIdx.x * 4 + w; chunk < nchunks; chunk += gridDim.x * 4) {
        const int r0 = chunk * 32;
        // stage y rows -> t-buffer (bf16, swizzled)
        for (int g = lane; g < 1024; g += 64) {
            int r = g >> 5, k0 = (g & 31) * 4;
            int rc = r0 + r; if (rc > nrows - 1) rc = nrows - 1;
            float4 v = *(const float4*)&yin[(size_t)rc * 128 + k0];
            unsigned lo = pack_bf16(v.x, v.y);
            unsigned hi = pack_bf16(v.z, v.w);
            *(uint2*)(tbase + swz(r * 256 + k0 * 2)) = make_uint2(lo, hi);
        }
        // y state fp32, C-layout (per-lane 4 tiles x 16 regs)
        float yv[4][16], av[4][16];
#pragma unroll
        for (int q = 0; q < 16; q++) {
            int rr = (q & 3) + 8 * (q >> 2) + 4 * lh;
            int rc = r0 + rr; if (rc > nrows - 1) rc = nrows - 1;
            const float* rp = &yin[(size_t)rc * 128 + cl];
#pragma unroll
            for (int n = 0; n < 4; n++) { yv[n][q] = rp[n * 32]; av[n][q] = yv[n][q]; }
        }

#pragma unroll 1
        for (int step = 0; step < 4; step++) {
#pragma unroll 1
            for (int st = 0; st < 4; st++) {
                const float ca = (st == 0 || st == 3) ? dt / 6.f : dt / 3.f;
                const float ct = (st < 2) ? dt * 0.5f : dt;
                const bool last = (st == 3);
                // A fragments for all 8 K-steps (held across n-tiles)
                bf16x8 af[8];
#pragma unroll
                for (int ks = 0; ks < 8; ks++)
                    af[ks] = *(const bf16x8*)(tbase + swz(cl * 256 + ks * 32 + lh * 16));
#pragma unroll
                for (int n = 0; n < 4; n++) {
                    f32x16 acc;
#pragma unroll
                    for (int q = 0; q < 16; q++) acc[q] = 0.f;
#pragma unroll
                    for (int ks = 0; ks < 8; ks++) {
                        bf16x8 bf = *(const bf16x8*)((char*)Wt +
                                      swz((n * 32 + cl) * 256 + ks * 32 + lh * 16));
                        acc = __builtin_amdgcn_mfma_f32_32x32x16_bf16(af[ks], bf, acc, 0, 0, 0);
                    }
#pragma unroll
                    for (int q = 0; q < 16; q++) {
                        float kk = gelu_f(acc[q] + bcol[n]);
                        av[n][q] = fmaf(ca, kk, av[n][q]);
                        float tn;
                        if (last) { yv[n][q] = av[n][q]; tn = av[n][q]; }
                        else      { tn = fmaf(ct, kk, yv[n][q]); }
                        int rr = (q & 3) + 8 * (q >> 2) + 4 * lh;
                        *(unsigned short*)(tbase + swz(rr * 256 + (n * 32 + cl) * 2)) = bfbits(tn);
                    }
                }
            }
        }
        // final store: av -> ybf (bf16 scalar stores, ushort[row][128])
#pragma unroll
        for (int q = 0; q < 16; q++) {
            int rr = (q & 3) + 8 * (q >> 2) + 4 * lh;
            int rg = r0 + rr;
            if (rg < nrows) {
#pragma unroll
                for (int n = 0; n < 4; n++)
                    ybf[(size_t)rg * 128 + n * 32 + cl] = bfbits(av[n][q]);
            }
        }
    }
}

// ----------------------- hop mean-aggregation (bf16) -----------------------
__launch_bounds__(256)
__global__ void hop_k(const unsigned* __restrict__ cur, const int* __restrict__ col,
                      const int* __restrict__ offs, const int* __restrict__ deg,
                      unsigned* __restrict__ outbf, int nnodes)
{
    __shared__ int scol[4][64];
    const int w = threadIdx.x >> 6;
    const int n = blockIdx.x * 4 + w;
    if (n >= nnodes) return;
    const int lane = threadIdx.x & 63;
    const int e0 = offs[n], e1 = offs[n + 1];
    float ax = 0.f, ay = 0.f;
    for (int base = e0; base < e1; base += 64) {
        int idx = base + lane;
        if (idx < e1) scol[w][lane] = col[idx];
        int cnt = e1 - base; if (cnt > 64) cnt = 64;
#pragma unroll 4
        for (int j = 0; j < cnt; j++) {
            int sj = scol[w][j];
            unsigned u = cur[(size_t)sj * 64 + lane];
            ax += bf_lo(u); ay += bf_hi(u);
        }
    }
    float dg = fmaxf((float)deg[n], 1.0f);
    outbf[(size_t)n * 64 + lane] = pack_bf16(ax / dg, ay / dg);
}

// ----------------------- hop-attention combine -----------------------------
__launch_bounds__(256)
__global__ void final2_k(const unsigned* __restrict__ s0b, const unsigned* __restrict__ s1b,
                         const unsigned* __restrict__ s2b, const unsigned* __restrict__ s3b,
                         const float* __restrict__ att, float* __restrict__ outp, int nnodes)
{
    const int n = blockIdx.x * 4 + (threadIdx.x >> 6);
    if (n >= nnodes) return;
    const int lane = threadIdx.x & 63;
    size_t b = (size_t)n * 64 + lane;
    float2 a = *(const float2*)&att[lane * 2];
    unsigned u0 = s0b[b], u1 = s1b[b], u2 = s2b[b], u3 = s3b[b];
    float p0 = bf_lo(u0) * a.x + bf_hi(u0) * a.y;
    float p1 = bf_lo(u1) * a.x + bf_hi(u1) * a.y;
    float p2 = bf_lo(u2) * a.x + bf_hi(u2) * a.y;
    float p3 = bf_lo(u3) * a.x + bf_hi(u3) * a.y;
#pragma unroll
    for (int mk = 32; mk >= 1; mk >>= 1) {
        p0 += __shfl_xor(p0, mk); p1 += __shfl_xor(p1, mk);
        p2 += __shfl_xor(p2, mk); p3 += __shfl_xor(p3, mk);
    }
    float mm = fmaxf(fmaxf(p0, p1), fmaxf(p2, p3));
    float e0 = __expf(p0 - mm), e1 = __expf(p1 - mm), e2 = __expf(p2 - mm), e3 = __expf(p3 - mm);
    float inv = 1.0f / (e0 + e1 + e2 + e3);
    float w0 = e0 * inv, w1 = e1 * inv, w2 = e2 * inv, w3 = e3 * inv;
    float ox = w0 * bf_lo(u0) + w1 * bf_lo(u1) + w2 * bf_lo(u2) + w3 * bf_lo(u3);
    float oy = w0 * bf_hi(u0) + w1 * bf_hi(u1) + w2 * bf_hi(u2) + w3 * bf_hi(u3);
    *(float2*)&outp[(size_t)n * 128 + lane * 2] = make_float2(ox, oy);
}

// ---------------------------------------------------------------------------
extern "C" void kernel_launch(void* const* d_in, const int* in_sizes, int n_in,
                              void* d_out, int out_size, void* d_ws, size_t ws_size,
                              hipStream_t stream)
{
    const float* x     = (const float*)d_in[0];
    const int*   ei    = (const int*)d_in[1];
    const float* W_in  = (const float*)d_in[2];
    const float* b_in  = (const float*)d_in[3];
    const float* W1    = (const float*)d_in[4];
    const float* a_s1  = (const float*)d_in[5];
    const float* a_d1  = (const float*)d_in[6];
    const float* b1    = (const float*)d_in[7];
    const float* W2    = (const float*)d_in[8];
    const float* a_s2  = (const float*)d_in[9];
    const float* a_d2  = (const float*)d_in[10];
    const float* b2    = (const float*)d_in[11];
    const float* g1    = (const float*)d_in[12];
    const float* be1   = (const float*)d_in[13];
    const float* g2    = (const float*)d_in[14];
    const float* be2   = (const float*)d_in[15];
    const float* W_ode = (const float*)d_in[16];
    const float* b_ode = (const float*)d_in[17];
    const float* att   = (const float*)d_in[18];

    const int N = in_sizes[0] / 128;
    const int E = in_sizes[1] / 2;
    const int* srcv = ei;
    const int* dstv = ei + E;

    char* wsb = (char*)d_ws;
    size_t off = 0;
    auto alloc = [&](size_t bytes) -> void* {
        void* p = wsb + off;
        off = (off + bytes + 511) & ~(size_t)511;
        return p;
    };
    float*    WnIn   = (float*)alloc(65536);
    float*    WnOde  = (float*)alloc(65536);
    float*    als    = (float*)alloc((size_t)N * 4 * 4);
    float*    ald    = (float*)alloc((size_t)N * 4 * 4);
    int*      deg    = (int*)alloc((size_t)N * 4);
    int*      cursor = (int*)alloc((size_t)N * 4);
    int*      offs   = (int*)alloc((size_t)(N + 1) * 4);
    int*      col    = (int*)alloc((size_t)E * 4);
    float*    B0     = (float*)alloc((size_t)N * 128 * 4);   // fp32 activations
    unsigned* xhbf   = (unsigned*)alloc((size_t)N * 64 * 4); // bf16 xh / hop1
    unsigned* ybf    = (unsigned*)alloc((size_t)N * 64 * 4); // bf16 ODE out
    unsigned* h2bf   = (unsigned*)alloc((size_t)N * 64 * 4);
    unsigned* h3bf   = (unsigned*)alloc((size_t)N * 64 * 4);

    (void)hipMemsetAsync(deg, 0, (size_t)N * 4, stream);
    (void)hipMemsetAsync(cursor, 0, (size_t)N * 4, stream);

    sn_k<<<2, 128, 0, stream>>>(W_in, W_ode, WnIn, WnOde);
    hist_k<<<(E + 255) / 256, 256, 0, stream>>>(dstv, deg, E, N);
    scan_k<<<1, 1024, 0, stream>>>(deg, offs, N);
    scatter_k<<<(E + 255) / 256, 256, 0, stream>>>(srcv, dstv, offs, cursor, col, E, N);

    const int gblocks = (N + 127) / 128;
    const int ablocks = (N + 3) / 4;

    // input layer: B0 = gelu(x @ sn(W_in) + b_in)
    gemm128_k<<<gblocks, 256, 0, stream>>>(x, WnIn, b_in, B0, nullptr, N, 1,
        nullptr, nullptr, nullptr, nullptr);

    // GAT layer 1
    gemm128_k<<<gblocks, 256, 0, stream>>>(B0, W1, nullptr, nullptr, xhbf, N, 0,
        a_s1, a_d1, als, ald);
    gat_agg2_k<<<ablocks, 256, 0, stream>>>(xhbf, als, ald, col, offs, b1, g1, be1, B0, N);

    // GAT layer 2
    gemm128_k<<<gblocks, 256, 0, stream>>>(B0, W2, nullptr, nullptr, xhbf, N, 0,
        a_s2, a_d2, als, ald);
    gat_agg2_k<<<ablocks, 256, 0, stream>>>(xhbf, als, ald, col, offs, b2, g2, be2, B0, N);

    // fused RK4 ODE (bf16 MFMA): B0 -> ybf
    const int nchunks = (N + 31) / 32;
    const int oblocks = (nchunks + 3) / 4;
    ode_mfma_k<<<oblocks, 256, 0, stream>>>(B0, WnOde, b_ode, (unsigned short*)ybf, N, nchunks);

    // 3-hop mean broadcast (bf16 stack) + attention combine
    hop_k<<<ablocks, 256, 0, stream>>>(ybf,  col, offs, deg, xhbf, N);  // hop1
    hop_k<<<ablocks, 256, 0, stream>>>(xhbf, col, offs, deg, h2bf, N);  // hop2
    hop_k<<<ablocks, 256, 0, stream>>>(h2bf, col, offs, deg, h3bf, N);  // hop3
    final2_k<<<ablocks, 256, 0, stream>>>(ybf, xhbf, h2bf, h3bf, att, (float*)d_out, N);
}

// Round 4
// 1051.626 us; speedup vs baseline: 2.0626x; 1.0946x over previous
//
#include <hip/hip_runtime.h>
#include <math.h>

// ---------------------------------------------------------------------------
// TemporalGraphEncoder: N=50000, E=1.6M, D=128, H=4, C=32, HOPS=3
// r4: ODE MFMA kernel reworked to 16-row chunks + mfma_f32_16x16x32_bf16 so
//     RK4 state fits in VGPRs (r3 spilled ~290MB to scratch: FETCH 340MB).
// ---------------------------------------------------------------------------

typedef __attribute__((ext_vector_type(8))) short bf16x8;
typedef __attribute__((ext_vector_type(4))) float f32x4;

__device__ __forceinline__ float gelu_f(float x) {
    return 0.5f * x * (1.0f + erff(x * 0.70710678118654752f));
}
__device__ __forceinline__ unsigned pack_bf16(float a, float b) {
    unsigned ua = __float_as_uint(a), ub = __float_as_uint(b);
    ua += 0x7fffu + ((ua >> 16) & 1u);
    ub += 0x7fffu + ((ub >> 16) & 1u);
    return (ua >> 16) | (ub & 0xffff0000u);
}
__device__ __forceinline__ unsigned short bfbits(float x) {
    unsigned u = __float_as_uint(x);
    u += 0x7fffu + ((u >> 16) & 1u);
    return (unsigned short)(u >> 16);
}
__device__ __forceinline__ float bf_lo(unsigned u) { return __uint_as_float(u << 16); }
__device__ __forceinline__ float bf_hi(unsigned u) { return __uint_as_float(u & 0xffff0000u); }
// XOR swizzle for 256B-row-stride LDS tiles (16B granule)
__device__ __forceinline__ int swz(int byte) { return byte ^ (((byte >> 8) & 15) << 4); }

// ---------------------- spectral norm (power iteration) --------------------
__launch_bounds__(128, 1)
__global__ void sn_k(const float* __restrict__ Win, const float* __restrict__ Wode,
                     float* __restrict__ WnIn, float* __restrict__ WnOde)
{
    __shared__ float Ws[128 * 128];
    __shared__ float Wt[128 * 128];
    __shared__ float red[128];
    const float* W  = (blockIdx.x == 0) ? Win  : Wode;
    float*       Wn = (blockIdx.x == 0) ? WnIn : WnOde;
    const int t = threadIdx.x;

    for (int i = t * 4; i < 16384; i += 512) {
        float4 v = *(const float4*)&W[i];
        *(float4*)&Ws[i] = v;
        int r = i >> 7, c = i & 127;
        Wt[(c + 0) * 128 + r] = v.x;
        Wt[(c + 1) * 128 + r] = v.y;
        Wt[(c + 2) * 128 + r] = v.z;
        Wt[(c + 3) * 128 + r] = v.w;
    }
    __syncthreads();

    float u = 0.088388347648318447f;  // 1/sqrt(128)
    float v = 0.0f;
    for (int it = 0; it < 5; it++) {
        red[t] = u; __syncthreads();
        float vv = 0.f;
        for (int i = 0; i < 128; i++) vv = fmaf(Ws[i * 128 + t], red[i], vv);
        __syncthreads();
        red[t] = vv * vv; __syncthreads();
        for (int s = 64; s > 0; s >>= 1) { if (t < s) red[t] += red[t + s]; __syncthreads(); }
        float nv = sqrtf(red[0]) + 1e-12f;
        v = vv / nv;
        __syncthreads();
        red[t] = v; __syncthreads();
        float uu = 0.f;
        for (int i = 0; i < 128; i++) uu = fmaf(Wt[i * 128 + t], red[i], uu);
        __syncthreads();
        red[t] = uu * uu; __syncthreads();
        for (int s = 64; s > 0; s >>= 1) { if (t < s) red[t] += red[t + s]; __syncthreads(); }
        float nu = sqrtf(red[0]) + 1e-12f;
        u = uu / nu;
        __syncthreads();
    }
    red[t] = v; __syncthreads();
    float wv = 0.f;
    for (int i = 0; i < 128; i++) wv = fmaf(Wt[i * 128 + t], red[i], wv);
    __syncthreads();
    red[t] = u * wv; __syncthreads();
    for (int s = 64; s > 0; s >>= 1) { if (t < s) red[t] += red[t + s]; __syncthreads(); }
    float inv = 1.0f / (red[0] + 1e-12f);
    __syncthreads();
    for (int i = t * 4; i < 16384; i += 512) {
        float4 w = *(const float4*)&Ws[i];
        w.x *= inv; w.y *= inv; w.z *= inv; w.w *= inv;
        *(float4*)&Wn[i] = w;
    }
}

// ------------------------------ CSR build ----------------------------------
__global__ void hist_k(const int* __restrict__ dst, int* __restrict__ deg, int E, int N)
{
    int e = blockIdx.x * blockDim.x + threadIdx.x;
    if (e < E) {
        int d = dst[e];
        d = (d < 0) ? 0 : (d >= N ? N - 1 : d);
        atomicAdd(&deg[d], 1);
    }
}

__launch_bounds__(1024, 1)
__global__ void scan_k(const int* __restrict__ deg, int* __restrict__ offs, int n)
{
    __shared__ int part[1024];
    const int t = threadIdx.x;
    const int chunk = (n + 1023) >> 10;
    int lo = t * chunk; if (lo > n) lo = n;
    int hi = lo + chunk; if (hi > n) hi = n;
    int s = 0;
    for (int i = lo; i < hi; i++) s += deg[i];
    part[t] = s; __syncthreads();
    for (int d = 1; d < 1024; d <<= 1) {
        int v = (t >= d) ? part[t - d] : 0;
        __syncthreads();
        part[t] += v;
        __syncthreads();
    }
    int run = (t == 0) ? 0 : part[t - 1];
    for (int i = lo; i < hi; i++) { offs[i] = run; run += deg[i]; }
    if (t == 1023) offs[n] = run;
}

__global__ void scatter_k(const int* __restrict__ src, const int* __restrict__ dst,
                          const int* __restrict__ offs, int* __restrict__ cursor,
                          int* __restrict__ col, int E, int N)
{
    int e = blockIdx.x * blockDim.x + threadIdx.x;
    if (e < E) {
        int d = dst[e];
        d = (d < 0) ? 0 : (d >= N ? N - 1 : d);
        int s = src[e];
        s = (s < 0) ? 0 : (s >= N ? N - 1 : s);
        int pos = offs[d] + atomicAdd(&cursor[d], 1);
        col[pos] = s;
    }
}

// ------------------------------ GEMM 128 (fp32 VALU) -----------------------
// mode 0: xh = in@W -> bf16 out_bf + fused al_s/al_d head reductions (fp32)
// mode 1: out_f32 = gelu(in@W + bias)
__launch_bounds__(256, 2)
__global__ void gemm128_k(const float* __restrict__ in, const float* __restrict__ W,
                          const float* __restrict__ bias, float* __restrict__ out_f32,
                          unsigned* __restrict__ out_bf, int nrows, int mode,
                          const float* __restrict__ a_s, const float* __restrict__ a_d,
                          float* __restrict__ als, float* __restrict__ ald)
{
    __shared__ float Ws[128 * 128];
    const int t = threadIdx.x;
    const int n0 = blockIdx.x * 128;

    for (int i = t * 4; i < 16384; i += 1024)
        *(float4*)&Ws[i] = *(const float4*)&W[i];
    __syncthreads();

    const int cg = t & 15, rg = t >> 4;
    const int c0 = cg * 8, r0 = rg * 8;

    const float* xrow[8];
    bool rowok[8];
#pragma unroll
    for (int i = 0; i < 8; i++) {
        int r = n0 + r0 + i;
        rowok[i] = (r < nrows);
        int rc = rowok[i] ? r : (nrows - 1);
        xrow[i] = in + (size_t)rc * 128;
    }

    float acc[8][8];
#pragma unroll
    for (int i = 0; i < 8; i++)
#pragma unroll
        for (int j = 0; j < 8; j++) acc[i][j] = 0.f;

    for (int k = 0; k < 128; k += 4) {
        float4 xv[8];
#pragma unroll
        for (int i = 0; i < 8; i++) xv[i] = *(const float4*)(xrow[i] + k);
#pragma unroll
        for (int kk = 0; kk < 4; kk++) {
            float4 w0 = *(const float4*)&Ws[(k + kk) * 128 + c0];
            float4 w1 = *(const float4*)&Ws[(k + kk) * 128 + c0 + 4];
#pragma unroll
            for (int i = 0; i < 8; i++) {
                float xk = (kk == 0) ? xv[i].x : (kk == 1) ? xv[i].y : (kk == 2) ? xv[i].z : xv[i].w;
                acc[i][0] = fmaf(xk, w0.x, acc[i][0]);
                acc[i][1] = fmaf(xk, w0.y, acc[i][1]);
                acc[i][2] = fmaf(xk, w0.z, acc[i][2]);
                acc[i][3] = fmaf(xk, w0.w, acc[i][3]);
                acc[i][4] = fmaf(xk, w1.x, acc[i][4]);
                acc[i][5] = fmaf(xk, w1.y, acc[i][5]);
                acc[i][6] = fmaf(xk, w1.z, acc[i][6]);
                acc[i][7] = fmaf(xk, w1.w, acc[i][7]);
            }
        }
    }

    if (mode == 0) {
        const int h = cg >> 2, coff = (cg & 3) * 8;
        float ps[8], pd[8];
#pragma unroll
        for (int i = 0; i < 8; i++) {
            float s_ = 0.f, d_ = 0.f;
#pragma unroll
            for (int j = 0; j < 8; j++) {
                s_ = fmaf(acc[i][j], a_s[h * 32 + coff + j], s_);
                d_ = fmaf(acc[i][j], a_d[h * 32 + coff + j], d_);
            }
            ps[i] = s_; pd[i] = d_;
        }
#pragma unroll
        for (int mk = 1; mk < 4; mk <<= 1) {
#pragma unroll
            for (int i = 0; i < 8; i++) {
                ps[i] += __shfl_xor(ps[i], mk);
                pd[i] += __shfl_xor(pd[i], mk);
            }
        }
        if ((cg & 3) == 0) {
#pragma unroll
            for (int i = 0; i < 8; i++) if (rowok[i]) {
                als[(size_t)(n0 + r0 + i) * 4 + h] = ps[i];
                ald[(size_t)(n0 + r0 + i) * 4 + h] = pd[i];
            }
        }
#pragma unroll
        for (int i = 0; i < 8; i++) if (rowok[i]) {
            size_t b = (size_t)(n0 + r0 + i) * 64 + cg * 4;
            uint4 o;
            o.x = pack_bf16(acc[i][0], acc[i][1]);
            o.y = pack_bf16(acc[i][2], acc[i][3]);
            o.z = pack_bf16(acc[i][4], acc[i][5]);
            o.w = pack_bf16(acc[i][6], acc[i][7]);
            *(uint4*)&out_bf[b] = o;
        }
    } else {
#pragma unroll
        for (int i = 0; i < 8; i++) if (rowok[i]) {
            size_t b = (size_t)(n0 + r0 + i) * 128 + c0;
            float o[8];
#pragma unroll
            for (int j = 0; j < 8; j++) o[j] = gelu_f(acc[i][j] + bias[c0 + j]);
            *(float4*)&out_f32[b]     = make_float4(o[0], o[1], o[2], o[3]);
            *(float4*)&out_f32[b + 4] = make_float4(o[4], o[5], o[6], o[7]);
        }
    }
}

// ----------------------- GAT aggregation v2 --------------------------------
__launch_bounds__(256)
__global__ void gat_agg2_k(const unsigned* __restrict__ xhbf, const float* __restrict__ als,
                           const float* __restrict__ ald, const int* __restrict__ col,
                           const int* __restrict__ offs, const float* __restrict__ bias,
                           const float* __restrict__ g, const float* __restrict__ be,
                           float* __restrict__ hout, int nnodes)
{
    __shared__ float alph[4][64][4];
    __shared__ int   scol[4][64];
    const int w = threadIdx.x >> 6;
    const int n = blockIdx.x * 4 + w;
    if (n >= nnodes) return;
    const int lane = threadIdx.x & 63;
    const int e0 = offs[n], e1 = offs[n + 1];
    const float4 aldv = *(const float4*)&ald[(size_t)n * 4];

    float m0 = -1e30f, m1 = -1e30f, m2 = -1e30f, m3 = -1e30f;
    float s0 = 0.f, s1 = 0.f, s2 = 0.f, s3 = 0.f;
    for (int i = e0 + lane; i < e1; i += 64) {
        int sv = col[i];
        float4 av = *(const float4*)&als[(size_t)sv * 4];
        float l0 = av.x + aldv.x; l0 = l0 > 0.f ? l0 : 0.2f * l0;
        float l1 = av.y + aldv.y; l1 = l1 > 0.f ? l1 : 0.2f * l1;
        float l2 = av.z + aldv.z; l2 = l2 > 0.f ? l2 : 0.2f * l2;
        float l3 = av.w + aldv.w; l3 = l3 > 0.f ? l3 : 0.2f * l3;
        float M;
        M = fmaxf(m0, l0); s0 = s0 * __expf(m0 - M) + __expf(l0 - M); m0 = M;
        M = fmaxf(m1, l1); s1 = s1 * __expf(m1 - M) + __expf(l1 - M); m1 = M;
        M = fmaxf(m2, l2); s2 = s2 * __expf(m2 - M) + __expf(l2 - M); m2 = M;
        M = fmaxf(m3, l3); s3 = s3 * __expf(m3 - M) + __expf(l3 - M); m3 = M;
    }
#pragma unroll
    for (int mk = 1; mk < 64; mk <<= 1) {
        float mo, so, M;
        mo = __shfl_xor(m0, mk); so = __shfl_xor(s0, mk);
        M = fmaxf(m0, mo); s0 = s0 * __expf(m0 - M) + so * __expf(mo - M); m0 = M;
        mo = __shfl_xor(m1, mk); so = __shfl_xor(s1, mk);
        M = fmaxf(m1, mo); s1 = s1 * __expf(m1 - M) + so * __expf(mo - M); m1 = M;
        mo = __shfl_xor(m2, mk); so = __shfl_xor(s2, mk);
        M = fmaxf(m2, mo); s2 = s2 * __expf(m2 - M) + so * __expf(mo - M); m2 = M;
        mo = __shfl_xor(m3, mk); so = __shfl_xor(s3, mk);
        M = fmaxf(m3, mo); s3 = s3 * __expf(m3 - M) + so * __expf(mo - M); m3 = M;
    }
    const float i0 = 1.f / (s0 + 1e-16f), i1 = 1.f / (s1 + 1e-16f);
    const float i2 = 1.f / (s2 + 1e-16f), i3 = 1.f / (s3 + 1e-16f);

    const int hh = lane >> 4;
    float ax = 0.f, ay = 0.f;
    for (int base = e0; base < e1; base += 64) {
        int idx = base + lane;
        if (idx < e1) {
            int sv = col[idx];
            float4 av = *(const float4*)&als[(size_t)sv * 4];
            float l0 = av.x + aldv.x; l0 = l0 > 0.f ? l0 : 0.2f * l0;
            float l1 = av.y + aldv.y; l1 = l1 > 0.f ? l1 : 0.2f * l1;
            float l2 = av.z + aldv.z; l2 = l2 > 0.f ? l2 : 0.2f * l2;
            float l3 = av.w + aldv.w; l3 = l3 > 0.f ? l3 : 0.2f * l3;
            float4 a4;
            a4.x = __expf(l0 - m0) * i0;
            a4.y = __expf(l1 - m1) * i1;
            a4.z = __expf(l2 - m2) * i2;
            a4.w = __expf(l3 - m3) * i3;
            *(float4*)&alph[w][lane][0] = a4;
            scol[w][lane] = sv;
        }
        int cnt = e1 - base; if (cnt > 64) cnt = 64;
#pragma unroll 4
        for (int j = 0; j < cnt; j++) {
            int sj = scol[w][j];
            float aj = alph[w][j][hh];
            unsigned u = xhbf[(size_t)sj * 64 + lane];
            ax = fmaf(aj, bf_lo(u), ax);
            ay = fmaf(aj, bf_hi(u), ay);
        }
    }

    const int c0 = lane * 2;
    float v0 = gelu_f(ax + bias[c0]);
    float v1 = gelu_f(ay + bias[c0 + 1]);
    float sum = v0 + v1;
#pragma unroll
    for (int mk = 32; mk >= 1; mk >>= 1) sum += __shfl_xor(sum, mk);
    float mean = sum * (1.0f / 128.0f);
    float d0 = v0 - mean, d1 = v1 - mean;
    float vs = d0 * d0 + d1 * d1;
#pragma unroll
    for (int mk = 32; mk >= 1; mk >>= 1) vs += __shfl_xor(vs, mk);
    float rstd = rsqrtf(vs * (1.0f / 128.0f) + 1e-5f);
    size_t b = (size_t)n * 128 + c0;
    hout[b]     = d0 * rstd * g[c0] + be[c0];
    hout[b + 1] = d1 * rstd * g[c0 + 1] + be[c0 + 1];
}

// ----------------------- fused RK4 ODE block (bf16 MFMA, 16-row chunks) ----
// 256 threads = 4 waves. LDS: W^T bf16 swizzled [c][k] (32KB) + bias +
// per-wave 16x128 bf16 t-buffer (4KB each). Each wave: one 16-row chunk,
// all 16 RK4 stages via mfma_f32_16x16x32_bf16 over 8 column tiles.
// C/D (16x16): col = lane&15, row = (lane>>4)*4 + reg.
// A frag: row = lane&15, k = ks*32 + (lane>>4)*8 + j   (b128 from LDS)
// B frag: col = lane&15 -> W^T row c, same k pattern.
// Per-lane state: yv[8][4] + av[8][4] fp32 (64) + af 16 + acc 4 -> no spill.
__launch_bounds__(256, 3)
__global__ void ode_mfma_k(const float* __restrict__ yin, const float* __restrict__ Wn,
                           const float* __restrict__ bias, unsigned short* __restrict__ ybf,
                           int nrows, int nchunks)
{
    __shared__ unsigned short Wt[128 * 128];     // [c][k] bf16, swizzled
    __shared__ float bs[128];
    __shared__ unsigned short tl[4][16 * 128];   // per-wave [r][k] bf16, swizzled
    const int t = threadIdx.x;
    const int w = t >> 6, lane = t & 63;
    const int cl = lane & 15, lg = lane >> 4;    // col-in-tile, lane group

    // stage W^T (bf16, swizzled): W[k][c] coalesced read, b16 scatter
    for (int i = t; i < 16384; i += 256) {
        int k = i >> 7, c = i & 127;
        float v = Wn[i];
        *(unsigned short*)((char*)Wt + swz((c << 8) + (k << 1))) = bfbits(v);
    }
    if (t < 128) bs[t] = bias[t];
    __syncthreads();

    float bcol[8];
#pragma unroll
    for (int n = 0; n < 8; n++) bcol[n] = bs[n * 16 + cl];

    const float dt = 0.25f;
    char* tbase = (char*)&tl[w][0];

    for (int chunk = blockIdx.x * 4 + w; chunk < nchunks; chunk += gridDim.x * 4) {
        const int r0 = chunk * 16;
        // stage y rows -> t-buffer (bf16, swizzled): 8 iters of float4/uint2
        for (int g = lane; g < 512; g += 64) {
            int r = g >> 5, k0 = (g & 31) * 4;
            int rc = r0 + r; if (rc > nrows - 1) rc = nrows - 1;
            float4 v = *(const float4*)&yin[(size_t)rc * 128 + k0];
            unsigned lo = pack_bf16(v.x, v.y);
            unsigned hi = pack_bf16(v.z, v.w);
            *(uint2*)(tbase + swz(r * 256 + k0 * 2)) = make_uint2(lo, hi);
        }
        // y state fp32 in C-layout: row = lg*4+q, col = n*16+cl
        float yv[8][4], av[8][4];
#pragma unroll
        for (int q = 0; q < 4; q++) {
            int rc = r0 + lg * 4 + q; if (rc > nrows - 1) rc = nrows - 1;
            const float* rp = &yin[(size_t)rc * 128 + cl];
#pragma unroll
            for (int n = 0; n < 8; n++) { yv[n][q] = rp[n * 16]; av[n][q] = yv[n][q]; }
        }

#pragma unroll 1
        for (int step = 0; step < 4; step++) {
#pragma unroll 1
            for (int st = 0; st < 4; st++) {
                const float ca = (st == 0 || st == 3) ? dt / 6.f : dt / 3.f;
                const float ct = (st < 2) ? dt * 0.5f : dt;
                const bool last = (st == 3);
                // A fragments for the 4 K-blocks (shared across all 8 n-tiles)
                bf16x8 af[4];
#pragma unroll
                for (int ks = 0; ks < 4; ks++)
                    af[ks] = *(const bf16x8*)(tbase + swz(cl * 256 + ks * 64 + lg * 16));
#pragma unroll
                for (int n = 0; n < 8; n++) {
                    f32x4 acc = {0.f, 0.f, 0.f, 0.f};
#pragma unroll
                    for (int ks = 0; ks < 4; ks++) {
                        bf16x8 bf = *(const bf16x8*)((char*)Wt +
                                      swz((n * 16 + cl) * 256 + ks * 64 + lg * 16));
                        acc = __builtin_amdgcn_mfma_f32_16x16x32_bf16(af[ks], bf, acc, 0, 0, 0);
                    }
#pragma unroll
                    for (int q = 0; q < 4; q++) {
                        float kk = gelu_f(acc[q] + bcol[n]);
                        av[n][q] = fmaf(ca, kk, av[n][q]);
                        float tn;
                        if (last) { yv[n][q] = av[n][q]; tn = av[n][q]; }
                        else      { tn = fmaf(ct, kk, yv[n][q]); }
                        int rr = lg * 4 + q;
                        *(unsigned short*)(tbase + swz(rr * 256 + (n * 16 + cl) * 2)) = bfbits(tn);
                    }
                }
            }
        }
        // final store: av -> ybf (bf16 ushort[row][128])
#pragma unroll
        for (int q = 0; q < 4; q++) {
            int rg = r0 + lg * 4 + q;
            if (rg < nrows) {
#pragma unroll
                for (int n = 0; n < 8; n++)
                    ybf[(size_t)rg * 128 + n * 16 + cl] = bfbits(av[n][q]);
            }
        }
    }
}

// ----------------------- hop mean-aggregation (bf16) -----------------------
__launch_bounds__(256)
__global__ void hop_k(const unsigned* __restrict__ cur, const int* __restrict__ col,
                      const int* __restrict__ offs, const int* __restrict__ deg,
                      unsigned* __restrict__ outbf, int nnodes)
{
    __shared__ int scol[4][64];
    const int w = threadIdx.x >> 6;
    const int n = blockIdx.x * 4 + w;
    if (n >= nnodes) return;
    const int lane = threadIdx.x & 63;
    const int e0 = offs[n], e1 = offs[n + 1];
    float ax = 0.f, ay = 0.f;
    for (int base = e0; base < e1; base += 64) {
        int idx = base + lane;
        if (idx < e1) scol[w][lane] = col[idx];
        int cnt = e1 - base; if (cnt > 64) cnt = 64;
#pragma unroll 4
        for (int j = 0; j < cnt; j++) {
            int sj = scol[w][j];
            unsigned u = cur[(size_t)sj * 64 + lane];
            ax += bf_lo(u); ay += bf_hi(u);
        }
    }
    float dg = fmaxf((float)deg[n], 1.0f);
    outbf[(size_t)n * 64 + lane] = pack_bf16(ax / dg, ay / dg);
}

// ----------------------- hop-attention combine -----------------------------
__launch_bounds__(256)
__global__ void final2_k(const unsigned* __restrict__ s0b, const unsigned* __restrict__ s1b,
                         const unsigned* __restrict__ s2b, const unsigned* __restrict__ s3b,
                         const float* __restrict__ att, float* __restrict__ outp, int nnodes)
{
    const int n = blockIdx.x * 4 + (threadIdx.x >> 6);
    if (n >= nnodes) return;
    const int lane = threadIdx.x & 63;
    size_t b = (size_t)n * 64 + lane;
    float2 a = *(const float2*)&att[lane * 2];
    unsigned u0 = s0b[b], u1 = s1b[b], u2 = s2b[b], u3 = s3b[b];
    float p0 = bf_lo(u0) * a.x + bf_hi(u0) * a.y;
    float p1 = bf_lo(u1) * a.x + bf_hi(u1) * a.y;
    float p2 = bf_lo(u2) * a.x + bf_hi(u2) * a.y;
    float p3 = bf_lo(u3) * a.x + bf_hi(u3) * a.y;
#pragma unroll
    for (int mk = 32; mk >= 1; mk >>= 1) {
        p0 += __shfl_xor(p0, mk); p1 += __shfl_xor(p1, mk);
        p2 += __shfl_xor(p2, mk); p3 += __shfl_xor(p3, mk);
    }
    float mm = fmaxf(fmaxf(p0, p1), fmaxf(p2, p3));
    float e0 = __expf(p0 - mm), e1 = __expf(p1 - mm), e2 = __expf(p2 - mm), e3 = __expf(p3 - mm);
    float inv = 1.0f / (e0 + e1 + e2 + e3);
    float w0 = e0 * inv, w1 = e1 * inv, w2 = e2 * inv, w3 = e3 * inv;
    float ox = w0 * bf_lo(u0) + w1 * bf_lo(u1) + w2 * bf_lo(u2) + w3 * bf_lo(u3);
    float oy = w0 * bf_hi(u0) + w1 * bf_hi(u1) + w2 * bf_hi(u2) + w3 * bf_hi(u3);
    *(float2*)&outp[(size_t)n * 128 + lane * 2] = make_float2(ox, oy);
}

// ---------------------------------------------------------------------------
extern "C" void kernel_launch(void* const* d_in, const int* in_sizes, int n_in,
                              void* d_out, int out_size, void* d_ws, size_t ws_size,
                              hipStream_t stream)
{
    const float* x     = (const float*)d_in[0];
    const int*   ei    = (const int*)d_in[1];
    const float* W_in  = (const float*)d_in[2];
    const float* b_in  = (const float*)d_in[3];
    const float* W1    = (const float*)d_in[4];
    const float* a_s1  = (const float*)d_in[5];
    const float* a_d1  = (const float*)d_in[6];
    const float* b1    = (const float*)d_in[7];
    const float* W2    = (const float*)d_in[8];
    const float* a_s2  = (const float*)d_in[9];
    const float* a_d2  = (const float*)d_in[10];
    const float* b2    = (const float*)d_in[11];
    const float* g1    = (const float*)d_in[12];
    const float* be1   = (const float*)d_in[13];
    const float* g2    = (const float*)d_in[14];
    const float* be2   = (const float*)d_in[15];
    const float* W_ode = (const float*)d_in[16];
    const float* b_ode = (const float*)d_in[17];
    const float* att   = (const float*)d_in[18];

    const int N = in_sizes[0] / 128;
    const int E = in_sizes[1] / 2;
    const int* srcv = ei;
    const int* dstv = ei + E;

    char* wsb = (char*)d_ws;
    size_t off = 0;
    auto alloc = [&](size_t bytes) -> void* {
        void* p = wsb + off;
        off = (off + bytes + 511) & ~(size_t)511;
        return p;
    };
    float*    WnIn   = (float*)alloc(65536);
    float*    WnOde  = (float*)alloc(65536);
    float*    als    = (float*)alloc((size_t)N * 4 * 4);
    float*    ald    = (float*)alloc((size_t)N * 4 * 4);
    int*      deg    = (int*)alloc((size_t)N * 4);
    int*      cursor = (int*)alloc((size_t)N * 4);
    int*      offs   = (int*)alloc((size_t)(N + 1) * 4);
    int*      col    = (int*)alloc((size_t)E * 4);
    float*    B0     = (float*)alloc((size_t)N * 128 * 4);   // fp32 activations
    unsigned* xhbf   = (unsigned*)alloc((size_t)N * 64 * 4); // bf16 xh / hop1
    unsigned* ybf    = (unsigned*)alloc((size_t)N * 64 * 4); // bf16 ODE out
    unsigned* h2bf   = (unsigned*)alloc((size_t)N * 64 * 4);
    unsigned* h3bf   = (unsigned*)alloc((size_t)N * 64 * 4);

    (void)hipMemsetAsync(deg, 0, (size_t)N * 4, stream);
    (void)hipMemsetAsync(cursor, 0, (size_t)N * 4, stream);

    sn_k<<<2, 128, 0, stream>>>(W_in, W_ode, WnIn, WnOde);
    hist_k<<<(E + 255) / 256, 256, 0, stream>>>(dstv, deg, E, N);
    scan_k<<<1, 1024, 0, stream>>>(deg, offs, N);
    scatter_k<<<(E + 255) / 256, 256, 0, stream>>>(srcv, dstv, offs, cursor, col, E, N);

    const int gblocks = (N + 127) / 128;
    const int ablocks = (N + 3) / 4;

    // input layer: B0 = gelu(x @ sn(W_in) + b_in)
    gemm128_k<<<gblocks, 256, 0, stream>>>(x, WnIn, b_in, B0, nullptr, N, 1,
        nullptr, nullptr, nullptr, nullptr);

    // GAT layer 1
    gemm128_k<<<gblocks, 256, 0, stream>>>(B0, W1, nullptr, nullptr, xhbf, N, 0,
        a_s1, a_d1, als, ald);
    gat_agg2_k<<<ablocks, 256, 0, stream>>>(xhbf, als, ald, col, offs, b1, g1, be1, B0, N);

    // GAT layer 2
    gemm128_k<<<gblocks, 256, 0, stream>>>(B0, W2, nullptr, nullptr, xhbf, N, 0,
        a_s2, a_d2, als, ald);
    gat_agg2_k<<<ablocks, 256, 0, stream>>>(xhbf, als, ald, col, offs, b2, g2, be2, B0, N);

    // fused RK4 ODE (bf16 MFMA, 16-row chunks): B0 -> ybf
    const int nchunks = (N + 15) / 16;
    const int oblocks = (nchunks + 3) / 4;
    ode_mfma_k<<<oblocks, 256, 0, stream>>>(B0, WnOde, b_ode, (unsigned short*)ybf, N, nchunks);

    // 3-hop mean broadcast (bf16 stack) + attention combine
    hop_k<<<ablocks, 256, 0, stream>>>(ybf,  col, offs, deg, xhbf, N);  // hop1
    hop_k<<<ablocks, 256, 0, stream>>>(xhbf, col, offs, deg, h2bf, N);  // hop2
    hop_k<<<ablocks, 256, 0, stream>>>(h2bf, col, offs, deg, h3bf, N);  // hop3
    final2_k<<<ablocks, 256, 0, stream>>>(ybf, xhbf, h2bf, h3bf, att, (float*)d_out, N);
}

// Round 5
// 787.172 us; speedup vs baseline: 2.7555x; 1.3360x over previous
//
#include <hip/hip_runtime.h>
#include <math.h>

// ---------------------------------------------------------------------------
// TemporalGraphEncoder: N=50000, E=1.6M, D=128, H=4, C=32, HOPS=3
// r5: ODE MFMA kernel: wave-pair column split so RK4 state = 32 fp32/lane
//     (r4's 128 fp32/lane was demoted to scratch: VGPR=84, FETCH 635MB).
// ---------------------------------------------------------------------------

typedef __attribute__((ext_vector_type(8))) short bf16x8;
typedef __attribute__((ext_vector_type(4))) float f32x4;

__device__ __forceinline__ float gelu_f(float x) {
    return 0.5f * x * (1.0f + erff(x * 0.70710678118654752f));
}
__device__ __forceinline__ unsigned pack_bf16(float a, float b) {
    unsigned ua = __float_as_uint(a), ub = __float_as_uint(b);
    ua += 0x7fffu + ((ua >> 16) & 1u);
    ub += 0x7fffu + ((ub >> 16) & 1u);
    return (ua >> 16) | (ub & 0xffff0000u);
}
__device__ __forceinline__ unsigned short bfbits(float x) {
    unsigned u = __float_as_uint(x);
    u += 0x7fffu + ((u >> 16) & 1u);
    return (unsigned short)(u >> 16);
}
__device__ __forceinline__ float bf_lo(unsigned u) { return __uint_as_float(u << 16); }
__device__ __forceinline__ float bf_hi(unsigned u) { return __uint_as_float(u & 0xffff0000u); }
// XOR swizzle for 256B-row-stride LDS tiles (16B granule)
__device__ __forceinline__ int swz(int byte) { return byte ^ (((byte >> 8) & 15) << 4); }

// ---------------------- spectral norm (power iteration) --------------------
__launch_bounds__(128, 1)
__global__ void sn_k(const float* __restrict__ Win, const float* __restrict__ Wode,
                     float* __restrict__ WnIn, float* __restrict__ WnOde)
{
    __shared__ float Ws[128 * 128];
    __shared__ float Wt[128 * 128];
    __shared__ float red[128];
    const float* W  = (blockIdx.x == 0) ? Win  : Wode;
    float*       Wn = (blockIdx.x == 0) ? WnIn : WnOde;
    const int t = threadIdx.x;

    for (int i = t * 4; i < 16384; i += 512) {
        float4 v = *(const float4*)&W[i];
        *(float4*)&Ws[i] = v;
        int r = i >> 7, c = i & 127;
        Wt[(c + 0) * 128 + r] = v.x;
        Wt[(c + 1) * 128 + r] = v.y;
        Wt[(c + 2) * 128 + r] = v.z;
        Wt[(c + 3) * 128 + r] = v.w;
    }
    __syncthreads();

    float u = 0.088388347648318447f;  // 1/sqrt(128)
    float v = 0.0f;
    for (int it = 0; it < 5; it++) {
        red[t] = u; __syncthreads();
        float vv = 0.f;
        for (int i = 0; i < 128; i++) vv = fmaf(Ws[i * 128 + t], red[i], vv);
        __syncthreads();
        red[t] = vv * vv; __syncthreads();
        for (int s = 64; s > 0; s >>= 1) { if (t < s) red[t] += red[t + s]; __syncthreads(); }
        float nv = sqrtf(red[0]) + 1e-12f;
        v = vv / nv;
        __syncthreads();
        red[t] = v; __syncthreads();
        float uu = 0.f;
        for (int i = 0; i < 128; i++) uu = fmaf(Wt[i * 128 + t], red[i], uu);
        __syncthreads();
        red[t] = uu * uu; __syncthreads();
        for (int s = 64; s > 0; s >>= 1) { if (t < s) red[t] += red[t + s]; __syncthreads(); }
        float nu = sqrtf(red[0]) + 1e-12f;
        u = uu / nu;
        __syncthreads();
    }
    red[t] = v; __syncthreads();
    float wv = 0.f;
    for (int i = 0; i < 128; i++) wv = fmaf(Wt[i * 128 + t], red[i], wv);
    __syncthreads();
    red[t] = u * wv; __syncthreads();
    for (int s = 64; s > 0; s >>= 1) { if (t < s) red[t] += red[t + s]; __syncthreads(); }
    float inv = 1.0f / (red[0] + 1e-12f);
    __syncthreads();
    for (int i = t * 4; i < 16384; i += 512) {
        float4 w = *(const float4*)&Ws[i];
        w.x *= inv; w.y *= inv; w.z *= inv; w.w *= inv;
        *(float4*)&Wn[i] = w;
    }
}

// ------------------------------ CSR build ----------------------------------
__global__ void hist_k(const int* __restrict__ dst, int* __restrict__ deg, int E, int N)
{
    int e = blockIdx.x * blockDim.x + threadIdx.x;
    if (e < E) {
        int d = dst[e];
        d = (d < 0) ? 0 : (d >= N ? N - 1 : d);
        atomicAdd(&deg[d], 1);
    }
}

__launch_bounds__(1024, 1)
__global__ void scan_k(const int* __restrict__ deg, int* __restrict__ offs, int n)
{
    __shared__ int part[1024];
    const int t = threadIdx.x;
    const int chunk = (n + 1023) >> 10;
    int lo = t * chunk; if (lo > n) lo = n;
    int hi = lo + chunk; if (hi > n) hi = n;
    int s = 0;
    for (int i = lo; i < hi; i++) s += deg[i];
    part[t] = s; __syncthreads();
    for (int d = 1; d < 1024; d <<= 1) {
        int v = (t >= d) ? part[t - d] : 0;
        __syncthreads();
        part[t] += v;
        __syncthreads();
    }
    int run = (t == 0) ? 0 : part[t - 1];
    for (int i = lo; i < hi; i++) { offs[i] = run; run += deg[i]; }
    if (t == 1023) offs[n] = run;
}

__global__ void scatter_k(const int* __restrict__ src, const int* __restrict__ dst,
                          const int* __restrict__ offs, int* __restrict__ cursor,
                          int* __restrict__ col, int E, int N)
{
    int e = blockIdx.x * blockDim.x + threadIdx.x;
    if (e < E) {
        int d = dst[e];
        d = (d < 0) ? 0 : (d >= N ? N - 1 : d);
        int s = src[e];
        s = (s < 0) ? 0 : (s >= N ? N - 1 : s);
        int pos = offs[d] + atomicAdd(&cursor[d], 1);
        col[pos] = s;
    }
}

// ------------------------------ GEMM 128 (fp32 VALU) -----------------------
// mode 0: xh = in@W -> bf16 out_bf + fused al_s/al_d head reductions (fp32)
// mode 1: out_f32 = gelu(in@W + bias)
__launch_bounds__(256, 2)
__global__ void gemm128_k(const float* __restrict__ in, const float* __restrict__ W,
                          const float* __restrict__ bias, float* __restrict__ out_f32,
                          unsigned* __restrict__ out_bf, int nrows, int mode,
                          const float* __restrict__ a_s, const float* __restrict__ a_d,
                          float* __restrict__ als, float* __restrict__ ald)
{
    __shared__ float Ws[128 * 128];
    const int t = threadIdx.x;
    const int n0 = blockIdx.x * 128;

    for (int i = t * 4; i < 16384; i += 1024)
        *(float4*)&Ws[i] = *(const float4*)&W[i];
    __syncthreads();

    const int cg = t & 15, rg = t >> 4;
    const int c0 = cg * 8, r0 = rg * 8;

    const float* xrow[8];
    bool rowok[8];
#pragma unroll
    for (int i = 0; i < 8; i++) {
        int r = n0 + r0 + i;
        rowok[i] = (r < nrows);
        int rc = rowok[i] ? r : (nrows - 1);
        xrow[i] = in + (size_t)rc * 128;
    }

    float acc[8][8];
#pragma unroll
    for (int i = 0; i < 8; i++)
#pragma unroll
        for (int j = 0; j < 8; j++) acc[i][j] = 0.f;

    for (int k = 0; k < 128; k += 4) {
        float4 xv[8];
#pragma unroll
        for (int i = 0; i < 8; i++) xv[i] = *(const float4*)(xrow[i] + k);
#pragma unroll
        for (int kk = 0; kk < 4; kk++) {
            float4 w0 = *(const float4*)&Ws[(k + kk) * 128 + c0];
            float4 w1 = *(const float4*)&Ws[(k + kk) * 128 + c0 + 4];
#pragma unroll
            for (int i = 0; i < 8; i++) {
                float xk = (kk == 0) ? xv[i].x : (kk == 1) ? xv[i].y : (kk == 2) ? xv[i].z : xv[i].w;
                acc[i][0] = fmaf(xk, w0.x, acc[i][0]);
                acc[i][1] = fmaf(xk, w0.y, acc[i][1]);
                acc[i][2] = fmaf(xk, w0.z, acc[i][2]);
                acc[i][3] = fmaf(xk, w0.w, acc[i][3]);
                acc[i][4] = fmaf(xk, w1.x, acc[i][4]);
                acc[i][5] = fmaf(xk, w1.y, acc[i][5]);
                acc[i][6] = fmaf(xk, w1.z, acc[i][6]);
                acc[i][7] = fmaf(xk, w1.w, acc[i][7]);
            }
        }
    }

    if (mode == 0) {
        const int h = cg >> 2, coff = (cg & 3) * 8;
        float ps[8], pd[8];
#pragma unroll
        for (int i = 0; i < 8; i++) {
            float s_ = 0.f, d_ = 0.f;
#pragma unroll
            for (int j = 0; j < 8; j++) {
                s_ = fmaf(acc[i][j], a_s[h * 32 + coff + j], s_);
                d_ = fmaf(acc[i][j], a_d[h * 32 + coff + j], d_);
            }
            ps[i] = s_; pd[i] = d_;
        }
#pragma unroll
        for (int mk = 1; mk < 4; mk <<= 1) {
#pragma unroll
            for (int i = 0; i < 8; i++) {
                ps[i] += __shfl_xor(ps[i], mk);
                pd[i] += __shfl_xor(pd[i], mk);
            }
        }
        if ((cg & 3) == 0) {
#pragma unroll
            for (int i = 0; i < 8; i++) if (rowok[i]) {
                als[(size_t)(n0 + r0 + i) * 4 + h] = ps[i];
                ald[(size_t)(n0 + r0 + i) * 4 + h] = pd[i];
            }
        }
#pragma unroll
        for (int i = 0; i < 8; i++) if (rowok[i]) {
            size_t b = (size_t)(n0 + r0 + i) * 64 + cg * 4;
            uint4 o;
            o.x = pack_bf16(acc[i][0], acc[i][1]);
            o.y = pack_bf16(acc[i][2], acc[i][3]);
            o.z = pack_bf16(acc[i][4], acc[i][5]);
            o.w = pack_bf16(acc[i][6], acc[i][7]);
            *(uint4*)&out_bf[b] = o;
        }
    } else {
#pragma unroll
        for (int i = 0; i < 8; i++) if (rowok[i]) {
            size_t b = (size_t)(n0 + r0 + i) * 128 + c0;
            float o[8];
#pragma unroll
            for (int j = 0; j < 8; j++) o[j] = gelu_f(acc[i][j] + bias[c0 + j]);
            *(float4*)&out_f32[b]     = make_float4(o[0], o[1], o[2], o[3]);
            *(float4*)&out_f32[b + 4] = make_float4(o[4], o[5], o[6], o[7]);
        }
    }
}

// ----------------------- GAT aggregation v2 --------------------------------
__launch_bounds__(256)
__global__ void gat_agg2_k(const unsigned* __restrict__ xhbf, const float* __restrict__ als,
                           const float* __restrict__ ald, const int* __restrict__ col,
                           const int* __restrict__ offs, const float* __restrict__ bias,
                           const float* __restrict__ g, const float* __restrict__ be,
                           float* __restrict__ hout, int nnodes)
{
    __shared__ float alph[4][64][4];
    __shared__ int   scol[4][64];
    const int w = threadIdx.x >> 6;
    const int n = blockIdx.x * 4 + w;
    if (n >= nnodes) return;
    const int lane = threadIdx.x & 63;
    const int e0 = offs[n], e1 = offs[n + 1];
    const float4 aldv = *(const float4*)&ald[(size_t)n * 4];

    float m0 = -1e30f, m1 = -1e30f, m2 = -1e30f, m3 = -1e30f;
    float s0 = 0.f, s1 = 0.f, s2 = 0.f, s3 = 0.f;
    for (int i = e0 + lane; i < e1; i += 64) {
        int sv = col[i];
        float4 av = *(const float4*)&als[(size_t)sv * 4];
        float l0 = av.x + aldv.x; l0 = l0 > 0.f ? l0 : 0.2f * l0;
        float l1 = av.y + aldv.y; l1 = l1 > 0.f ? l1 : 0.2f * l1;
        float l2 = av.z + aldv.z; l2 = l2 > 0.f ? l2 : 0.2f * l2;
        float l3 = av.w + aldv.w; l3 = l3 > 0.f ? l3 : 0.2f * l3;
        float M;
        M = fmaxf(m0, l0); s0 = s0 * __expf(m0 - M) + __expf(l0 - M); m0 = M;
        M = fmaxf(m1, l1); s1 = s1 * __expf(m1 - M) + __expf(l1 - M); m1 = M;
        M = fmaxf(m2, l2); s2 = s2 * __expf(m2 - M) + __expf(l2 - M); m2 = M;
        M = fmaxf(m3, l3); s3 = s3 * __expf(m3 - M) + __expf(l3 - M); m3 = M;
    }
#pragma unroll
    for (int mk = 1; mk < 64; mk <<= 1) {
        float mo, so, M;
        mo = __shfl_xor(m0, mk); so = __shfl_xor(s0, mk);
        M = fmaxf(m0, mo); s0 = s0 * __expf(m0 - M) + so * __expf(mo - M); m0 = M;
        mo = __shfl_xor(m1, mk); so = __shfl_xor(s1, mk);
        M = fmaxf(m1, mo); s1 = s1 * __expf(m1 - M) + so * __expf(mo - M); m1 = M;
        mo = __shfl_xor(m2, mk); so = __shfl_xor(s2, mk);
        M = fmaxf(m2, mo); s2 = s2 * __expf(m2 - M) + so * __expf(mo - M); m2 = M;
        mo = __shfl_xor(m3, mk); so = __shfl_xor(s3, mk);
        M = fmaxf(m3, mo); s3 = s3 * __expf(m3 - M) + so * __expf(mo - M); m3 = M;
    }
    const float i0 = 1.f / (s0 + 1e-16f), i1 = 1.f / (s1 + 1e-16f);
    const float i2 = 1.f / (s2 + 1e-16f), i3 = 1.f / (s3 + 1e-16f);

    const int hh = lane >> 4;
    float ax = 0.f, ay = 0.f;
    for (int base = e0; base < e1; base += 64) {
        int idx = base + lane;
        if (idx < e1) {
            int sv = col[idx];
            float4 av = *(const float4*)&als[(size_t)sv * 4];
            float l0 = av.x + aldv.x; l0 = l0 > 0.f ? l0 : 0.2f * l0;
            float l1 = av.y + aldv.y; l1 = l1 > 0.f ? l1 : 0.2f * l1;
            float l2 = av.z + aldv.z; l2 = l2 > 0.f ? l2 : 0.2f * l2;
            float l3 = av.w + aldv.w; l3 = l3 > 0.f ? l3 : 0.2f * l3;
            float4 a4;
            a4.x = __expf(l0 - m0) * i0;
            a4.y = __expf(l1 - m1) * i1;
            a4.z = __expf(l2 - m2) * i2;
            a4.w = __expf(l3 - m3) * i3;
            *(float4*)&alph[w][lane][0] = a4;
            scol[w][lane] = sv;
        }
        int cnt = e1 - base; if (cnt > 64) cnt = 64;
#pragma unroll 4
        for (int j = 0; j < cnt; j++) {
            int sj = scol[w][j];
            float aj = alph[w][j][hh];
            unsigned u = xhbf[(size_t)sj * 64 + lane];
            ax = fmaf(aj, bf_lo(u), ax);
            ay = fmaf(aj, bf_hi(u), ay);
        }
    }

    const int c0 = lane * 2;
    float v0 = gelu_f(ax + bias[c0]);
    float v1 = gelu_f(ay + bias[c0 + 1]);
    float sum = v0 + v1;
#pragma unroll
    for (int mk = 32; mk >= 1; mk >>= 1) sum += __shfl_xor(sum, mk);
    float mean = sum * (1.0f / 128.0f);
    float d0 = v0 - mean, d1 = v1 - mean;
    float vs = d0 * d0 + d1 * d1;
#pragma unroll
    for (int mk = 32; mk >= 1; mk >>= 1) vs += __shfl_xor(vs, mk);
    float rstd = rsqrtf(vs * (1.0f / 128.0f) + 1e-5f);
    size_t b = (size_t)n * 128 + c0;
    hout[b]     = d0 * rstd * g[c0] + be[c0];
    hout[b + 1] = d1 * rstd * g[c0 + 1] + be[c0 + 1];
}

// ----------------------- fused RK4 ODE block (bf16 MFMA, wave-pair) --------
// 256 threads = 4 waves = 2 pairs. Each pair owns one 16-row chunk; within a
// pair, wave hf owns columns hf*64..hf*64+63 (4 of 8 col-tiles).
// LDS: W^T bf16 swizzled [c][k] (32KB) + 2 pair t-buffers 16x128 bf16 (4KB ea).
// Per stage: af loads (full t rows) -> barrier -> 16 MFMA -> epilogue writes
// own column half -> barrier. Per-lane state: yv[4][4]+av[4][4]+af[4]+acc[4]
// ~= 100 VGPR -> fits the 128-reg cap at 4 waves/EU (r4's 128-float state
// was scratch-demoted: VGPR=84, FETCH 635MB).
__launch_bounds__(256, 4)
__global__ void ode_mfma_k(const float* __restrict__ yin, const float* __restrict__ Wn,
                           const float* __restrict__ bias, unsigned short* __restrict__ ybf,
                           int nrows, int nchunks)
{
    __shared__ unsigned short Wt[128 * 128];     // [c][k] bf16, swizzled (32KB)
    __shared__ unsigned short tl[2][16 * 128];   // per-pair [r][k] bf16, swizzled
    const int t = threadIdx.x;
    const int w = t >> 6, lane = t & 63;
    const int pair = w >> 1, hf = w & 1;
    const int cl = lane & 15, lg = lane >> 4;    // col-in-tile, lane group

    // stage W^T (bf16, swizzled): W[k][c] coalesced read, b16 scatter
    for (int i = t; i < 16384; i += 256) {
        int k = i >> 7, c = i & 127;
        *(unsigned short*)((char*)Wt + swz((c << 8) + (k << 1))) = bfbits(Wn[i]);
    }

    // bias for this wave's 4 column tiles (global scalar reads, L2-hot)
    float bcol[4];
#pragma unroll
    for (int n = 0; n < 4; n++) bcol[n] = bias[(hf * 4 + n) * 16 + cl];

    const float dt = 0.25f;
    char* tbase = (char*)&tl[pair][0];

    int chunk = blockIdx.x * 2 + pair;
    if (chunk > nchunks - 1) chunk = nchunks - 1;
    const int r0 = chunk * 16;

    // stage y rows -> pair t-buffer (128 threads per pair, 4 rows/iter)
    for (int i2 = hf * 64 + lane; i2 < 512; i2 += 128) {
        int r = i2 >> 5, k0 = (i2 & 31) * 4;
        int rc = r0 + r; if (rc > nrows - 1) rc = nrows - 1;
        float4 v = *(const float4*)&yin[(size_t)rc * 128 + k0];
        *(uint2*)(tbase + swz(r * 256 + k0 * 2)) =
            make_uint2(pack_bf16(v.x, v.y), pack_bf16(v.z, v.w));
    }
    // y state fp32: rows lg*4+q, cols hf*64 + n*16 + cl
    float yv[4][4], av[4][4];
#pragma unroll
    for (int q = 0; q < 4; q++) {
        int rc = r0 + lg * 4 + q; if (rc > nrows - 1) rc = nrows - 1;
        const float* rp = &yin[(size_t)rc * 128 + hf * 64 + cl];
#pragma unroll
        for (int n = 0; n < 4; n++) { yv[n][q] = rp[n * 16]; av[n][q] = yv[n][q]; }
    }
    __syncthreads();

#pragma unroll 1
    for (int step = 0; step < 4; step++) {
#pragma unroll 1
        for (int st = 0; st < 4; st++) {
            const float ca = (st == 0 || st == 3) ? dt / 6.f : dt / 3.f;
            const float ct = (st < 2) ? dt * 0.5f : dt;
            const bool last = (st == 3);
            // A fragments: full K for own rows (reads whole pair t-buffer)
            bf16x8 af[4];
#pragma unroll
            for (int ks = 0; ks < 4; ks++)
                af[ks] = *(const bf16x8*)(tbase + swz(cl * 256 + ks * 64 + lg * 16));
            // MFMA over this wave's 4 column tiles
            f32x4 acc[4];
#pragma unroll
            for (int n = 0; n < 4; n++) {
                acc[n] = (f32x4){0.f, 0.f, 0.f, 0.f};
#pragma unroll
                for (int ks = 0; ks < 4; ks++) {
                    bf16x8 bf = *(const bf16x8*)((char*)Wt +
                                  swz(((hf * 4 + n) * 16 + cl) * 256 + ks * 64 + lg * 16));
                    acc[n] = __builtin_amdgcn_mfma_f32_16x16x32_bf16(af[ks], bf, acc[n], 0, 0, 0);
                }
            }
            __syncthreads();   // all t-reads (af loads) complete block-wide
#pragma unroll
            for (int n = 0; n < 4; n++) {
#pragma unroll
                for (int q = 0; q < 4; q++) {
                    float kk = gelu_f(acc[n][q] + bcol[n]);
                    av[n][q] = fmaf(ca, kk, av[n][q]);
                    float tn;
                    if (last) { yv[n][q] = av[n][q]; tn = av[n][q]; }
                    else      { tn = fmaf(ct, kk, yv[n][q]); }
                    int rr = lg * 4 + q;
                    *(unsigned short*)(tbase +
                        swz(rr * 256 + ((hf * 4 + n) * 16 + cl) * 2)) = bfbits(tn);
                }
            }
            __syncthreads();   // t-writes visible before next stage's reads
        }
    }
    // final store: av -> ybf (bf16 ushort[row][128], own column half)
#pragma unroll
    for (int q = 0; q < 4; q++) {
        int rg = r0 + lg * 4 + q;
        if (rg < nrows) {
#pragma unroll
            for (int n = 0; n < 4; n++)
                ybf[(size_t)rg * 128 + hf * 64 + n * 16 + cl] = bfbits(av[n][q]);
        }
    }
}

// ----------------------- hop mean-aggregation (bf16) -----------------------
__launch_bounds__(256)
__global__ void hop_k(const unsigned* __restrict__ cur, const int* __restrict__ col,
                      const int* __restrict__ offs, const int* __restrict__ deg,
                      unsigned* __restrict__ outbf, int nnodes)
{
    __shared__ int scol[4][64];
    const int w = threadIdx.x >> 6;
    const int n = blockIdx.x * 4 + w;
    if (n >= nnodes) return;
    const int lane = threadIdx.x & 63;
    const int e0 = offs[n], e1 = offs[n + 1];
    float ax = 0.f, ay = 0.f;
    for (int base = e0; base < e1; base += 64) {
        int idx = base + lane;
        if (idx < e1) scol[w][lane] = col[idx];
        int cnt = e1 - base; if (cnt > 64) cnt = 64;
#pragma unroll 4
        for (int j = 0; j < cnt; j++) {
            int sj = scol[w][j];
            unsigned u = cur[(size_t)sj * 64 + lane];
            ax += bf_lo(u); ay += bf_hi(u);
        }
    }
    float dg = fmaxf((float)deg[n], 1.0f);
    outbf[(size_t)n * 64 + lane] = pack_bf16(ax / dg, ay / dg);
}

// ----------------------- hop-attention combine -----------------------------
__launch_bounds__(256)
__global__ void final2_k(const unsigned* __restrict__ s0b, const unsigned* __restrict__ s1b,
                         const unsigned* __restrict__ s2b, const unsigned* __restrict__ s3b,
                         const float* __restrict__ att, float* __restrict__ outp, int nnodes)
{
    const int n = blockIdx.x * 4 + (threadIdx.x >> 6);
    if (n >= nnodes) return;
    const int lane = threadIdx.x & 63;
    size_t b = (size_t)n * 64 + lane;
    float2 a = *(const float2*)&att[lane * 2];
    unsigned u0 = s0b[b], u1 = s1b[b], u2 = s2b[b], u3 = s3b[b];
    float p0 = bf_lo(u0) * a.x + bf_hi(u0) * a.y;
    float p1 = bf_lo(u1) * a.x + bf_hi(u1) * a.y;
    float p2 = bf_lo(u2) * a.x + bf_hi(u2) * a.y;
    float p3 = bf_lo(u3) * a.x + bf_hi(u3) * a.y;
#pragma unroll
    for (int mk = 32; mk >= 1; mk >>= 1) {
        p0 += __shfl_xor(p0, mk); p1 += __shfl_xor(p1, mk);
        p2 += __shfl_xor(p2, mk); p3 += __shfl_xor(p3, mk);
    }
    float mm = fmaxf(fmaxf(p0, p1), fmaxf(p2, p3));
    float e0 = __expf(p0 - mm), e1 = __expf(p1 - mm), e2 = __expf(p2 - mm), e3 = __expf(p3 - mm);
    float inv = 1.0f / (e0 + e1 + e2 + e3);
    float w0 = e0 * inv, w1 = e1 * inv, w2 = e2 * inv, w3 = e3 * inv;
    float ox = w0 * bf_lo(u0) + w1 * bf_lo(u1) + w2 * bf_lo(u2) + w3 * bf_lo(u3);
    float oy = w0 * bf_hi(u0) + w1 * bf_hi(u1) + w2 * bf_hi(u2) + w3 * bf_hi(u3);
    *(float2*)&outp[(size_t)n * 128 + lane * 2] = make_float2(ox, oy);
}

// ---------------------------------------------------------------------------
extern "C" void kernel_launch(void* const* d_in, const int* in_sizes, int n_in,
                              void* d_out, int out_size, void* d_ws, size_t ws_size,
                              hipStream_t stream)
{
    const float* x     = (const float*)d_in[0];
    const int*   ei    = (const int*)d_in[1];
    const float* W_in  = (const float*)d_in[2];
    const float* b_in  = (const float*)d_in[3];
    const float* W1    = (const float*)d_in[4];
    const float* a_s1  = (const float*)d_in[5];
    const float* a_d1  = (const float*)d_in[6];
    const float* b1    = (const float*)d_in[7];
    const float* W2    = (const float*)d_in[8];
    const float* a_s2  = (const float*)d_in[9];
    const float* a_d2  = (const float*)d_in[10];
    const float* b2    = (const float*)d_in[11];
    const float* g1    = (const float*)d_in[12];
    const float* be1   = (const float*)d_in[13];
    const float* g2    = (const float*)d_in[14];
    const float* be2   = (const float*)d_in[15];
    const float* W_ode = (const float*)d_in[16];
    const float* b_ode = (const float*)d_in[17];
    const float* att   = (const float*)d_in[18];

    const int N = in_sizes[0] / 128;
    const int E = in_sizes[1] / 2;
    const int* srcv = ei;
    const int* dstv = ei + E;

    char* wsb = (char*)d_ws;
    size_t off = 0;
    auto alloc = [&](size_t bytes) -> void* {
        void* p = wsb + off;
        off = (off + bytes + 511) & ~(size_t)511;
        return p;
    };
    float*    WnIn   = (float*)alloc(65536);
    float*    WnOde  = (float*)alloc(65536);
    float*    als    = (float*)alloc((size_t)N * 4 * 4);
    float*    ald    = (float*)alloc((size_t)N * 4 * 4);
    int*      deg    = (int*)alloc((size_t)N * 4);
    int*      cursor = (int*)alloc((size_t)N * 4);
    int*      offs   = (int*)alloc((size_t)(N + 1) * 4);
    int*      col    = (int*)alloc((size_t)E * 4);
    float*    B0     = (float*)alloc((size_t)N * 128 * 4);   // fp32 activations
    unsigned* xhbf   = (unsigned*)alloc((size_t)N * 64 * 4); // bf16 xh / hop1
    unsigned* ybf    = (unsigned*)alloc((size_t)N * 64 * 4); // bf16 ODE out
    unsigned* h2bf   = (unsigned*)alloc((size_t)N * 64 * 4);
    unsigned* h3bf   = (unsigned*)alloc((size_t)N * 64 * 4);

    (void)hipMemsetAsync(deg, 0, (size_t)N * 4, stream);
    (void)hipMemsetAsync(cursor, 0, (size_t)N * 4, stream);

    sn_k<<<2, 128, 0, stream>>>(W_in, W_ode, WnIn, WnOde);
    hist_k<<<(E + 255) / 256, 256, 0, stream>>>(dstv, deg, E, N);
    scan_k<<<1, 1024, 0, stream>>>(deg, offs, N);
    scatter_k<<<(E + 255) / 256, 256, 0, stream>>>(srcv, dstv, offs, cursor, col, E, N);

    const int gblocks = (N + 127) / 128;
    const int ablocks = (N + 3) / 4;

    // input layer: B0 = gelu(x @ sn(W_in) + b_in)
    gemm128_k<<<gblocks, 256, 0, stream>>>(x, WnIn, b_in, B0, nullptr, N, 1,
        nullptr, nullptr, nullptr, nullptr);

    // GAT layer 1
    gemm128_k<<<gblocks, 256, 0, stream>>>(B0, W1, nullptr, nullptr, xhbf, N, 0,
        a_s1, a_d1, als, ald);
    gat_agg2_k<<<ablocks, 256, 0, stream>>>(xhbf, als, ald, col, offs, b1, g1, be1, B0, N);

    // GAT layer 2
    gemm128_k<<<gblocks, 256, 0, stream>>>(B0, W2, nullptr, nullptr, xhbf, N, 0,
        a_s2, a_d2, als, ald);
    gat_agg2_k<<<ablocks, 256, 0, stream>>>(xhbf, als, ald, col, offs, b2, g2, be2, B0, N);

    // fused RK4 ODE (bf16 MFMA, wave-pair 16-row chunks): B0 -> ybf
    const int nchunks = (N + 15) / 16;
    const int oblocks = (nchunks + 1) / 2;
    ode_mfma_k<<<oblocks, 256, 0, stream>>>(B0, WnOde, b_ode, (unsigned short*)ybf, N, nchunks);

    // 3-hop mean broadcast (bf16 stack) + attention combine
    hop_k<<<ablocks, 256, 0, stream>>>(ybf,  col, offs, deg, xhbf, N);  // hop1
    hop_k<<<ablocks, 256, 0, stream>>>(xhbf, col, offs, deg, h2bf, N);  // hop2
    hop_k<<<ablocks, 256, 0, stream>>>(h2bf, col, offs, deg, h3bf, N);  // hop3
    final2_k<<<ablocks, 256, 0, stream>>>(ybf, xhbf, h2bf, h3bf, att, (float*)d_out, N);
}

// Round 6
// 681.737 us; speedup vs baseline: 3.1817x; 1.1547x over previous
//
#include <hip/hip_runtime.h>
#include <math.h>

// ---------------------------------------------------------------------------
// TemporalGraphEncoder: N=50000, E=1.6M, D=128, H=4, C=32, HOPS=3
// r6: (1) two-level bucketed CSR scatter (kills E*64B write amplification:
//     scatter_k wrote 101MB for a 6.4MB col array);
//     (2) all three dense GEMMs moved to bf16 MFMA (fp32 VALU -> matrix pipe).
// ---------------------------------------------------------------------------

typedef __attribute__((ext_vector_type(8))) short bf16x8;
typedef __attribute__((ext_vector_type(4))) float f32x4;

#define BSN 256   // nodes per bucket in CSR build (bucket id = dst >> 8)

__device__ __forceinline__ float gelu_f(float x) {
    return 0.5f * x * (1.0f + erff(x * 0.70710678118654752f));
}
__device__ __forceinline__ unsigned pack_bf16(float a, float b) {
    unsigned ua = __float_as_uint(a), ub = __float_as_uint(b);
    ua += 0x7fffu + ((ua >> 16) & 1u);
    ub += 0x7fffu + ((ub >> 16) & 1u);
    return (ua >> 16) | (ub & 0xffff0000u);
}
__device__ __forceinline__ unsigned short bfbits(float x) {
    unsigned u = __float_as_uint(x);
    u += 0x7fffu + ((u >> 16) & 1u);
    return (unsigned short)(u >> 16);
}
__device__ __forceinline__ float bf_lo(unsigned u) { return __uint_as_float(u << 16); }
__device__ __forceinline__ float bf_hi(unsigned u) { return __uint_as_float(u & 0xffff0000u); }
// XOR swizzle for 256B-row-stride LDS tiles (16B granule)
__device__ __forceinline__ int swz(int byte) { return byte ^ (((byte >> 8) & 15) << 4); }

// ---------------------- spectral norm (power iteration) --------------------
__launch_bounds__(128, 1)
__global__ void sn_k(const float* __restrict__ Win, const float* __restrict__ Wode,
                     float* __restrict__ WnIn, float* __restrict__ WnOde)
{
    __shared__ float Ws[128 * 128];
    __shared__ float Wt[128 * 128];
    __shared__ float red[128];
    const float* W  = (blockIdx.x == 0) ? Win  : Wode;
    float*       Wn = (blockIdx.x == 0) ? WnIn : WnOde;
    const int t = threadIdx.x;

    for (int i = t * 4; i < 16384; i += 512) {
        float4 v = *(const float4*)&W[i];
        *(float4*)&Ws[i] = v;
        int r = i >> 7, c = i & 127;
        Wt[(c + 0) * 128 + r] = v.x;
        Wt[(c + 1) * 128 + r] = v.y;
        Wt[(c + 2) * 128 + r] = v.z;
        Wt[(c + 3) * 128 + r] = v.w;
    }
    __syncthreads();

    float u = 0.088388347648318447f;  // 1/sqrt(128)
    float v = 0.0f;
    for (int it = 0; it < 5; it++) {
        red[t] = u; __syncthreads();
        float vv = 0.f;
        for (int i = 0; i < 128; i++) vv = fmaf(Ws[i * 128 + t], red[i], vv);
        __syncthreads();
        red[t] = vv * vv; __syncthreads();
        for (int s = 64; s > 0; s >>= 1) { if (t < s) red[t] += red[t + s]; __syncthreads(); }
        float nv = sqrtf(red[0]) + 1e-12f;
        v = vv / nv;
        __syncthreads();
        red[t] = v; __syncthreads();
        float uu = 0.f;
        for (int i = 0; i < 128; i++) uu = fmaf(Wt[i * 128 + t], red[i], uu);
        __syncthreads();
        red[t] = uu * uu; __syncthreads();
        for (int s = 64; s > 0; s >>= 1) { if (t < s) red[t] += red[t + s]; __syncthreads(); }
        float nu = sqrtf(red[0]) + 1e-12f;
        u = uu / nu;
        __syncthreads();
    }
    red[t] = v; __syncthreads();
    float wv = 0.f;
    for (int i = 0; i < 128; i++) wv = fmaf(Wt[i * 128 + t], red[i], wv);
    __syncthreads();
    red[t] = u * wv; __syncthreads();
    for (int s = 64; s > 0; s >>= 1) { if (t < s) red[t] += red[t + s]; __syncthreads(); }
    float inv = 1.0f / (red[0] + 1e-12f);
    __syncthreads();
    for (int i = t * 4; i < 16384; i += 512) {
        float4 w = *(const float4*)&Ws[i];
        w.x *= inv; w.y *= inv; w.z *= inv; w.w *= inv;
        *(float4*)&Wn[i] = w;
    }
}

// ------------------------------ CSR build ----------------------------------
__global__ void hist_k(const int* __restrict__ dst, int* __restrict__ deg, int E, int N)
{
    int e = blockIdx.x * blockDim.x + threadIdx.x;
    if (e < E) {
        int d = dst[e];
        d = (d < 0) ? 0 : (d >= N ? N - 1 : d);
        atomicAdd(&deg[d], 1);
    }
}

__launch_bounds__(1024, 1)
__global__ void scan_k(const int* __restrict__ deg, int* __restrict__ offs, int n)
{
    __shared__ int part[1024];
    const int t = threadIdx.x;
    const int chunk = (n + 1023) >> 10;
    int lo = t * chunk; if (lo > n) lo = n;
    int hi = lo + chunk; if (hi > n) hi = n;
    int s = 0;
    for (int i = lo; i < hi; i++) s += deg[i];
    part[t] = s; __syncthreads();
    for (int d = 1; d < 1024; d <<= 1) {
        int v = (t >= d) ? part[t - d] : 0;
        __syncthreads();
        part[t] += v;
        __syncthreads();
    }
    int run = (t == 0) ? 0 : part[t - 1];
    for (int i = lo; i < hi; i++) { offs[i] = run; run += deg[i]; }
    if (t == 1023) offs[n] = run;
}

// bucket cursor init: bcur[b] = offs[min(b*BSN, N)]
__global__ void binit_k(const int* __restrict__ offs, int* __restrict__ bcur, int N, int nb)
{
    int b = blockIdx.x * blockDim.x + threadIdx.x;
    if (b < nb) {
        int n = b * BSN; if (n > N) n = N;
        bcur[b] = offs[n];
    }
}

// pass A: block-level multisplit of edges into bucket regions of pairbuf.
// LDS-reordered so global writes are coalesced runs per (block,bucket).
__launch_bounds__(256, 2)
__global__ void scatA_k(const int* __restrict__ src, const int* __restrict__ dst,
                        int* __restrict__ bcur, uint2* __restrict__ pairbuf, int E, int N)
{
    __shared__ int cnt[256];
    __shared__ int sc[256];     // inclusive scan
    __shared__ int ebase[256];  // exclusive base per bucket
    __shared__ int delta[256];  // global base - local base
    __shared__ uint2 pr[4096];
    __shared__ unsigned char bid[4096];
    const int t = threadIdx.x;
    const int e0 = blockIdx.x * 4096;

    int s[16], d[16], rk[16], bb[16];
    cnt[t] = 0;
    __syncthreads();
#pragma unroll
    for (int i = 0; i < 16; i++) {
        int e = e0 + i * 256 + t;
        if (e < E) {
            int dd = dst[e]; dd = (dd < 0) ? 0 : (dd >= N ? N - 1 : dd);
            int ss = src[e]; ss = (ss < 0) ? 0 : (ss >= N ? N - 1 : ss);
            s[i] = ss; d[i] = dd; bb[i] = dd >> 8;
            rk[i] = atomicAdd(&cnt[bb[i]], 1);
        } else bb[i] = -1;
    }
    __syncthreads();
    sc[t] = cnt[t]; __syncthreads();
    for (int st = 1; st < 256; st <<= 1) {
        int v = (t >= st) ? sc[t - st] : 0;
        __syncthreads();
        sc[t] += v;
        __syncthreads();
    }
    int excl = sc[t] - cnt[t];
    int gbase = (cnt[t] > 0) ? atomicAdd(&bcur[t], cnt[t]) : 0;
    ebase[t] = excl;
    delta[t] = gbase - excl;
    __syncthreads();
#pragma unroll
    for (int i = 0; i < 16; i++) {
        if (bb[i] >= 0) {
            int slot = ebase[bb[i]] + rk[i];
            pr[slot] = make_uint2((unsigned)s[i], (unsigned)d[i]);
            bid[slot] = (unsigned char)bb[i];
        }
    }
    __syncthreads();
    const int total = sc[255];
    for (int i2 = t; i2 < total; i2 += 256) {
        int b = bid[i2];
        pairbuf[delta[b] + i2] = pr[i2];
    }
}

// pass B: one block per bucket; finalize col with LDS node cursors.
// random 4B writes confined to the bucket's ~64KB col region (L2-hot).
__launch_bounds__(256, 4)
__global__ void scatB_k(const uint2* __restrict__ pairbuf, const int* __restrict__ offs,
                        int* __restrict__ col, int N)
{
    __shared__ int cur[BSN];
    const int b = blockIdx.x;
    const int n0 = b * BSN;
    const int t = threadIdx.x;
    int nn = N - n0; if (nn > BSN) nn = BSN;
    if (t < nn) cur[t] = offs[n0 + t];
    __syncthreads();
    const int es = offs[n0], ee = offs[n0 + nn];
    for (int e = es + t; e < ee; e += 256) {
        uint2 p = pairbuf[e];
        int pos = atomicAdd(&cur[(int)p.y - n0], 1);
        col[pos] = (int)p.x;
    }
}

// ------------------------ GEMM 128 (bf16 MFMA) -----------------------------
// 128-row x 128-col tile per block (4 waves: wave w rows w*32..w*32+31).
// W^T and A staged bf16 in swizzled LDS. mfma_f32_16x16x32_bf16.
// mode 0: xh -> out_bf (ushort[node][128]) + fused al_s/al_d reductions
// mode 1: out_f32 = gelu(acc + bias)
__launch_bounds__(256, 2)
__global__ void gemm_mfma_k(const float* __restrict__ in, const float* __restrict__ W,
                            const float* __restrict__ bias, float* __restrict__ out_f32,
                            unsigned short* __restrict__ out_bf, int nrows, int mode,
                            const float* __restrict__ a_s, const float* __restrict__ a_d,
                            float* __restrict__ als, float* __restrict__ ald)
{
    __shared__ unsigned short Wt[128 * 128];  // [c][k] bf16, swizzled (32KB)
    __shared__ unsigned short As[128 * 128];  // [r][k] bf16, swizzled (32KB)
    const int t = threadIdx.x;
    const int w = t >> 6, lane = t & 63;
    const int cl = lane & 15, lg = lane >> 4;
    const int r0 = blockIdx.x * 128;

    for (int i = t; i < 16384; i += 256) {
        int k = i >> 7, c = i & 127;
        *(unsigned short*)((char*)Wt + swz((c << 8) + (k << 1))) = bfbits(W[i]);
    }
    for (int i2 = t; i2 < 4096; i2 += 256) {
        int r = i2 >> 5, k0 = (i2 & 31) * 4;
        int rc = r0 + r; if (rc > nrows - 1) rc = nrows - 1;
        float4 v = *(const float4*)&in[(size_t)rc * 128 + k0];
        *(uint2*)((char*)As + swz((r << 8) + (k0 << 1))) =
            make_uint2(pack_bf16(v.x, v.y), pack_bf16(v.z, v.w));
    }
    __syncthreads();

    bf16x8 af[2][4];
#pragma unroll
    for (int rt = 0; rt < 2; rt++)
#pragma unroll
        for (int ks = 0; ks < 4; ks++)
            af[rt][ks] = *(const bf16x8*)((char*)As +
                           swz((w * 32 + rt * 16 + cl) * 256 + ks * 64 + lg * 16));

    f32x4 acc[2][8];
#pragma unroll
    for (int rt = 0; rt < 2; rt++)
#pragma unroll
        for (int n = 0; n < 8; n++) acc[rt][n] = (f32x4){0.f, 0.f, 0.f, 0.f};

#pragma unroll
    for (int n = 0; n < 8; n++) {
#pragma unroll
        for (int ks = 0; ks < 4; ks++) {
            bf16x8 bf = *(const bf16x8*)((char*)Wt +
                          swz((n * 16 + cl) * 256 + ks * 64 + lg * 16));
            acc[0][n] = __builtin_amdgcn_mfma_f32_16x16x32_bf16(af[0][ks], bf, acc[0][n], 0, 0, 0);
            acc[1][n] = __builtin_amdgcn_mfma_f32_16x16x32_bf16(af[1][ks], bf, acc[1][n], 0, 0, 0);
        }
    }

    if (mode == 0) {
        float asv[4][2], adv[4][2];
#pragma unroll
        for (int h = 0; h < 4; h++) {
            asv[h][0] = a_s[h * 32 + cl];      asv[h][1] = a_s[h * 32 + 16 + cl];
            adv[h][0] = a_d[h * 32 + cl];      adv[h][1] = a_d[h * 32 + 16 + cl];
        }
#pragma unroll
        for (int rt = 0; rt < 2; rt++) {
#pragma unroll
            for (int q = 0; q < 4; q++) {
                int row = r0 + w * 32 + rt * 16 + lg * 4 + q;
                float sh[4], dh[4];
#pragma unroll
                for (int h = 0; h < 4; h++) {
                    sh[h] = acc[rt][2 * h][q] * asv[h][0] + acc[rt][2 * h + 1][q] * asv[h][1];
                    dh[h] = acc[rt][2 * h][q] * adv[h][0] + acc[rt][2 * h + 1][q] * adv[h][1];
                }
#pragma unroll
                for (int mk = 1; mk < 16; mk <<= 1) {
#pragma unroll
                    for (int h = 0; h < 4; h++) {
                        sh[h] += __shfl_xor(sh[h], mk);
                        dh[h] += __shfl_xor(dh[h], mk);
                    }
                }
                if (cl == 0 && row < nrows) {
#pragma unroll
                    for (int h = 0; h < 4; h++) {
                        als[(size_t)row * 4 + h] = sh[h];
                        ald[(size_t)row * 4 + h] = dh[h];
                    }
                }
            }
            // xh bf16 stores (ushort per col; layout-compatible with uint pairs)
#pragma unroll
            for (int q = 0; q < 4; q++) {
                int row = r0 + w * 32 + rt * 16 + lg * 4 + q;
                if (row < nrows) {
#pragma unroll
                    for (int n = 0; n < 8; n++)
                        out_bf[(size_t)row * 128 + n * 16 + cl] = bfbits(acc[rt][n][q]);
                }
            }
        }
    } else {
        float bc[8];
#pragma unroll
        for (int n = 0; n < 8; n++) bc[n] = bias[n * 16 + cl];
#pragma unroll
        for (int rt = 0; rt < 2; rt++)
#pragma unroll
            for (int q = 0; q < 4; q++) {
                int row = r0 + w * 32 + rt * 16 + lg * 4 + q;
                if (row < nrows) {
#pragma unroll
                    for (int n = 0; n < 8; n++)
                        out_f32[(size_t)row * 128 + n * 16 + cl] =
                            gelu_f(acc[rt][n][q] + bc[n]);
                }
            }
    }
}

// ----------------------- GAT aggregation v2 --------------------------------
__launch_bounds__(256)
__global__ void gat_agg2_k(const unsigned* __restrict__ xhbf, const float* __restrict__ als,
                           const float* __restrict__ ald, const int* __restrict__ col,
                           const int* __restrict__ offs, const float* __restrict__ bias,
                           const float* __restrict__ g, const float* __restrict__ be,
                           float* __restrict__ hout, int nnodes)
{
    __shared__ float alph[4][64][4];
    __shared__ int   scol[4][64];
    const int w = threadIdx.x >> 6;
    const int n = blockIdx.x * 4 + w;
    if (n >= nnodes) return;
    const int lane = threadIdx.x & 63;
    const int e0 = offs[n], e1 = offs[n + 1];
    const float4 aldv = *(const float4*)&ald[(size_t)n * 4];

    float m0 = -1e30f, m1 = -1e30f, m2 = -1e30f, m3 = -1e30f;
    float s0 = 0.f, s1 = 0.f, s2 = 0.f, s3 = 0.f;
    for (int i = e0 + lane; i < e1; i += 64) {
        int sv = col[i];
        float4 av = *(const float4*)&als[(size_t)sv * 4];
        float l0 = av.x + aldv.x; l0 = l0 > 0.f ? l0 : 0.2f * l0;
        float l1 = av.y + aldv.y; l1 = l1 > 0.f ? l1 : 0.2f * l1;
        float l2 = av.z + aldv.z; l2 = l2 > 0.f ? l2 : 0.2f * l2;
        float l3 = av.w + aldv.w; l3 = l3 > 0.f ? l3 : 0.2f * l3;
        float M;
        M = fmaxf(m0, l0); s0 = s0 * __expf(m0 - M) + __expf(l0 - M); m0 = M;
        M = fmaxf(m1, l1); s1 = s1 * __expf(m1 - M) + __expf(l1 - M); m1 = M;
        M = fmaxf(m2, l2); s2 = s2 * __expf(m2 - M) + __expf(l2 - M); m2 = M;
        M = fmaxf(m3, l3); s3 = s3 * __expf(m3 - M) + __expf(l3 - M); m3 = M;
    }
#pragma unroll
    for (int mk = 1; mk < 64; mk <<= 1) {
        float mo, so, M;
        mo = __shfl_xor(m0, mk); so = __shfl_xor(s0, mk);
        M = fmaxf(m0, mo); s0 = s0 * __expf(m0 - M) + so * __expf(mo - M); m0 = M;
        mo = __shfl_xor(m1, mk); so = __shfl_xor(s1, mk);
        M = fmaxf(m1, mo); s1 = s1 * __expf(m1 - M) + so * __expf(mo - M); m1 = M;
        mo = __shfl_xor(m2, mk); so = __shfl_xor(s2, mk);
        M = fmaxf(m2, mo); s2 = s2 * __expf(m2 - M) + so * __expf(mo - M); m2 = M;
        mo = __shfl_xor(m3, mk); so = __shfl_xor(s3, mk);
        M = fmaxf(m3, mo); s3 = s3 * __expf(m3 - M) + so * __expf(mo - M); m3 = M;
    }
    const float i0 = 1.f / (s0 + 1e-16f), i1 = 1.f / (s1 + 1e-16f);
    const float i2 = 1.f / (s2 + 1e-16f), i3 = 1.f / (s3 + 1e-16f);

    const int hh = lane >> 4;
    float ax = 0.f, ay = 0.f;
    for (int base = e0; base < e1; base += 64) {
        int idx = base + lane;
        if (idx < e1) {
            int sv = col[idx];
            float4 av = *(const float4*)&als[(size_t)sv * 4];
            float l0 = av.x + aldv.x; l0 = l0 > 0.f ? l0 : 0.2f * l0;
            float l1 = av.y + aldv.y; l1 = l1 > 0.f ? l1 : 0.2f * l1;
            float l2 = av.z + aldv.z; l2 = l2 > 0.f ? l2 : 0.2f * l2;
            float l3 = av.w + aldv.w; l3 = l3 > 0.f ? l3 : 0.2f * l3;
            float4 a4;
            a4.x = __expf(l0 - m0) * i0;
            a4.y = __expf(l1 - m1) * i1;
            a4.z = __expf(l2 - m2) * i2;
            a4.w = __expf(l3 - m3) * i3;
            *(float4*)&alph[w][lane][0] = a4;
            scol[w][lane] = sv;
        }
        int cnt = e1 - base; if (cnt > 64) cnt = 64;
#pragma unroll 4
        for (int j = 0; j < cnt; j++) {
            int sj = scol[w][j];
            float aj = alph[w][j][hh];
            unsigned u = xhbf[(size_t)sj * 64 + lane];
            ax = fmaf(aj, bf_lo(u), ax);
            ay = fmaf(aj, bf_hi(u), ay);
        }
    }

    const int c0 = lane * 2;
    float v0 = gelu_f(ax + bias[c0]);
    float v1 = gelu_f(ay + bias[c0 + 1]);
    float sum = v0 + v1;
#pragma unroll
    for (int mk = 32; mk >= 1; mk >>= 1) sum += __shfl_xor(sum, mk);
    float mean = sum * (1.0f / 128.0f);
    float d0 = v0 - mean, d1 = v1 - mean;
    float vs = d0 * d0 + d1 * d1;
#pragma unroll
    for (int mk = 32; mk >= 1; mk >>= 1) vs += __shfl_xor(vs, mk);
    float rstd = rsqrtf(vs * (1.0f / 128.0f) + 1e-5f);
    size_t b = (size_t)n * 128 + c0;
    hout[b]     = d0 * rstd * g[c0] + be[c0];
    hout[b + 1] = d1 * rstd * g[c0 + 1] + be[c0 + 1];
}

// ----------------------- fused RK4 ODE block (bf16 MFMA, wave-pair) --------
__launch_bounds__(256, 4)
__global__ void ode_mfma_k(const float* __restrict__ yin, const float* __restrict__ Wn,
                           const float* __restrict__ bias, unsigned short* __restrict__ ybf,
                           int nrows, int nchunks)
{
    __shared__ unsigned short Wt[128 * 128];     // [c][k] bf16, swizzled (32KB)
    __shared__ unsigned short tl[2][16 * 128];   // per-pair [r][k] bf16, swizzled
    const int t = threadIdx.x;
    const int w = t >> 6, lane = t & 63;
    const int pair = w >> 1, hf = w & 1;
    const int cl = lane & 15, lg = lane >> 4;

    for (int i = t; i < 16384; i += 256) {
        int k = i >> 7, c = i & 127;
        *(unsigned short*)((char*)Wt + swz((c << 8) + (k << 1))) = bfbits(Wn[i]);
    }

    float bcol[4];
#pragma unroll
    for (int n = 0; n < 4; n++) bcol[n] = bias[(hf * 4 + n) * 16 + cl];

    const float dt = 0.25f;
    char* tbase = (char*)&tl[pair][0];

    int chunk = blockIdx.x * 2 + pair;
    if (chunk > nchunks - 1) chunk = nchunks - 1;
    const int r0 = chunk * 16;

    for (int i2 = hf * 64 + lane; i2 < 512; i2 += 128) {
        int r = i2 >> 5, k0 = (i2 & 31) * 4;
        int rc = r0 + r; if (rc > nrows - 1) rc = nrows - 1;
        float4 v = *(const float4*)&yin[(size_t)rc * 128 + k0];
        *(uint2*)(tbase + swz(r * 256 + k0 * 2)) =
            make_uint2(pack_bf16(v.x, v.y), pack_bf16(v.z, v.w));
    }
    float yv[4][4], av[4][4];
#pragma unroll
    for (int q = 0; q < 4; q++) {
        int rc = r0 + lg * 4 + q; if (rc > nrows - 1) rc = nrows - 1;
        const float* rp = &yin[(size_t)rc * 128 + hf * 64 + cl];
#pragma unroll
        for (int n = 0; n < 4; n++) { yv[n][q] = rp[n * 16]; av[n][q] = yv[n][q]; }
    }
    __syncthreads();

#pragma unroll 1
    for (int step = 0; step < 4; step++) {
#pragma unroll 1
        for (int st = 0; st < 4; st++) {
            const float ca = (st == 0 || st == 3) ? dt / 6.f : dt / 3.f;
            const float ct = (st < 2) ? dt * 0.5f : dt;
            const bool last = (st == 3);
            bf16x8 af[4];
#pragma unroll
            for (int ks = 0; ks < 4; ks++)
                af[ks] = *(const bf16x8*)(tbase + swz(cl * 256 + ks * 64 + lg * 16));
            f32x4 acc[4];
#pragma unroll
            for (int n = 0; n < 4; n++) {
                acc[n] = (f32x4){0.f, 0.f, 0.f, 0.f};
#pragma unroll
                for (int ks = 0; ks < 4; ks++) {
                    bf16x8 bf = *(const bf16x8*)((char*)Wt +
                                  swz(((hf * 4 + n) * 16 + cl) * 256 + ks * 64 + lg * 16));
                    acc[n] = __builtin_amdgcn_mfma_f32_16x16x32_bf16(af[ks], bf, acc[n], 0, 0, 0);
                }
            }
            __syncthreads();
#pragma unroll
            for (int n = 0; n < 4; n++) {
#pragma unroll
                for (int q = 0; q < 4; q++) {
                    float kk = gelu_f(acc[n][q] + bcol[n]);
                    av[n][q] = fmaf(ca, kk, av[n][q]);
                    float tn;
                    if (last) { yv[n][q] = av[n][q]; tn = av[n][q]; }
                    else      { tn = fmaf(ct, kk, yv[n][q]); }
                    int rr = lg * 4 + q;
                    *(unsigned short*)(tbase +
                        swz(rr * 256 + ((hf * 4 + n) * 16 + cl) * 2)) = bfbits(tn);
                }
            }
            __syncthreads();
        }
    }
#pragma unroll
    for (int q = 0; q < 4; q++) {
        int rg = r0 + lg * 4 + q;
        if (rg < nrows) {
#pragma unroll
            for (int n = 0; n < 4; n++)
                ybf[(size_t)rg * 128 + hf * 64 + n * 16 + cl] = bfbits(av[n][q]);
        }
    }
}

// ----------------------- hop mean-aggregation (bf16) -----------------------
__launch_bounds__(256)
__global__ void hop_k(const unsigned* __restrict__ cur, const int* __restrict__ col,
                      const int* __restrict__ offs, const int* __restrict__ deg,
                      unsigned* __restrict__ outbf, int nnodes)
{
    __shared__ int scol[4][64];
    const int w = threadIdx.x >> 6;
    const int n = blockIdx.x * 4 + w;
    if (n >= nnodes) return;
    const int lane = threadIdx.x & 63;
    const int e0 = offs[n], e1 = offs[n + 1];
    float ax = 0.f, ay = 0.f;
    for (int base = e0; base < e1; base += 64) {
        int idx = base + lane;
        if (idx < e1) scol[w][lane] = col[idx];
        int cnt = e1 - base; if (cnt > 64) cnt = 64;
#pragma unroll 4
        for (int j = 0; j < cnt; j++) {
            int sj = scol[w][j];
            unsigned u = cur[(size_t)sj * 64 + lane];
            ax += bf_lo(u); ay += bf_hi(u);
        }
    }
    float dg = fmaxf((float)deg[n], 1.0f);
    outbf[(size_t)n * 64 + lane] = pack_bf16(ax / dg, ay / dg);
}

// ----------------------- hop-attention combine -----------------------------
__launch_bounds__(256)
__global__ void final2_k(const unsigned* __restrict__ s0b, const unsigned* __restrict__ s1b,
                         const unsigned* __restrict__ s2b, const unsigned* __restrict__ s3b,
                         const float* __restrict__ att, float* __restrict__ outp, int nnodes)
{
    const int n = blockIdx.x * 4 + (threadIdx.x >> 6);
    if (n >= nnodes) return;
    const int lane = threadIdx.x & 63;
    size_t b = (size_t)n * 64 + lane;
    float2 a = *(const float2*)&att[lane * 2];
    unsigned u0 = s0b[b], u1 = s1b[b], u2 = s2b[b], u3 = s3b[b];
    float p0 = bf_lo(u0) * a.x + bf_hi(u0) * a.y;
    float p1 = bf_lo(u1) * a.x + bf_hi(u1) * a.y;
    float p2 = bf_lo(u2) * a.x + bf_hi(u2) * a.y;
    float p3 = bf_lo(u3) * a.x + bf_hi(u3) * a.y;
#pragma unroll
    for (int mk = 32; mk >= 1; mk >>= 1) {
        p0 += __shfl_xor(p0, mk); p1 += __shfl_xor(p1, mk);
        p2 += __shfl_xor(p2, mk); p3 += __shfl_xor(p3, mk);
    }
    float mm = fmaxf(fmaxf(p0, p1), fmaxf(p2, p3));
    float e0 = __expf(p0 - mm), e1 = __expf(p1 - mm), e2 = __expf(p2 - mm), e3 = __expf(p3 - mm);
    float inv = 1.0f / (e0 + e1 + e2 + e3);
    float w0 = e0 * inv, w1 = e1 * inv, w2 = e2 * inv, w3 = e3 * inv;
    float ox = w0 * bf_lo(u0) + w1 * bf_lo(u1) + w2 * bf_lo(u2) + w3 * bf_lo(u3);
    float oy = w0 * bf_hi(u0) + w1 * bf_hi(u1) + w2 * bf_hi(u2) + w3 * bf_hi(u3);
    *(float2*)&outp[(size_t)n * 128 + lane * 2] = make_float2(ox, oy);
}

// ---------------------------------------------------------------------------
extern "C" void kernel_launch(void* const* d_in, const int* in_sizes, int n_in,
                              void* d_out, int out_size, void* d_ws, size_t ws_size,
                              hipStream_t stream)
{
    const float* x     = (const float*)d_in[0];
    const int*   ei    = (const int*)d_in[1];
    const float* W_in  = (const float*)d_in[2];
    const float* b_in  = (const float*)d_in[3];
    const float* W1    = (const float*)d_in[4];
    const float* a_s1  = (const float*)d_in[5];
    const float* a_d1  = (const float*)d_in[6];
    const float* b1    = (const float*)d_in[7];
    const float* W2    = (const float*)d_in[8];
    const float* a_s2  = (const float*)d_in[9];
    const float* a_d2  = (const float*)d_in[10];
    const float* b2    = (const float*)d_in[11];
    const float* g1    = (const float*)d_in[12];
    const float* be1   = (const float*)d_in[13];
    const float* g2    = (const float*)d_in[14];
    const float* be2   = (const float*)d_in[15];
    const float* W_ode = (const float*)d_in[16];
    const float* b_ode = (const float*)d_in[17];
    const float* att   = (const float*)d_in[18];

    const int N = in_sizes[0] / 128;
    const int E = in_sizes[1] / 2;
    const int* srcv = ei;
    const int* dstv = ei + E;
    const int nb = (N + BSN - 1) / BSN;

    char* wsb = (char*)d_ws;
    size_t off = 0;
    auto alloc = [&](size_t bytes) -> void* {
        void* p = wsb + off;
        off = (off + bytes + 511) & ~(size_t)511;
        return p;
    };
    float*    WnIn   = (float*)alloc(65536);
    float*    WnOde  = (float*)alloc(65536);
    float*    als    = (float*)alloc((size_t)N * 4 * 4);
    float*    ald    = (float*)alloc((size_t)N * 4 * 4);
    int*      deg    = (int*)alloc((size_t)N * 4);
    int*      bcur   = (int*)alloc((size_t)(nb + 1) * 4);
    int*      offs   = (int*)alloc((size_t)(N + 1) * 4);
    int*      col    = (int*)alloc((size_t)E * 4);
    float*    B0     = (float*)alloc((size_t)N * 128 * 4);   // fp32 activations
    unsigned* xhbf   = (unsigned*)alloc((size_t)N * 64 * 4); // bf16 xh / hop1
    unsigned* ybf    = (unsigned*)alloc((size_t)N * 64 * 4); // bf16 ODE out
    unsigned* h2bf   = (unsigned*)alloc((size_t)N * 64 * 4);
    unsigned* h3bf   = (unsigned*)alloc((size_t)N * 64 * 4);
    // pairbuf (E x 8B) aliases ybf (N*256B): used only before ode_mfma_k writes ybf
    uint2*    pairbuf = (uint2*)ybf;

    (void)hipMemsetAsync(deg, 0, (size_t)N * 4, stream);

    sn_k<<<2, 128, 0, stream>>>(W_in, W_ode, WnIn, WnOde);
    hist_k<<<(E + 255) / 256, 256, 0, stream>>>(dstv, deg, E, N);
    scan_k<<<1, 1024, 0, stream>>>(deg, offs, N);
    binit_k<<<(nb + 255) / 256, 256, 0, stream>>>(offs, bcur, N, nb);
    scatA_k<<<(E + 4095) / 4096, 256, 0, stream>>>(srcv, dstv, bcur, pairbuf, E, N);
    scatB_k<<<nb, 256, 0, stream>>>(pairbuf, offs, col, N);

    const int gblocks = (N + 127) / 128;
    const int ablocks = (N + 3) / 4;

    // input layer: B0 = gelu(x @ sn(W_in) + b_in)
    gemm_mfma_k<<<gblocks, 256, 0, stream>>>(x, WnIn, b_in, B0, nullptr, N, 1,
        nullptr, nullptr, nullptr, nullptr);

    // GAT layer 1
    gemm_mfma_k<<<gblocks, 256, 0, stream>>>(B0, W1, nullptr, nullptr,
        (unsigned short*)xhbf, N, 0, a_s1, a_d1, als, ald);
    gat_agg2_k<<<ablocks, 256, 0, stream>>>(xhbf, als, ald, col, offs, b1, g1, be1, B0, N);

    // GAT layer 2
    gemm_mfma_k<<<gblocks, 256, 0, stream>>>(B0, W2, nullptr, nullptr,
        (unsigned short*)xhbf, N, 0, a_s2, a_d2, als, ald);
    gat_agg2_k<<<ablocks, 256, 0, stream>>>(xhbf, als, ald, col, offs, b2, g2, be2, B0, N);

    // fused RK4 ODE (bf16 MFMA, wave-pair 16-row chunks): B0 -> ybf
    const int nchunks = (N + 15) / 16;
    const int oblocks = (nchunks + 1) / 2;
    ode_mfma_k<<<oblocks, 256, 0, stream>>>(B0, WnOde, b_ode, (unsigned short*)ybf, N, nchunks);

    // 3-hop mean broadcast (bf16 stack) + attention combine
    hop_k<<<ablocks, 256, 0, stream>>>(ybf,  col, offs, deg, xhbf, N);  // hop1
    hop_k<<<ablocks, 256, 0, stream>>>(xhbf, col, offs, deg, h2bf, N);  // hop2
    hop_k<<<ablocks, 256, 0, stream>>>(h2bf, col, offs, deg, h3bf, N);  // hop3
    final2_k<<<ablocks, 256, 0, stream>>>(ybf, xhbf, h2bf, h3bf, att, (float*)d_out, N);
}

// Round 7
// 675.657 us; speedup vs baseline: 3.2103x; 1.0090x over previous
//
#include <hip/hip_runtime.h>
#include <math.h>

// ---------------------------------------------------------------------------
// TemporalGraphEncoder: N=50000, E=1.6M, D=128, H=4, C=32, HOPS=3
// r7: (1) ODE gelu -> sigmoid-form tanh-GELU (erf gelu was 80% VALUBusy);
//     (2) hop_k / gat_agg2_k restructured to 32-lane node groups (2 nodes
//     per wave, 8B/lane gathers) to halve serial gather chains.
// ---------------------------------------------------------------------------

typedef __attribute__((ext_vector_type(8))) short bf16x8;
typedef __attribute__((ext_vector_type(4))) float f32x4;

#define BSN 256   // nodes per bucket in CSR build (bucket id = dst >> 8)

__device__ __forceinline__ float gelu_f(float x) {           // exact (erf)
    return 0.5f * x * (1.0f + erff(x * 0.70710678118654752f));
}
__device__ __forceinline__ float gelu_fast(float x) {        // tanh-form, sigmoid identity
    float y = 0.7978845608028654f * fmaf(0.044715f * x, x * x, x);
    float e = __expf(-2.0f * y);
    return x / (1.0f + e);
}
__device__ __forceinline__ unsigned pack_bf16(float a, float b) {
    unsigned ua = __float_as_uint(a), ub = __float_as_uint(b);
    ua += 0x7fffu + ((ua >> 16) & 1u);
    ub += 0x7fffu + ((ub >> 16) & 1u);
    return (ua >> 16) | (ub & 0xffff0000u);
}
__device__ __forceinline__ unsigned short bfbits(float x) {
    unsigned u = __float_as_uint(x);
    u += 0x7fffu + ((u >> 16) & 1u);
    return (unsigned short)(u >> 16);
}
__device__ __forceinline__ float bf_lo(unsigned u) { return __uint_as_float(u << 16); }
__device__ __forceinline__ float bf_hi(unsigned u) { return __uint_as_float(u & 0xffff0000u); }
// XOR swizzle for 256B-row-stride LDS tiles (16B granule)
__device__ __forceinline__ int swz(int byte) { return byte ^ (((byte >> 8) & 15) << 4); }

// ---------------------- spectral norm (power iteration) --------------------
__launch_bounds__(128, 1)
__global__ void sn_k(const float* __restrict__ Win, const float* __restrict__ Wode,
                     float* __restrict__ WnIn, float* __restrict__ WnOde)
{
    __shared__ float Ws[128 * 128];
    __shared__ float Wt[128 * 128];
    __shared__ float red[128];
    const float* W  = (blockIdx.x == 0) ? Win  : Wode;
    float*       Wn = (blockIdx.x == 0) ? WnIn : WnOde;
    const int t = threadIdx.x;

    for (int i = t * 4; i < 16384; i += 512) {
        float4 v = *(const float4*)&W[i];
        *(float4*)&Ws[i] = v;
        int r = i >> 7, c = i & 127;
        Wt[(c + 0) * 128 + r] = v.x;
        Wt[(c + 1) * 128 + r] = v.y;
        Wt[(c + 2) * 128 + r] = v.z;
        Wt[(c + 3) * 128 + r] = v.w;
    }
    __syncthreads();

    float u = 0.088388347648318447f;  // 1/sqrt(128)
    float v = 0.0f;
    for (int it = 0; it < 5; it++) {
        red[t] = u; __syncthreads();
        float vv = 0.f;
        for (int i = 0; i < 128; i++) vv = fmaf(Ws[i * 128 + t], red[i], vv);
        __syncthreads();
        red[t] = vv * vv; __syncthreads();
        for (int s = 64; s > 0; s >>= 1) { if (t < s) red[t] += red[t + s]; __syncthreads(); }
        float nv = sqrtf(red[0]) + 1e-12f;
        v = vv / nv;
        __syncthreads();
        red[t] = v; __syncthreads();
        float uu = 0.f;
        for (int i = 0; i < 128; i++) uu = fmaf(Wt[i * 128 + t], red[i], uu);
        __syncthreads();
        red[t] = uu * uu; __syncthreads();
        for (int s = 64; s > 0; s >>= 1) { if (t < s) red[t] += red[t + s]; __syncthreads(); }
        float nu = sqrtf(red[0]) + 1e-12f;
        u = uu / nu;
        __syncthreads();
    }
    red[t] = v; __syncthreads();
    float wv = 0.f;
    for (int i = 0; i < 128; i++) wv = fmaf(Wt[i * 128 + t], red[i], wv);
    __syncthreads();
    red[t] = u * wv; __syncthreads();
    for (int s = 64; s > 0; s >>= 1) { if (t < s) red[t] += red[t + s]; __syncthreads(); }
    float inv = 1.0f / (red[0] + 1e-12f);
    __syncthreads();
    for (int i = t * 4; i < 16384; i += 512) {
        float4 w = *(const float4*)&Ws[i];
        w.x *= inv; w.y *= inv; w.z *= inv; w.w *= inv;
        *(float4*)&Wn[i] = w;
    }
}

// ------------------------------ CSR build ----------------------------------
__global__ void hist_k(const int* __restrict__ dst, int* __restrict__ deg, int E, int N)
{
    int e = blockIdx.x * blockDim.x + threadIdx.x;
    if (e < E) {
        int d = dst[e];
        d = (d < 0) ? 0 : (d >= N ? N - 1 : d);
        atomicAdd(&deg[d], 1);
    }
}

__launch_bounds__(1024, 1)
__global__ void scan_k(const int* __restrict__ deg, int* __restrict__ offs, int n)
{
    __shared__ int part[1024];
    const int t = threadIdx.x;
    const int chunk = (n + 1023) >> 10;
    int lo = t * chunk; if (lo > n) lo = n;
    int hi = lo + chunk; if (hi > n) hi = n;
    int s = 0;
    for (int i = lo; i < hi; i++) s += deg[i];
    part[t] = s; __syncthreads();
    for (int d = 1; d < 1024; d <<= 1) {
        int v = (t >= d) ? part[t - d] : 0;
        __syncthreads();
        part[t] += v;
        __syncthreads();
    }
    int run = (t == 0) ? 0 : part[t - 1];
    for (int i = lo; i < hi; i++) { offs[i] = run; run += deg[i]; }
    if (t == 1023) offs[n] = run;
}

__global__ void binit_k(const int* __restrict__ offs, int* __restrict__ bcur, int N, int nb)
{
    int b = blockIdx.x * blockDim.x + threadIdx.x;
    if (b < nb) {
        int n = b * BSN; if (n > N) n = N;
        bcur[b] = offs[n];
    }
}

// pass A: block-level multisplit of edges into bucket regions of pairbuf.
__launch_bounds__(256, 2)
__global__ void scatA_k(const int* __restrict__ src, const int* __restrict__ dst,
                        int* __restrict__ bcur, uint2* __restrict__ pairbuf, int E, int N)
{
    __shared__ int cnt[256];
    __shared__ int sc[256];
    __shared__ int ebase[256];
    __shared__ int delta[256];
    __shared__ uint2 pr[4096];
    __shared__ unsigned char bid[4096];
    const int t = threadIdx.x;
    const int e0 = blockIdx.x * 4096;

    int s[16], d[16], rk[16], bb[16];
    cnt[t] = 0;
    __syncthreads();
#pragma unroll
    for (int i = 0; i < 16; i++) {
        int e = e0 + i * 256 + t;
        if (e < E) {
            int dd = dst[e]; dd = (dd < 0) ? 0 : (dd >= N ? N - 1 : dd);
            int ss = src[e]; ss = (ss < 0) ? 0 : (ss >= N ? N - 1 : ss);
            s[i] = ss; d[i] = dd; bb[i] = dd >> 8;
            rk[i] = atomicAdd(&cnt[bb[i]], 1);
        } else bb[i] = -1;
    }
    __syncthreads();
    sc[t] = cnt[t]; __syncthreads();
    for (int st = 1; st < 256; st <<= 1) {
        int v = (t >= st) ? sc[t - st] : 0;
        __syncthreads();
        sc[t] += v;
        __syncthreads();
    }
    int excl = sc[t] - cnt[t];
    int gbase = (cnt[t] > 0) ? atomicAdd(&bcur[t], cnt[t]) : 0;
    ebase[t] = excl;
    delta[t] = gbase - excl;
    __syncthreads();
#pragma unroll
    for (int i = 0; i < 16; i++) {
        if (bb[i] >= 0) {
            int slot = ebase[bb[i]] + rk[i];
            pr[slot] = make_uint2((unsigned)s[i], (unsigned)d[i]);
            bid[slot] = (unsigned char)bb[i];
        }
    }
    __syncthreads();
    const int total = sc[255];
    for (int i2 = t; i2 < total; i2 += 256) {
        int b = bid[i2];
        pairbuf[delta[b] + i2] = pr[i2];
    }
}

// pass B: one block per bucket; finalize col with LDS node cursors.
__launch_bounds__(256, 4)
__global__ void scatB_k(const uint2* __restrict__ pairbuf, const int* __restrict__ offs,
                        int* __restrict__ col, int N)
{
    __shared__ int cur[BSN];
    const int b = blockIdx.x;
    const int n0 = b * BSN;
    const int t = threadIdx.x;
    int nn = N - n0; if (nn > BSN) nn = BSN;
    if (t < nn) cur[t] = offs[n0 + t];
    __syncthreads();
    const int es = offs[n0], ee = offs[n0 + nn];
    for (int e = es + t; e < ee; e += 256) {
        uint2 p = pairbuf[e];
        int pos = atomicAdd(&cur[(int)p.y - n0], 1);
        col[pos] = (int)p.x;
    }
}

// ------------------------ GEMM 128 (bf16 MFMA) -----------------------------
__launch_bounds__(256, 2)
__global__ void gemm_mfma_k(const float* __restrict__ in, const float* __restrict__ W,
                            const float* __restrict__ bias, float* __restrict__ out_f32,
                            unsigned short* __restrict__ out_bf, int nrows, int mode,
                            const float* __restrict__ a_s, const float* __restrict__ a_d,
                            float* __restrict__ als, float* __restrict__ ald)
{
    __shared__ unsigned short Wt[128 * 128];
    __shared__ unsigned short As[128 * 128];
    const int t = threadIdx.x;
    const int w = t >> 6, lane = t & 63;
    const int cl = lane & 15, lg = lane >> 4;
    const int r0 = blockIdx.x * 128;

    for (int i = t; i < 16384; i += 256) {
        int k = i >> 7, c = i & 127;
        *(unsigned short*)((char*)Wt + swz((c << 8) + (k << 1))) = bfbits(W[i]);
    }
    for (int i2 = t; i2 < 4096; i2 += 256) {
        int r = i2 >> 5, k0 = (i2 & 31) * 4;
        int rc = r0 + r; if (rc > nrows - 1) rc = nrows - 1;
        float4 v = *(const float4*)&in[(size_t)rc * 128 + k0];
        *(uint2*)((char*)As + swz((r << 8) + (k0 << 1))) =
            make_uint2(pack_bf16(v.x, v.y), pack_bf16(v.z, v.w));
    }
    __syncthreads();

    bf16x8 af[2][4];
#pragma unroll
    for (int rt = 0; rt < 2; rt++)
#pragma unroll
        for (int ks = 0; ks < 4; ks++)
            af[rt][ks] = *(const bf16x8*)((char*)As +
                           swz((w * 32 + rt * 16 + cl) * 256 + ks * 64 + lg * 16));

    f32x4 acc[2][8];
#pragma unroll
    for (int rt = 0; rt < 2; rt++)
#pragma unroll
        for (int n = 0; n < 8; n++) acc[rt][n] = (f32x4){0.f, 0.f, 0.f, 0.f};

#pragma unroll
    for (int n = 0; n < 8; n++) {
#pragma unroll
        for (int ks = 0; ks < 4; ks++) {
            bf16x8 bf = *(const bf16x8*)((char*)Wt +
                          swz((n * 16 + cl) * 256 + ks * 64 + lg * 16));
            acc[0][n] = __builtin_amdgcn_mfma_f32_16x16x32_bf16(af[0][ks], bf, acc[0][n], 0, 0, 0);
            acc[1][n] = __builtin_amdgcn_mfma_f32_16x16x32_bf16(af[1][ks], bf, acc[1][n], 0, 0, 0);
        }
    }

    if (mode == 0) {
        float asv[4][2], adv[4][2];
#pragma unroll
        for (int h = 0; h < 4; h++) {
            asv[h][0] = a_s[h * 32 + cl];      asv[h][1] = a_s[h * 32 + 16 + cl];
            adv[h][0] = a_d[h * 32 + cl];      adv[h][1] = a_d[h * 32 + 16 + cl];
        }
#pragma unroll
        for (int rt = 0; rt < 2; rt++) {
#pragma unroll
            for (int q = 0; q < 4; q++) {
                int row = r0 + w * 32 + rt * 16 + lg * 4 + q;
                float sh[4], dh[4];
#pragma unroll
                for (int h = 0; h < 4; h++) {
                    sh[h] = acc[rt][2 * h][q] * asv[h][0] + acc[rt][2 * h + 1][q] * asv[h][1];
                    dh[h] = acc[rt][2 * h][q] * adv[h][0] + acc[rt][2 * h + 1][q] * adv[h][1];
                }
#pragma unroll
                for (int mk = 1; mk < 16; mk <<= 1) {
#pragma unroll
                    for (int h = 0; h < 4; h++) {
                        sh[h] += __shfl_xor(sh[h], mk);
                        dh[h] += __shfl_xor(dh[h], mk);
                    }
                }
                if (cl == 0 && row < nrows) {
#pragma unroll
                    for (int h = 0; h < 4; h++) {
                        als[(size_t)row * 4 + h] = sh[h];
                        ald[(size_t)row * 4 + h] = dh[h];
                    }
                }
            }
#pragma unroll
            for (int q = 0; q < 4; q++) {
                int row = r0 + w * 32 + rt * 16 + lg * 4 + q;
                if (row < nrows) {
#pragma unroll
                    for (int n = 0; n < 8; n++)
                        out_bf[(size_t)row * 128 + n * 16 + cl] = bfbits(acc[rt][n][q]);
                }
            }
        }
    } else {
        float bc[8];
#pragma unroll
        for (int n = 0; n < 8; n++) bc[n] = bias[n * 16 + cl];
#pragma unroll
        for (int rt = 0; rt < 2; rt++)
#pragma unroll
            for (int q = 0; q < 4; q++) {
                int row = r0 + w * 32 + rt * 16 + lg * 4 + q;
                if (row < nrows) {
#pragma unroll
                    for (int n = 0; n < 8; n++)
                        out_f32[(size_t)row * 128 + n * 16 + cl] =
                            gelu_f(acc[rt][n][q] + bc[n]);
                }
            }
    }
}

// ----------------------- GAT aggregation (32-lane node groups) -------------
// 8 nodes/block; each 32-lane group owns one node (lane covers 4 columns).
__launch_bounds__(256)
__global__ void gat_agg2_k(const unsigned* __restrict__ xhbf, const float* __restrict__ als,
                           const float* __restrict__ ald, const int* __restrict__ col,
                           const int* __restrict__ offs, const float* __restrict__ bias,
                           const float* __restrict__ g, const float* __restrict__ be,
                           float* __restrict__ hout, int nnodes)
{
    __shared__ float alph[8][32][4];
    __shared__ int   scol[8][32];
    const int gq = threadIdx.x >> 5;
    const int n = blockIdx.x * 8 + gq;
    if (n >= nnodes) return;
    const int l = threadIdx.x & 31;
    const int e0 = offs[n], e1 = offs[n + 1];
    const float4 aldv = *(const float4*)&ald[(size_t)n * 4];

    // online softmax stats, lane-strided (32) over edges
    float m0 = -1e30f, m1 = -1e30f, m2 = -1e30f, m3 = -1e30f;
    float s0 = 0.f, s1 = 0.f, s2 = 0.f, s3 = 0.f;
    for (int i = e0 + l; i < e1; i += 32) {
        int sv = col[i];
        float4 av = *(const float4*)&als[(size_t)sv * 4];
        float l0 = av.x + aldv.x; l0 = l0 > 0.f ? l0 : 0.2f * l0;
        float l1 = av.y + aldv.y; l1 = l1 > 0.f ? l1 : 0.2f * l1;
        float l2 = av.z + aldv.z; l2 = l2 > 0.f ? l2 : 0.2f * l2;
        float l3 = av.w + aldv.w; l3 = l3 > 0.f ? l3 : 0.2f * l3;
        float M;
        M = fmaxf(m0, l0); s0 = s0 * __expf(m0 - M) + __expf(l0 - M); m0 = M;
        M = fmaxf(m1, l1); s1 = s1 * __expf(m1 - M) + __expf(l1 - M); m1 = M;
        M = fmaxf(m2, l2); s2 = s2 * __expf(m2 - M) + __expf(l2 - M); m2 = M;
        M = fmaxf(m3, l3); s3 = s3 * __expf(m3 - M) + __expf(l3 - M); m3 = M;
    }
#pragma unroll
    for (int mk = 1; mk < 32; mk <<= 1) {   // stays within the 32-lane group
        float mo, so, M;
        mo = __shfl_xor(m0, mk); so = __shfl_xor(s0, mk);
        M = fmaxf(m0, mo); s0 = s0 * __expf(m0 - M) + so * __expf(mo - M); m0 = M;
        mo = __shfl_xor(m1, mk); so = __shfl_xor(s1, mk);
        M = fmaxf(m1, mo); s1 = s1 * __expf(m1 - M) + so * __expf(mo - M); m1 = M;
        mo = __shfl_xor(m2, mk); so = __shfl_xor(s2, mk);
        M = fmaxf(m2, mo); s2 = s2 * __expf(m2 - M) + so * __expf(mo - M); m2 = M;
        mo = __shfl_xor(m3, mk); so = __shfl_xor(s3, mk);
        M = fmaxf(m3, mo); s3 = s3 * __expf(m3 - M) + so * __expf(mo - M); m3 = M;
    }
    const float i0 = 1.f / (s0 + 1e-16f), i1 = 1.f / (s1 + 1e-16f);
    const float i2 = 1.f / (s2 + 1e-16f), i3 = 1.f / (s3 + 1e-16f);

    const int hh = l >> 3;   // head of this lane's 4 columns (4l..4l+3)
    float a0 = 0.f, a1 = 0.f, a2 = 0.f, a3 = 0.f;
    for (int base = e0; base < e1; base += 32) {
        int idx = base + l;
        if (idx < e1) {
            int sv = col[idx];
            float4 av = *(const float4*)&als[(size_t)sv * 4];
            float l0 = av.x + aldv.x; l0 = l0 > 0.f ? l0 : 0.2f * l0;
            float l1 = av.y + aldv.y; l1 = l1 > 0.f ? l1 : 0.2f * l1;
            float l2 = av.z + aldv.z; l2 = l2 > 0.f ? l2 : 0.2f * l2;
            float l3 = av.w + aldv.w; l3 = l3 > 0.f ? l3 : 0.2f * l3;
            float4 a4;
            a4.x = __expf(l0 - m0) * i0;
            a4.y = __expf(l1 - m1) * i1;
            a4.z = __expf(l2 - m2) * i2;
            a4.w = __expf(l3 - m3) * i3;
            *(float4*)&alph[gq][l][0] = a4;
            scol[gq][l] = sv;
        }
        int cnt = e1 - base; if (cnt > 32) cnt = 32;
#pragma unroll 4
        for (int j = 0; j < cnt; j++) {
            int sj = scol[gq][j];
            float aj = alph[gq][j][hh];
            uint2 u = *(const uint2*)&xhbf[(size_t)sj * 64 + l * 2];
            a0 = fmaf(aj, bf_lo(u.x), a0);
            a1 = fmaf(aj, bf_hi(u.x), a1);
            a2 = fmaf(aj, bf_lo(u.y), a2);
            a3 = fmaf(aj, bf_hi(u.y), a3);
        }
    }

    const int c0 = l * 4;
    float4 bv = *(const float4*)&bias[c0];
    float v0 = gelu_f(a0 + bv.x);
    float v1 = gelu_f(a1 + bv.y);
    float v2 = gelu_f(a2 + bv.z);
    float v3 = gelu_f(a3 + bv.w);
    float sum = v0 + v1 + v2 + v3;
#pragma unroll
    for (int mk = 1; mk < 32; mk <<= 1) sum += __shfl_xor(sum, mk);
    float mean = sum * (1.0f / 128.0f);
    float d0 = v0 - mean, d1 = v1 - mean, d2 = v2 - mean, d3 = v3 - mean;
    float vs = d0 * d0 + d1 * d1 + d2 * d2 + d3 * d3;
#pragma unroll
    for (int mk = 1; mk < 32; mk <<= 1) vs += __shfl_xor(vs, mk);
    float rstd = rsqrtf(vs * (1.0f / 128.0f) + 1e-5f);
    float4 gv = *(const float4*)&g[c0];
    float4 ev = *(const float4*)&be[c0];
    float4 o;
    o.x = d0 * rstd * gv.x + ev.x;
    o.y = d1 * rstd * gv.y + ev.y;
    o.z = d2 * rstd * gv.z + ev.z;
    o.w = d3 * rstd * gv.w + ev.w;
    *(float4*)&hout[(size_t)n * 128 + c0] = o;
}

// ----------------------- fused RK4 ODE block (bf16 MFMA, wave-pair) --------
__launch_bounds__(256, 4)
__global__ void ode_mfma_k(const float* __restrict__ yin, const float* __restrict__ Wn,
                           const float* __restrict__ bias, unsigned short* __restrict__ ybf,
                           int nrows, int nchunks)
{
    __shared__ unsigned short Wt[128 * 128];
    __shared__ unsigned short tl[2][16 * 128];
    const int t = threadIdx.x;
    const int w = t >> 6, lane = t & 63;
    const int pair = w >> 1, hf = w & 1;
    const int cl = lane & 15, lg = lane >> 4;

    for (int i = t; i < 16384; i += 256) {
        int k = i >> 7, c = i & 127;
        *(unsigned short*)((char*)Wt + swz((c << 8) + (k << 1))) = bfbits(Wn[i]);
    }

    float bcol[4];
#pragma unroll
    for (int n = 0; n < 4; n++) bcol[n] = bias[(hf * 4 + n) * 16 + cl];

    const float dt = 0.25f;
    char* tbase = (char*)&tl[pair][0];

    int chunk = blockIdx.x * 2 + pair;
    if (chunk > nchunks - 1) chunk = nchunks - 1;
    const int r0 = chunk * 16;

    for (int i2 = hf * 64 + lane; i2 < 512; i2 += 128) {
        int r = i2 >> 5, k0 = (i2 & 31) * 4;
        int rc = r0 + r; if (rc > nrows - 1) rc = nrows - 1;
        float4 v = *(const float4*)&yin[(size_t)rc * 128 + k0];
        *(uint2*)(tbase + swz(r * 256 + k0 * 2)) =
            make_uint2(pack_bf16(v.x, v.y), pack_bf16(v.z, v.w));
    }
    float yv[4][4], av[4][4];
#pragma unroll
    for (int q = 0; q < 4; q++) {
        int rc = r0 + lg * 4 + q; if (rc > nrows - 1) rc = nrows - 1;
        const float* rp = &yin[(size_t)rc * 128 + hf * 64 + cl];
#pragma unroll
        for (int n = 0; n < 4; n++) { yv[n][q] = rp[n * 16]; av[n][q] = yv[n][q]; }
    }
    __syncthreads();

#pragma unroll 1
    for (int step = 0; step < 4; step++) {
#pragma unroll 1
        for (int st = 0; st < 4; st++) {
            const float ca = (st == 0 || st == 3) ? dt / 6.f : dt / 3.f;
            const float ct = (st < 2) ? dt * 0.5f : dt;
            const bool last = (st == 3);
            bf16x8 af[4];
#pragma unroll
            for (int ks = 0; ks < 4; ks++)
                af[ks] = *(const bf16x8*)(tbase + swz(cl * 256 + ks * 64 + lg * 16));
            f32x4 acc[4];
#pragma unroll
            for (int n = 0; n < 4; n++) {
                acc[n] = (f32x4){0.f, 0.f, 0.f, 0.f};
#pragma unroll
                for (int ks = 0; ks < 4; ks++) {
                    bf16x8 bf = *(const bf16x8*)((char*)Wt +
                                  swz(((hf * 4 + n) * 16 + cl) * 256 + ks * 64 + lg * 16));
                    acc[n] = __builtin_amdgcn_mfma_f32_16x16x32_bf16(af[ks], bf, acc[n], 0, 0, 0);
                }
            }
            __syncthreads();
#pragma unroll
            for (int n = 0; n < 4; n++) {
#pragma unroll
                for (int q = 0; q < 4; q++) {
                    float kk = gelu_fast(acc[n][q] + bcol[n]);
                    av[n][q] = fmaf(ca, kk, av[n][q]);
                    float tn;
                    if (last) { yv[n][q] = av[n][q]; tn = av[n][q]; }
                    else      { tn = fmaf(ct, kk, yv[n][q]); }
                    int rr = lg * 4 + q;
                    *(unsigned short*)(tbase +
                        swz(rr * 256 + ((hf * 4 + n) * 16 + cl) * 2)) = bfbits(tn);
                }
            }
            __syncthreads();
        }
    }
#pragma unroll
    for (int q = 0; q < 4; q++) {
        int rg = r0 + lg * 4 + q;
        if (rg < nrows) {
#pragma unroll
            for (int n = 0; n < 4; n++)
                ybf[(size_t)rg * 128 + hf * 64 + n * 16 + cl] = bfbits(av[n][q]);
        }
    }
}

// ----------------------- hop mean-aggregation (32-lane groups) -------------
__launch_bounds__(256)
__global__ void hop_k(const unsigned* __restrict__ cur, const int* __restrict__ col,
                      const int* __restrict__ offs, const int* __restrict__ deg,
                      unsigned* __restrict__ outbf, int nnodes)
{
    __shared__ int scol[8][32];
    const int gq = threadIdx.x >> 5;
    const int n = blockIdx.x * 8 + gq;
    if (n >= nnodes) return;
    const int l = threadIdx.x & 31;
    const int e0 = offs[n], e1 = offs[n + 1];
    float a0 = 0.f, a1 = 0.f, a2 = 0.f, a3 = 0.f;
    for (int base = e0; base < e1; base += 32) {
        int idx = base + l;
        if (idx < e1) scol[gq][l] = col[idx];
        int cnt = e1 - base; if (cnt > 32) cnt = 32;
#pragma unroll 4
        for (int j = 0; j < cnt; j++) {
            int sj = scol[gq][j];
            uint2 u = *(const uint2*)&cur[(size_t)sj * 64 + l * 2];
            a0 += bf_lo(u.x); a1 += bf_hi(u.x);
            a2 += bf_lo(u.y); a3 += bf_hi(u.y);
        }
    }
    float inv = 1.0f / fmaxf((float)deg[n], 1.0f);
    *(uint2*)&outbf[(size_t)n * 64 + l * 2] =
        make_uint2(pack_bf16(a0 * inv, a1 * inv), pack_bf16(a2 * inv, a3 * inv));
}

// ----------------------- hop-attention combine -----------------------------
__launch_bounds__(256)
__global__ void final2_k(const unsigned* __restrict__ s0b, const unsigned* __restrict__ s1b,
                         const unsigned* __restrict__ s2b, const unsigned* __restrict__ s3b,
                         const float* __restrict__ att, float* __restrict__ outp, int nnodes)
{
    const int n = blockIdx.x * 4 + (threadIdx.x >> 6);
    if (n >= nnodes) return;
    const int lane = threadIdx.x & 63;
    size_t b = (size_t)n * 64 + lane;
    float2 a = *(const float2*)&att[lane * 2];
    unsigned u0 = s0b[b], u1 = s1b[b], u2 = s2b[b], u3 = s3b[b];
    float p0 = bf_lo(u0) * a.x + bf_hi(u0) * a.y;
    float p1 = bf_lo(u1) * a.x + bf_hi(u1) * a.y;
    float p2 = bf_lo(u2) * a.x + bf_hi(u2) * a.y;
    float p3 = bf_lo(u3) * a.x + bf_hi(u3) * a.y;
#pragma unroll
    for (int mk = 32; mk >= 1; mk >>= 1) {
        p0 += __shfl_xor(p0, mk); p1 += __shfl_xor(p1, mk);
        p2 += __shfl_xor(p2, mk); p3 += __shfl_xor(p3, mk);
    }
    float mm = fmaxf(fmaxf(p0, p1), fmaxf(p2, p3));
    float e0 = __expf(p0 - mm), e1 = __expf(p1 - mm), e2 = __expf(p2 - mm), e3 = __expf(p3 - mm);
    float inv = 1.0f / (e0 + e1 + e2 + e3);
    float w0 = e0 * inv, w1 = e1 * inv, w2 = e2 * inv, w3 = e3 * inv;
    float ox = w0 * bf_lo(u0) + w1 * bf_lo(u1) + w2 * bf_lo(u2) + w3 * bf_lo(u3);
    float oy = w0 * bf_hi(u0) + w1 * bf_hi(u1) + w2 * bf_hi(u2) + w3 * bf_hi(u3);
    *(float2*)&outp[(size_t)n * 128 + lane * 2] = make_float2(ox, oy);
}

// ---------------------------------------------------------------------------
extern "C" void kernel_launch(void* const* d_in, const int* in_sizes, int n_in,
                              void* d_out, int out_size, void* d_ws, size_t ws_size,
                              hipStream_t stream)
{
    const float* x     = (const float*)d_in[0];
    const int*   ei    = (const int*)d_in[1];
    const float* W_in  = (const float*)d_in[2];
    const float* b_in  = (const float*)d_in[3];
    const float* W1    = (const float*)d_in[4];
    const float* a_s1  = (const float*)d_in[5];
    const float* a_d1  = (const float*)d_in[6];
    const float* b1    = (const float*)d_in[7];
    const float* W2    = (const float*)d_in[8];
    const float* a_s2  = (const float*)d_in[9];
    const float* a_d2  = (const float*)d_in[10];
    const float* b2    = (const float*)d_in[11];
    const float* g1    = (const float*)d_in[12];
    const float* be1   = (const float*)d_in[13];
    const float* g2    = (const float*)d_in[14];
    const float* be2   = (const float*)d_in[15];
    const float* W_ode = (const float*)d_in[16];
    const float* b_ode = (const float*)d_in[17];
    const float* att   = (const float*)d_in[18];

    const int N = in_sizes[0] / 128;
    const int E = in_sizes[1] / 2;
    const int* srcv = ei;
    const int* dstv = ei + E;
    const int nb = (N + BSN - 1) / BSN;

    char* wsb = (char*)d_ws;
    size_t off = 0;
    auto alloc = [&](size_t bytes) -> void* {
        void* p = wsb + off;
        off = (off + bytes + 511) & ~(size_t)511;
        return p;
    };
    float*    WnIn   = (float*)alloc(65536);
    float*    WnOde  = (float*)alloc(65536);
    float*    als    = (float*)alloc((size_t)N * 4 * 4);
    float*    ald    = (float*)alloc((size_t)N * 4 * 4);
    int*      deg    = (int*)alloc((size_t)N * 4);
    int*      bcur   = (int*)alloc((size_t)(nb + 1) * 4);
    int*      offs   = (int*)alloc((size_t)(N + 1) * 4);
    int*      col    = (int*)alloc((size_t)E * 4);
    float*    B0     = (float*)alloc((size_t)N * 128 * 4);
    unsigned* xhbf   = (unsigned*)alloc((size_t)N * 64 * 4);
    unsigned* ybf    = (unsigned*)alloc((size_t)N * 64 * 4);
    unsigned* h2bf   = (unsigned*)alloc((size_t)N * 64 * 4);
    unsigned* h3bf   = (unsigned*)alloc((size_t)N * 64 * 4);
    uint2*    pairbuf = (uint2*)ybf;   // aliases ybf; consumed before ybf is written

    (void)hipMemsetAsync(deg, 0, (size_t)N * 4, stream);

    sn_k<<<2, 128, 0, stream>>>(W_in, W_ode, WnIn, WnOde);
    hist_k<<<(E + 255) / 256, 256, 0, stream>>>(dstv, deg, E, N);
    scan_k<<<1, 1024, 0, stream>>>(deg, offs, N);
    binit_k<<<(nb + 255) / 256, 256, 0, stream>>>(offs, bcur, N, nb);
    scatA_k<<<(E + 4095) / 4096, 256, 0, stream>>>(srcv, dstv, bcur, pairbuf, E, N);
    scatB_k<<<nb, 256, 0, stream>>>(pairbuf, offs, col, N);

    const int gblocks = (N + 127) / 128;
    const int ablocks = (N + 7) / 8;
    const int fblocks = (N + 3) / 4;

    gemm_mfma_k<<<gblocks, 256, 0, stream>>>(x, WnIn, b_in, B0, nullptr, N, 1,
        nullptr, nullptr, nullptr, nullptr);

    gemm_mfma_k<<<gblocks, 256, 0, stream>>>(B0, W1, nullptr, nullptr,
        (unsigned short*)xhbf, N, 0, a_s1, a_d1, als, ald);
    gat_agg2_k<<<ablocks, 256, 0, stream>>>(xhbf, als, ald, col, offs, b1, g1, be1, B0, N);

    gemm_mfma_k<<<gblocks, 256, 0, stream>>>(B0, W2, nullptr, nullptr,
        (unsigned short*)xhbf, N, 0, a_s2, a_d2, als, ald);
    gat_agg2_k<<<ablocks, 256, 0, stream>>>(xhbf, als, ald, col, offs, b2, g2, be2, B0, N);

    const int nchunks = (N + 15) / 16;
    const int oblocks = (nchunks + 1) / 2;
    ode_mfma_k<<<oblocks, 256, 0, stream>>>(B0, WnOde, b_ode, (unsigned short*)ybf, N, nchunks);

    hop_k<<<ablocks, 256, 0, stream>>>(ybf,  col, offs, deg, xhbf, N);  // hop1
    hop_k<<<ablocks, 256, 0, stream>>>(xhbf, col, offs, deg, h2bf, N);  // hop2
    hop_k<<<ablocks, 256, 0, stream>>>(h2bf, col, offs, deg, h3bf, N);  // hop3
    final2_k<<<fblocks, 256, 0, stream>>>(ybf, xhbf, h2bf, h3bf, att, (float*)d_out, N);
}